// Round 3
// baseline (975.461 us; speedup 1.0000x reference)
//
#include <hip/hip_runtime.h>
#include <hip/hip_cooperative_groups.h>
#include <math.h>

#define B_ 4
#define N_ 4096
#define D_ 128
#define NS_ 16
#define NT_ 64
#define SCALE_ 0.08838834764831843f
#define EPS_ 1e-10f

// workspace offsets (in floats) -- layout kept from r2 (ws_size known sufficient)
#define OFF_K      ((size_t)0)
#define OFF_V      (OFF_K + (size_t)B_*N_*D_)
#define OFF_WTKV   (OFF_V + (size_t)B_*N_*D_)
#define OFF_WQT    (OFF_WTKV + 128*256)
#define OFF_WC     (OFF_WQT + 128*128)
#define OFF_MW1T   (OFF_WC + 256*512)
#define OFF_MW2T   (OFF_MW1T + 128*512)
#define OFF_OW1T   (OFF_MW2T + 512*128)
#define OFF_OW2T   (OFF_OW1T + 256*1024)
#define OFF_SLOTS  (OFF_OW2T + 1024*128)
#define OFF_MU     (OFF_SLOTS + (size_t)B_*NS_*256)
#define OFF_WCOEF  (OFF_MU + (size_t)B_*NS_*128)
#define OFF_C      (OFF_WCOEF + (size_t)B_*128*32)
#define OFF_RS     (OFF_C + 64)
#define OFF_OPART  (OFF_RS + 64)
#define OFF_PART   (OFF_OPART + 64*4*128)
#define OFF_ATTNU  (OFF_PART + (size_t)B_*NT_*NS_*260)

// ---- dynamic LDS layout (floats) ----
#define P_KT   0        /* kT[c][l] c<128, l<64 : 8192 */
#define P_V    8192     /* xs[64][129] prologue; v[64][128] steps : 8256 */
#define P_ATT  16448    /* a[i][j] 16x64 : 1024 */
#define P_ESUM 17472    /* esum[w][l] 8x64 : 512 */
#define P_WCO  17984    /* wcoef slice for this b : 4096 */
#define P_SLOT 22080    /* slot scratch : 3840 */
#define LDS_FLOATS 25920
#define LDS_BYTES  (LDS_FLOATS * 4)

// slot scratch offsets within P_SLOT
#define S_ZS    0     /* 256 */
#define S_S2    256   /* 128 */
#define S_OUTG  384   /* 512 */
#define S_A1S   896   /* 512 */
#define S_UU    1408  /* 128 */
#define S_H2    1536  /* 128 */
#define S_SNEW  1664  /* 256 */
#define S_QM    1920  /* 128 */
#define S_QL    2048  /* 128 */
#define S_RED   2176  /* 512 */
#define S_PPART 2688  /* 512 */
#define S_QPART 3200  /* 512 */
#define S_HM    3712  /* 128 */

struct MegaP {
  const float* __restrict__ slots_in;
  const float* __restrict__ inputs;
  const float* __restrict__ wt;
  const float* __restrict__ wqT;
  const float* __restrict__ wc;
  const float* __restrict__ mw1T;
  const float* __restrict__ mw2T;
  const float* __restrict__ ow1T;
  const float* __restrict__ ow2T;
  const float* __restrict__ gin;
  const float* __restrict__ bin;
  const float* __restrict__ gsl;
  const float* __restrict__ bsl;
  const float* __restrict__ gmu;
  const float* __restrict__ bmu;
  const float* __restrict__ bih;
  const float* __restrict__ bhh;
  const float* __restrict__ mb1;
  const float* __restrict__ mb2;
  const float* __restrict__ ob1;
  const float* __restrict__ ob2;
  // cross-block communicated buffers: plain pointers (no restrict/const) so the
  // compiler never caches them in SMEM/K$ across grid syncs
  float* wcoef;
  float* cbuf;
  float* part;
  float* rowsum;
  float* slots;
  float* attnu;
  float* opart;
  float* out;
};

__device__ __forceinline__ float bRed512(float v, float* red, int tid) {
  red[tid] = v;
  __syncthreads();
  if (tid < 256) red[tid] += red[tid + 256];
  __syncthreads();
  if (tid < 128) red[tid] += red[tid + 128];
  __syncthreads();
  if (tid < 64) {
    float x = red[tid] + red[tid + 64];
    #pragma unroll
    for (int off = 32; off > 0; off >>= 1) x += __shfl_down(x, off, 64);
    if (tid == 0) red[0] = x;
  }
  __syncthreads();
  float r = red[0];
  __syncthreads();
  return r;
}

// LN'd 256-vec lives at sl[S_A1S..S_A1S+255]; writes wcoef/cbuf for (b2,i)
__device__ __forceinline__ void slotTail512(const MegaP& p, float* sl, int b2, int i, int tid) {
  int kg = tid >> 8, oq = tid & 255;
  int base = S_A1S + ((oq < 128) ? 0 : 128);
  int dout = oq & 127;
  float acc = 0.f;
  #pragma unroll 8
  for (int dd = 0; dd < 64; ++dd)
    acc = fmaf(sl[base + kg * 64 + dd], p.wqT[(kg * 64 + dd) * 128 + dout], acc);
  sl[S_QPART + kg * 256 + oq] = acc;
  __syncthreads();
  if (tid < 256) {
    float q = sl[S_QPART + tid] + sl[S_QPART + 256 + tid];
    if (tid < 128) sl[S_QM + tid] = q; else sl[S_QL + tid - 128] = q;
  }
  __syncthreads();
  float cp = 0.f;
  if (tid < 128) {
    float iv = expf(-2.f * sl[S_QL + tid]);
    float a1 = SCALE_ * iv;
    float a2 = -2.f * SCALE_ * iv * sl[S_QM + tid];
    float* wrow = &p.wcoef[((size_t)b2 * 128 + tid) * 32];
    wrow[2 * i] = a2;
    wrow[2 * i + 1] = a1;
    cp = SCALE_ * iv * sl[S_QM + tid] * sl[S_QM + tid];
  }
  float ctot = bRed512(cp, sl + S_RED, tid);
  if (tid == 0) p.cbuf[b2 * NS_ + i] = ctot;
}

__device__ __forceinline__ void slotUpdate(const MegaP& p, float* sl, int b2, int i, int tid) {
  size_t pbase = ((size_t)(b2 * NT_) * NS_ + i) * 260;
  const size_t pstr = (size_t)NS_ * 260;
  {
    int th = tid >> 8, e = tid & 255;
    float s = 0.f;
    #pragma unroll 8
    for (int t = 0; t < 32; ++t) s += p.part[pbase + (size_t)(th * 32 + t) * pstr + e];
    sl[S_PPART + th * 256 + e] = s;
  }
  float rp = (tid < 64) ? p.part[pbase + (size_t)tid * pstr + 256] : 0.f;
  float rt = bRed512(rp, sl + S_RED, tid);  // internal syncs cover ppart
  if (tid == 0) p.rowsum[b2 * NS_ + i] = rt;
  if (tid < 128) sl[S_ZS + tid] = (sl[S_PPART + tid] + sl[S_PPART + 256 + tid]) / rt;
  else if (tid < 256) sl[S_S2 + tid - 128] = (sl[S_PPART + tid] + sl[S_PPART + 256 + tid]) / rt;
  else if (tid < 384) sl[S_ZS + tid - 128] = sl[S_HM + tid - 256];
  __syncthreads();
  // unified GRU matvec: [xs|hm] @ WC (256x512)
  {
    float acc = 0.f;
    #pragma unroll 8
    for (int dd = 0; dd < 256; ++dd) acc = fmaf(sl[S_ZS + dd], p.wc[dd * 512 + tid], acc);
    sl[S_OUTG + tid] = acc;
  }
  __syncthreads();
  if (tid < 128) {
    float r = 1.f / (1.f + expf(-(sl[S_OUTG + tid] + p.bih[tid] + p.bhh[tid])));
    float z = 1.f / (1.f + expf(-(sl[S_OUTG + 128 + tid] + p.bih[128 + tid] + p.bhh[128 + tid])));
    float nn = tanhf(sl[S_OUTG + 256 + tid] + p.bih[256 + tid] +
                     r * (sl[S_OUTG + 384 + tid] + p.bhh[256 + tid]));
    sl[S_UU + tid] = (1.f - z) * nn + z * sl[S_ZS + 128 + tid];
  }
  __syncthreads();
  // LN(u)
  float uv = (tid < 128) ? sl[S_UU + tid] : 0.f;
  float m = bRed512(uv, sl + S_RED, tid) * (1.f / 128.f);
  float dv = (tid < 128) ? (sl[S_UU + tid] - m) : 0.f;
  float var = bRed512(dv * dv, sl + S_RED, tid) * (1.f / 128.f);
  float rsq = rsqrtf(var + 1e-5f);
  if (tid < 128) sl[S_H2 + tid] = dv * rsq * p.gmu[tid] + p.bmu[tid];
  __syncthreads();
  // MLP up
  {
    float a = p.mb1[tid];
    #pragma unroll 8
    for (int dd = 0; dd < 128; ++dd) a = fmaf(sl[S_H2 + dd], p.mw1T[dd * 512 + tid], a);
    sl[S_A1S + tid] = fmaxf(a, 0.f);
  }
  __syncthreads();
  // MLP down, q split 4 ways
  {
    int qg = tid >> 7, d = tid & 127;
    float dp = 0.f;
    #pragma unroll 8
    for (int qq = 0; qq < 128; ++qq)
      dp = fmaf(sl[S_A1S + qg * 128 + qq], p.mw2T[(qg * 128 + qq) * 128 + d], dp);
    sl[S_QPART + qg * 128 + d] = dp;
  }
  __syncthreads();
  if (tid < 128) {
    float o = p.mb2[tid] + sl[S_QPART + tid] + sl[S_QPART + 128 + tid] +
              sl[S_QPART + 256 + tid] + sl[S_QPART + 384 + tid];
    float uf = sl[S_UU + tid] + o;
    float xsv = sl[S_ZS + tid];
    float arg = sl[S_S2 + tid] - 2.f * uf * xsv + uf * uf + EPS_;
    float lsv = 0.5f * logf(fmaxf(arg, 1e-30f));
    sl[S_SNEW + tid] = uf;
    sl[S_SNEW + 128 + tid] = lsv;
    size_t so = (size_t)(b2 * NS_ + i) * 256;
    p.slots[so + tid] = uf;
    p.slots[so + 128 + tid] = lsv;
  }
  __syncthreads();
  // next-step LN over new slot row
  float x = (tid < 256) ? sl[S_SNEW + tid] : 0.f;
  float m2 = bRed512(x, sl + S_RED, tid) * (1.f / 256.f);
  float d2 = (tid < 256) ? (sl[S_SNEW + tid] - m2) : 0.f;
  float v2 = bRed512(d2 * d2, sl + S_RED, tid) * (1.f / 256.f);
  float rs2 = rsqrtf(v2 + 1e-5f);
  if (tid < 256) {
    float slv = d2 * rs2 * p.gsl[tid] + p.bsl[tid];
    sl[S_A1S + tid] = slv;
    if (tid < 128) sl[S_HM + tid] = slv;
  }
  __syncthreads();
  slotTail512(p, sl, b2, i, tid);
}

__global__ __launch_bounds__(512, 1) void megaK(MegaP p) {
  extern __shared__ float lds[];
  cooperative_groups::grid_group grid = cooperative_groups::this_grid();
  const int tid = threadIdx.x;
  const int blk = blockIdx.x;
  const int b = blk >> 6, jt = blk & 63;
  const int rowbase = jt * 64;
  float* sl = lds + P_SLOT;

  // ---- prologue: stage + LN x-tile into P_V as xs[64][129] ----
  #pragma unroll
  for (int it = 0; it < 4; ++it) {
    int f = tid + it * 512;
    int row = f >> 5, c4 = (f & 31) * 4;
    const float4 v = *(const float4*)&p.inputs[((size_t)b * N_ + rowbase + row) * 128 + c4];
    float* xr = &lds[P_V + row * 129 + c4];
    xr[0] = v.x; xr[1] = v.y; xr[2] = v.z; xr[3] = v.w;
  }
  __syncthreads();
  {
    int row = tid >> 3, pt = tid & 7;
    float s = 0.f;
    #pragma unroll
    for (int e = 0; e < 16; ++e) s += lds[P_V + row * 129 + pt * 16 + e];
    sl[S_RED + row * 8 + pt] = s;
    __syncthreads();
    if (pt == 0) {
      float m = 0.f;
      #pragma unroll
      for (int q = 0; q < 8; ++q) m += sl[S_RED + row * 8 + q];
      sl[S_QM + row] = m * (1.f / 128.f);
    }
    __syncthreads();
    float m = sl[S_QM + row];
    s = 0.f;
    #pragma unroll
    for (int e = 0; e < 16; ++e) {
      float d = lds[P_V + row * 129 + pt * 16 + e] - m;
      s += d * d;
    }
    sl[S_RED + row * 8 + pt] = s;
    __syncthreads();
    if (pt == 0) {
      float v = 0.f;
      #pragma unroll
      for (int q = 0; q < 8; ++q) v += sl[S_RED + row * 8 + q];
      sl[S_QM + 64 + row] = rsqrtf(v * (1.f / 128.f) + 1e-5f);
    }
    __syncthreads();
    float rs = sl[S_QM + 64 + row];
    #pragma unroll
    for (int e = 0; e < 16; ++e) {
      int c = pt * 16 + e;
      lds[P_V + row * 129 + c] = (lds[P_V + row * 129 + c] - m) * rs * p.gin[c] + p.bin[c];
    }
  }
  __syncthreads();
  // ---- GEMM: k -> kT (LDS), v -> regs -> v (LDS) ----
  {
    int l = tid & 63;
    int w = __builtin_amdgcn_readfirstlane(threadIdx.x >> 6);
    float acc[16], va[16];
    #pragma unroll
    for (int e = 0; e < 16; ++e) { acc[e] = 0.f; va[e] = 0.f; }
    #pragma unroll 4
    for (int kk = 0; kk < 128; ++kk) {
      float a = lds[P_V + l * 129 + kk];
      const float* wr = &p.wt[kk * 256 + w * 16];          // wave-uniform -> s_load
      #pragma unroll
      for (int e = 0; e < 16; ++e) acc[e] = fmaf(a, wr[e], acc[e]);
      const float* wr2 = &p.wt[kk * 256 + 128 + w * 16];
      #pragma unroll
      for (int e = 0; e < 16; ++e) va[e] = fmaf(a, wr2[e], va[e]);
    }
    #pragma unroll
    for (int e = 0; e < 16; ++e) lds[P_KT + (w * 16 + e) * 64 + l] = acc[e];
    __syncthreads();  // all xs reads done before v overwrites the region
    #pragma unroll
    for (int e4 = 0; e4 < 4; ++e4)
      *(float4*)&lds[P_V + l * 128 + w * 16 + e4 * 4] =
          make_float4(va[e4 * 4], va[e4 * 4 + 1], va[e4 * 4 + 2], va[e4 * 4 + 3]);
  }
  // ---- initial slot prep (blocks < 64) ----
  if (blk < 64) {
    __syncthreads();
    int b2 = blk >> 4, i = blk & 15;
    float x = (tid < 256) ? p.slots_in[(size_t)(b2 * NS_ + i) * 256 + tid] : 0.f;
    float m = bRed512((tid < 256) ? x : 0.f, sl + S_RED, tid) * (1.f / 256.f);
    float d = (tid < 256) ? (x - m) : 0.f;
    float var = bRed512(d * d, sl + S_RED, tid) * (1.f / 256.f);
    float rs = rsqrtf(var + 1e-5f);
    if (tid < 256) {
      float slv = d * rs * p.gsl[tid] + p.bsl[tid];
      sl[S_A1S + tid] = slv;
      if (tid < 128) sl[S_HM + tid] = slv;
    }
    __syncthreads();
    slotTail512(p, sl, blk >> 4, blk & 15, tid);
  }
  __threadfence();
  grid.sync();

  // ---- 4 steps ----
  for (int s = 0; s < 4; ++s) {
    // stage this batch's wcoef slice into LDS
    for (int f4 = tid; f4 < 1024; f4 += 512) {
      float4 t = *(const float4*)&p.wcoef[(size_t)b * 4096 + f4 * 4];
      *(float4*)&lds[P_WCO + f4 * 4] = t;
    }
    __syncthreads();
    // phase A: dots + column softmax
    {
      int l = tid & 63;
      int w = tid >> 6;
      int i0 = 2 * w, i1 = 2 * w + 1;
      float d0 = p.cbuf[b * NS_ + i0], d1 = p.cbuf[b * NS_ + i1];
      #pragma unroll 8
      for (int kk = 0; kk < 128; ++kk) {
        float kv = lds[P_KT + kk * 64 + l];
        float4 wv = *(const float4*)&lds[P_WCO + kk * 32 + 4 * w];
        d0 = fmaf(fmaf(wv.y, kv, wv.x), kv, d0);
        d1 = fmaf(fmaf(wv.w, kv, wv.z), kv, d1);
      }
      float e0 = expf(-d0) + EPS_;
      float e1 = expf(-d1) + EPS_;
      lds[P_ESUM + w * 64 + l] = e0 + e1;
      __syncthreads();
      float tot = 0.f;
      #pragma unroll
      for (int q = 0; q < 8; ++q) tot += lds[P_ESUM + q * 64 + l];
      float a0 = e0 / tot, a1v = e1 / tot;
      lds[P_ATT + i0 * 64 + l] = a0;
      lds[P_ATT + i1 * 64 + l] = a1v;
      if (s == 3) {
        p.attnu[(size_t)(b * NS_ + i0) * N_ + rowbase + l] = a0;
        p.attnu[(size_t)(b * NS_ + i1) * N_ + rowbase + l] = a1v;
      }
    }
    __syncthreads();
    // phase B: partial Sv, Sv2, rowsum
    {
      int ii = tid >> 5, dg = tid & 31;
      float av0 = 0, av1 = 0, av2 = 0, av3 = 0, aw0 = 0, aw1 = 0, aw2 = 0, aw3 = 0, rsum = 0;
      #pragma unroll 4
      for (int j = 0; j < 64; ++j) {
        float a = lds[P_ATT + ii * 64 + j];
        const float4 v4 = *(const float4*)&lds[P_V + j * 128 + dg * 4];
        rsum += a;
        float m0 = a * v4.x, m1 = a * v4.y, m2 = a * v4.z, m3 = a * v4.w;
        av0 += m0; av1 += m1; av2 += m2; av3 += m3;
        aw0 = fmaf(m0, v4.x, aw0); aw1 = fmaf(m1, v4.y, aw1);
        aw2 = fmaf(m2, v4.z, aw2); aw3 = fmaf(m3, v4.w, aw3);
      }
      float* pr = &p.part[((size_t)(b * NT_ + jt) * NS_ + ii) * 260];
      *(float4*)&pr[dg * 4] = make_float4(av0, av1, av2, av3);
      *(float4*)&pr[128 + dg * 4] = make_float4(aw0, aw1, aw2, aw3);
      if (dg == 0) pr[256] = rsum;
    }
    __threadfence();
    grid.sync();
    // slot phase
    if (blk < 64) slotUpdate(p, sl, blk >> 4, blk & 15, tid);
    __threadfence();
    grid.sync();
  }

  // ---- out phase ----
  // attn normalize (each block: 256 float4)
  if (tid < 256) {
    int idx4 = blk * 256 + tid;
    int base = idx4 * 4;
    int row = base >> 12;
    float rs = p.rowsum[row];
    float4 v = *(const float4*)&p.attnu[base];
    v.x /= rs; v.y /= rs; v.z /= rs; v.w /= rs;
    *(float4*)&p.out[8192 + base] = v;
  }
  // out MLP partial: bi = blk>>2, chunk c = blk&3
  {
    int bi = blk >> 2, c = blk & 3;
    if (tid < 256) sl[S_ZS + tid] = p.slots[(size_t)bi * 256 + tid];
    __syncthreads();
    {
      int q = tid & 255, kg = tid >> 8;
      float acc = 0.f;
      #pragma unroll 8
      for (int dd = 0; dd < 128; ++dd)
        acc = fmaf(sl[S_ZS + kg * 128 + dd], p.ow1T[(size_t)(kg * 128 + dd) * 1024 + c * 256 + q], acc);
      sl[S_OUTG + kg * 256 + q] = acc;
    }
    __syncthreads();
    if (tid < 256)
      sl[S_A1S + tid] = fmaxf(sl[S_OUTG + tid] + sl[S_OUTG + 256 + tid] + p.ob1[c * 256 + tid], 0.f);
    __syncthreads();
    {
      int qg = tid >> 7, d = tid & 127;
      float dp = 0.f;
      #pragma unroll 8
      for (int qq = 0; qq < 64; ++qq)
        dp = fmaf(sl[S_A1S + qg * 64 + qq], p.ow2T[(size_t)(c * 256 + qg * 64 + qq) * 128 + d], dp);
      sl[S_QPART + qg * 128 + d] = dp;
    }
    __syncthreads();
    if (tid < 128)
      p.opart[(size_t)blk * 128 + tid] = sl[S_QPART + tid] + sl[S_QPART + 128 + tid] +
                                         sl[S_QPART + 256 + tid] + sl[S_QPART + 384 + tid];
  }
  __threadfence();
  grid.sync();
  if (blk < 16) {
    int idx = blk * 512 + tid;
    int bi = idx >> 7, d = idx & 127;
    p.out[idx] = p.ob2[d] + p.opart[(size_t)(bi * 4 + 0) * 128 + d]
                          + p.opart[(size_t)(bi * 4 + 1) * 128 + d]
                          + p.opart[(size_t)(bi * 4 + 2) * 128 + d]
                          + p.opart[(size_t)(bi * 4 + 3) * 128 + d];
  }
}

// ---------- weight transposes + WC build (once) ----------
__global__ __launch_bounds__(256) void tK(
    const float* __restrict__ Wq, const float* __restrict__ Wk, const float* __restrict__ Wv,
    const float* __restrict__ Wih, const float* __restrict__ Whh,
    const float* __restrict__ mW1, const float* __restrict__ mW2,
    const float* __restrict__ oW1, const float* __restrict__ oW2,
    float* __restrict__ ws) {
  int tid = blockIdx.x * blockDim.x + threadIdx.x;
  int stride = gridDim.x * blockDim.x;
  for (int idx = tid; idx < 128 * 256; idx += stride) {
    int kk = idx >> 8, c = idx & 255;
    ws[OFF_WTKV + idx] = (c < 128) ? Wk[c * 128 + kk] : Wv[(c - 128) * 128 + kk];
  }
  for (int idx = tid; idx < 128 * 128; idx += stride) {
    int kk = idx >> 7, c = idx & 127;
    ws[OFF_WQT + idx] = Wq[c * 128 + kk];
  }
  for (int idx = tid; idx < 256 * 512; idx += stride) {
    int dd = idx >> 9, q = idx & 511;
    float v;
    if (dd < 128) {
      v = (q < 384) ? Wih[q * 128 + dd] : 0.f;
    } else {
      int dh = dd - 128;
      if (q < 256) v = Whh[q * 128 + dh];
      else if (q < 384) v = 0.f;
      else v = Whh[(q - 128) * 128 + dh];
    }
    ws[OFF_WC + idx] = v;
  }
  for (int idx = tid; idx < 128 * 512; idx += stride) {
    int kk = idx >> 9, q = idx & 511;
    ws[OFF_MW1T + idx] = mW1[q * 128 + kk];
  }
  for (int idx = tid; idx < 512 * 128; idx += stride) {
    int q = idx >> 7, d = idx & 127;
    ws[OFF_MW2T + idx] = mW2[d * 512 + q];
  }
  for (int idx = tid; idx < 256 * 1024; idx += stride) {
    int dd = idx >> 10, q = idx & 1023;
    ws[OFF_OW1T + idx] = oW1[q * 256 + dd];
  }
  for (int idx = tid; idx < 1024 * 128; idx += stride) {
    int q = idx >> 7, d = idx & 127;
    ws[OFF_OW2T + idx] = oW2[d * 1024 + q];
  }
}

extern "C" void kernel_launch(void* const* d_in, const int* in_sizes, int n_in,
                              void* d_out, int out_size, void* d_ws, size_t ws_size,
                              hipStream_t stream) {
  const float* slots_in = (const float*)d_in[0];
  const float* inputs   = (const float*)d_in[1];
  const float* Wq  = (const float*)d_in[2];
  const float* Wk  = (const float*)d_in[3];
  const float* Wv  = (const float*)d_in[4];
  const float* Wih = (const float*)d_in[5];
  const float* Whh = (const float*)d_in[6];
  const float* bih = (const float*)d_in[7];
  const float* bhh = (const float*)d_in[8];
  const float* mW1 = (const float*)d_in[9];
  const float* mb1 = (const float*)d_in[10];
  const float* mW2 = (const float*)d_in[11];
  const float* mb2 = (const float*)d_in[12];
  const float* g_in  = (const float*)d_in[13];
  const float* be_in = (const float*)d_in[14];
  const float* g_sl  = (const float*)d_in[15];
  const float* be_sl = (const float*)d_in[16];
  const float* g_mu  = (const float*)d_in[17];
  const float* be_mu = (const float*)d_in[18];
  const float* oW1 = (const float*)d_in[19];
  const float* ob1 = (const float*)d_in[20];
  const float* oW2 = (const float*)d_in[21];
  const float* ob2 = (const float*)d_in[22];
  float* ws  = (float*)d_ws;
  float* out = (float*)d_out;
  (void)in_sizes; (void)n_in; (void)out_size; (void)ws_size;

  hipLaunchKernelGGL(tK, dim3(256), dim3(256), 0, stream,
                     Wq, Wk, Wv, Wih, Whh, mW1, mW2, oW1, oW2, ws);

  MegaP p;
  p.slots_in = slots_in; p.inputs = inputs;
  p.wt = ws + OFF_WTKV; p.wqT = ws + OFF_WQT; p.wc = ws + OFF_WC;
  p.mw1T = ws + OFF_MW1T; p.mw2T = ws + OFF_MW2T;
  p.ow1T = ws + OFF_OW1T; p.ow2T = ws + OFF_OW2T;
  p.gin = g_in; p.bin = be_in; p.gsl = g_sl; p.bsl = be_sl; p.gmu = g_mu; p.bmu = be_mu;
  p.bih = bih; p.bhh = bhh; p.mb1 = mb1; p.mb2 = mb2; p.ob1 = ob1; p.ob2 = ob2;
  p.wcoef = ws + OFF_WCOEF; p.cbuf = ws + OFF_C; p.part = ws + OFF_PART;
  p.rowsum = ws + OFF_RS; p.slots = ws + OFF_SLOTS;
  p.attnu = ws + OFF_ATTNU; p.opart = ws + OFF_OPART; p.out = out;

  (void)hipFuncSetAttribute((const void*)megaK,
                            hipFuncAttributeMaxDynamicSharedMemorySize, LDS_BYTES);
  void* args[] = { &p };
  (void)hipLaunchCooperativeKernel((const void*)megaK, dim3(256), dim3(512),
                                   args, LDS_BYTES, stream);
}

// Round 4
// 396.122 us; speedup vs baseline: 2.4625x; 2.4625x over previous
//
#include <hip/hip_runtime.h>
#include <math.h>

#define B_ 4
#define N_ 4096
#define D_ 128
#define NS_ 16
#define NT_ 64
#define SCALE_ 0.08838834764831843f
#define EPS_ 1e-10f

// workspace offsets (floats)
#define OFF_K      ((size_t)0)
#define OFF_V      (OFF_K + (size_t)B_*N_*D_)
#define OFF_WTKV   (OFF_V + (size_t)B_*N_*D_)
#define OFF_SLOTS  (OFF_WTKV + 128*256)
#define OFF_MU     (OFF_SLOTS + (size_t)B_*NS_*256)
#define OFF_WCOEF  (OFF_MU + (size_t)B_*NS_*128)
#define OFF_C      (OFF_WCOEF + (size_t)B_*128*32)
#define OFF_RS     (OFF_C + 64)
#define OFF_TICK   (OFF_RS + 64)
#define OFF_PART   (OFF_TICK + 16)
#define OFF_ATTNU  (OFF_PART + (size_t)B_*NT_*NS_*260)

// slot scratch offsets (floats, all 16B-aligned)
#define S_ZS    0
#define S_S2    256
#define S_GI    384
#define S_GH    768
#define S_UU    1152
#define S_H2    1280
#define S_A1S   1408
#define S_SNEW  1920
#define S_QM    2176
#define S_QL    2304
#define S_RED   2432
#define S_PPART 2944
#define S_QPART 3456
#define S_TOT   3968

struct PP {
  const float* kb; const float* vb;
  float* wcoef; float* cbuf;
  float* part; float* attnu;
  int* tickets;
  const float* Wih; const float* Whh; const float* bih; const float* bhh;
  const float* mW1; const float* mb1; const float* mW2; const float* mb2;
  const float* gmu; const float* bmu; const float* gsl; const float* bsl;
  const float* Wq;
  float* slots; float* mu; float* rowsum;
  int last; int step;
};

__device__ __forceinline__ float bRed512(float v, float* red, int tid) {
  red[tid] = v;
  __syncthreads();
  if (tid < 256) red[tid] += red[tid + 256];
  __syncthreads();
  if (tid < 128) red[tid] += red[tid + 128];
  __syncthreads();
  if (tid < 64) {
    float x = red[tid] + red[tid + 64];
    #pragma unroll
    for (int off = 32; off > 0; off >>= 1) x += __shfl_down(x, off, 64);
    if (tid == 0) red[0] = x;
  }
  __syncthreads();
  float r = red[0];
  __syncthreads();
  return r;
}

// input: sl[S_A1S..S_A1S+255] = LN'd slot row; writes wcoef/cbuf for (b,i)
__device__ __forceinline__ void slotTailV(float* sl, int b, int i, int tid,
    const float* __restrict__ Wq, float* wcoef, float* cbuf) {
  {
    int half = tid >> 8;        // K half (0/1 of 128)
    int rest = tid & 255;       // 256 outputs: 0..127 qm, 128..255 ql
    int wh = rest >> 7;
    int o = rest & 127;
    const float4* s4 = (const float4*)&sl[S_A1S + wh * 128 + half * 64];
    const float4* w4 = (const float4*)&Wq[(size_t)o * 128 + half * 64];
    float acc = 0.f;
    #pragma unroll
    for (int c = 0; c < 16; ++c) {
      float4 wv = w4[c], svv = s4[c];
      acc = fmaf(wv.x, svv.x, acc); acc = fmaf(wv.y, svv.y, acc);
      acc = fmaf(wv.z, svv.z, acc); acc = fmaf(wv.w, svv.w, acc);
    }
    sl[S_QPART + half * 256 + rest] = acc;
  }
  __syncthreads();
  if (tid < 256) {
    float q = sl[S_QPART + tid] + sl[S_QPART + 256 + tid];
    if (tid < 128) sl[S_QM + tid] = q; else sl[S_QL + (tid - 128)] = q;
  }
  __syncthreads();
  float cp = 0.f;
  if (tid < 128) {
    float iv = expf(-2.f * sl[S_QL + tid]);
    float a1 = SCALE_ * iv;
    float a2 = -2.f * SCALE_ * iv * sl[S_QM + tid];
    float* wrow = &wcoef[((size_t)b * 128 + tid) * 32];
    wrow[2 * i] = a2;
    wrow[2 * i + 1] = a1;
    cp = SCALE_ * iv * sl[S_QM + tid] * sl[S_QM + tid];
  }
  float ctot = bRed512(cp, sl + S_RED, tid);
  if (tid == 0) cbuf[b * NS_ + i] = ctot;
}

__device__ void slotUpdateV(float* sl, int b, int i, int tid, const PP& p) {
  size_t pbase = ((size_t)(b * NT_) * NS_ + i) * 260;
  const size_t pstr = (size_t)NS_ * 260;
  {
    int th = tid >> 8, e = tid & 255;
    float s = 0.f;
    #pragma unroll 8
    for (int t = 0; t < 32; ++t) s += p.part[pbase + (size_t)(th * 32 + t) * pstr + e];
    sl[S_PPART + th * 256 + e] = s;
  }
  float rp = (tid < 64) ? p.part[pbase + (size_t)tid * pstr + 256] : 0.f;
  float rt = bRed512(rp, sl + S_RED, tid);  // internal syncs cover ppart visibility
  if (tid == 0) p.rowsum[b * NS_ + i] = rt;
  if (tid < 128) sl[S_ZS + tid] = (sl[S_PPART + tid] + sl[S_PPART + 256 + tid]) / rt;
  else if (tid < 256) sl[S_S2 + tid - 128] = (sl[S_PPART + tid] + sl[S_PPART + 256 + tid]) / rt;
  else if (tid < 384) sl[S_ZS + tid - 128] = p.mu[(size_t)(b * NS_ + i) * 128 + (tid - 256)];
  __syncthreads();
  // GRU gates: gi/gh for 384 gates, row-major W with float4
  if (tid < 384) {
    const float4* wI = (const float4*)&p.Wih[(size_t)tid * 128];
    const float4* wH = (const float4*)&p.Whh[(size_t)tid * 128];
    const float4* x4 = (const float4*)&sl[S_ZS];
    const float4* h4 = (const float4*)&sl[S_ZS + 128];
    float aI = 0.f, aH = 0.f;
    #pragma unroll 8
    for (int c = 0; c < 32; ++c) {
      float4 wi = wI[c], xv = x4[c];
      aI = fmaf(wi.x, xv.x, aI); aI = fmaf(wi.y, xv.y, aI);
      aI = fmaf(wi.z, xv.z, aI); aI = fmaf(wi.w, xv.w, aI);
      float4 wh = wH[c], hv = h4[c];
      aH = fmaf(wh.x, hv.x, aH); aH = fmaf(wh.y, hv.y, aH);
      aH = fmaf(wh.z, hv.z, aH); aH = fmaf(wh.w, hv.w, aH);
    }
    sl[S_GI + tid] = aI + p.bih[tid];
    sl[S_GH + tid] = aH + p.bhh[tid];
  }
  __syncthreads();
  if (tid < 128) {
    float r = 1.f / (1.f + expf(-(sl[S_GI + tid] + sl[S_GH + tid])));
    float z = 1.f / (1.f + expf(-(sl[S_GI + 128 + tid] + sl[S_GH + 128 + tid])));
    float nn = tanhf(sl[S_GI + 256 + tid] + r * sl[S_GH + 256 + tid]);
    sl[S_UU + tid] = (1.f - z) * nn + z * sl[S_ZS + 128 + tid];
  }
  __syncthreads();
  // LN(u)
  float uv = (tid < 128) ? sl[S_UU + tid] : 0.f;
  float m = bRed512(uv, sl + S_RED, tid) * (1.f / 128.f);
  float dv = (tid < 128) ? (sl[S_UU + tid] - m) : 0.f;
  float var = bRed512(dv * dv, sl + S_RED, tid) * (1.f / 128.f);
  float rsq = rsqrtf(var + 1e-5f);
  if (tid < 128) sl[S_H2 + tid] = dv * rsq * p.gmu[tid] + p.bmu[tid];
  __syncthreads();
  // MLP up: hidden = tid, mW1 row contiguous
  {
    const float4* w4 = (const float4*)&p.mW1[(size_t)tid * 128];
    const float4* h4 = (const float4*)&sl[S_H2];
    float a = p.mb1[tid];
    #pragma unroll 8
    for (int c = 0; c < 32; ++c) {
      float4 wv = w4[c], hv = h4[c];
      a = fmaf(wv.x, hv.x, a); a = fmaf(wv.y, hv.y, a);
      a = fmaf(wv.z, hv.z, a); a = fmaf(wv.w, hv.w, a);
    }
    sl[S_A1S + tid] = fmaxf(a, 0.f);
  }
  __syncthreads();
  // MLP down: K-split 4, mW2 row contiguous
  {
    int qg = tid >> 7, d = tid & 127;
    const float4* a4 = (const float4*)&sl[S_A1S + qg * 128];
    const float4* w4 = (const float4*)&p.mW2[(size_t)d * 512 + qg * 128];
    float dp = 0.f;
    #pragma unroll 8
    for (int c = 0; c < 32; ++c) {
      float4 wv = w4[c], av = a4[c];
      dp = fmaf(wv.x, av.x, dp); dp = fmaf(wv.y, av.y, dp);
      dp = fmaf(wv.z, av.z, dp); dp = fmaf(wv.w, av.w, dp);
    }
    sl[S_QPART + qg * 128 + d] = dp;
  }
  __syncthreads();
  if (tid < 128) {
    float o = p.mb2[tid] + sl[S_QPART + tid] + sl[S_QPART + 128 + tid] +
              sl[S_QPART + 256 + tid] + sl[S_QPART + 384 + tid];
    float uf = sl[S_UU + tid] + o;
    float xsv = sl[S_ZS + tid];
    float arg = sl[S_S2 + tid] - 2.f * uf * xsv + uf * uf + EPS_;
    float lsv = 0.5f * logf(fmaxf(arg, 1e-30f));
    sl[S_SNEW + tid] = uf;
    sl[S_SNEW + 128 + tid] = lsv;
    size_t so = (size_t)(b * NS_ + i) * 256;
    p.slots[so + tid] = uf;
    p.slots[so + 128 + tid] = lsv;
  }
  __syncthreads();
  // next-step LN over new slot row
  float x = (tid < 256) ? sl[S_SNEW + tid] : 0.f;
  float m2 = bRed512(x, sl + S_RED, tid) * (1.f / 256.f);
  float d2 = (tid < 256) ? (sl[S_SNEW + tid] - m2) : 0.f;
  float v2 = bRed512(d2 * d2, sl + S_RED, tid) * (1.f / 256.f);
  float rs2 = rsqrtf(v2 + 1e-5f);
  if (tid < 256) {
    float slv = d2 * rs2 * p.gsl[tid] + p.bsl[tid];
    sl[S_A1S + tid] = slv;
    if (tid < 128) p.mu[(size_t)(b * NS_ + i) * 128 + tid] = slv;
  }
  __syncthreads();
  slotTailV(sl, b, i, tid, p.Wq, p.wcoef, p.cbuf);
}

// ---------- tK: k/v weight transpose + ticket zeroing (every call) ----------
__global__ __launch_bounds__(256) void tK(const float* __restrict__ Wk,
    const float* __restrict__ Wv, float* __restrict__ ws, int* tickets) {
  int tid = blockIdx.x * blockDim.x + threadIdx.x;
  if (tid < 16) tickets[tid] = 0;
  int stride = gridDim.x * blockDim.x;
  for (int idx = tid; idx < 128 * 256; idx += stride) {
    int kk = idx >> 8, c = idx & 255;
    ws[OFF_WTKV + idx] = (c < 128) ? Wk[c * 128 + kk] : Wv[(c - 128) * 128 + kk];
  }
}

// ---------- kvK: LN(inputs)+k/v GEMM (blocks 0..255) + initial slot prep (256..319) ----------
__global__ __launch_bounds__(512) void kvK(const float* __restrict__ inp,
    const float* __restrict__ wt, const float* __restrict__ gin, const float* __restrict__ bin,
    const float* __restrict__ slots_in, const float* __restrict__ gsl, const float* __restrict__ bsl,
    const float* __restrict__ Wq,
    float* __restrict__ kb, float* __restrict__ vb,
    float* __restrict__ mu, float* wcoef, float* cbuf) {
  __shared__ __align__(16) float shm[8896];
  int tid = threadIdx.x;
  int blk = blockIdx.x;
  if (blk < 256) {
    float* xs = shm;            // [64][129]
    float* red = shm + 8256;    // [64][8]
    float* mrow = shm + 8768;   // 64
    float* rrow = shm + 8832;   // 64
    int rowbase = blk * 64;
    #pragma unroll
    for (int it = 0; it < 4; ++it) {
      int f = tid + it * 512;
      int row = f >> 5, c4 = (f & 31) * 4;
      const float4 v = *(const float4*)&inp[(size_t)(rowbase + row) * 128 + c4];
      float* xr = &xs[row * 129 + c4];
      xr[0] = v.x; xr[1] = v.y; xr[2] = v.z; xr[3] = v.w;
    }
    __syncthreads();
    int row = tid >> 3, part = tid & 7;
    float s = 0.f;
    #pragma unroll
    for (int e = 0; e < 16; ++e) s += xs[row * 129 + part * 16 + e];
    red[row * 8 + part] = s;
    __syncthreads();
    if (part == 0) {
      float m = 0.f;
      #pragma unroll
      for (int q = 0; q < 8; ++q) m += red[row * 8 + q];
      mrow[row] = m * (1.f / 128.f);
    }
    __syncthreads();
    float m = mrow[row];
    s = 0.f;
    #pragma unroll
    for (int e = 0; e < 16; ++e) { float d = xs[row * 129 + part * 16 + e] - m; s += d * d; }
    red[row * 8 + part] = s;
    __syncthreads();
    if (part == 0) {
      float v = 0.f;
      #pragma unroll
      for (int q = 0; q < 8; ++q) v += red[row * 8 + q];
      rrow[row] = rsqrtf(v * (1.f / 128.f) + 1e-5f);
    }
    __syncthreads();
    float rs = rrow[row];
    #pragma unroll
    for (int e = 0; e < 16; ++e) {
      int c = part * 16 + e;
      xs[row * 129 + c] = (xs[row * 129 + c] - m) * rs * gin[c] + bin[c];
    }
    __syncthreads();
    int l = tid & 63;
    int w = __builtin_amdgcn_readfirstlane(threadIdx.x >> 6);
    for (int pass = 0; pass < 2; ++pass) {
      int cbase = pass * 128 + w * 16;
      float acc[16];
      #pragma unroll
      for (int e = 0; e < 16; ++e) acc[e] = 0.f;
      #pragma unroll 4
      for (int kk = 0; kk < 128; ++kk) {
        float a = xs[l * 129 + kk];
        const float* wr = &wt[kk * 256 + cbase];  // wave-uniform -> s_load
        #pragma unroll
        for (int e = 0; e < 16; ++e) acc[e] = fmaf(a, wr[e], acc[e]);
      }
      float* outp = (cbase < 128) ? kb : vb;
      int col = cbase & 127;
      size_t o = (size_t)(rowbase + l) * 128 + col;
      #pragma unroll
      for (int e4 = 0; e4 < 4; ++e4)
        *(float4*)&outp[o + e4 * 4] =
            make_float4(acc[e4 * 4], acc[e4 * 4 + 1], acc[e4 * 4 + 2], acc[e4 * 4 + 3]);
    }
  } else {
    float* sl = shm;
    int sb = blk - 256;
    int b2 = sb >> 4, i = sb & 15;
    float x = (tid < 256) ? slots_in[(size_t)(b2 * NS_ + i) * 256 + tid] : 0.f;
    float m = bRed512(x, sl + S_RED, tid) * (1.f / 256.f);
    float d = (tid < 256) ? (x - m) : 0.f;
    float var = bRed512(d * d, sl + S_RED, tid) * (1.f / 256.f);
    float rs = rsqrtf(var + 1e-5f);
    if (tid < 256) {
      float slv = d * rs * gsl[tid] + bsl[tid];
      sl[S_A1S + tid] = slv;
      if (tid < 128) mu[(size_t)(b2 * NS_ + i) * 128 + tid] = slv;
    }
    __syncthreads();
    slotTailV(sl, b2, i, tid, Wq, wcoef, cbuf);
  }
}

// ---------- pK: token pass + fused last-arriver slot update ----------
__global__ __launch_bounds__(512) void pK(PP p) {
  __shared__ __align__(16) float shm[8448 + 1056 + 512 + S_TOT];
  __shared__ int tickL;
  float* buf = shm;                 // kT[128][66] then v[64][132]
  float* a1s = shm + 8448;          // [16][66]
  float* esum = shm + 9504;         // [8][64]
  float* sl = shm + 10016;          // slot scratch
  int tid = threadIdx.x;
  int jt = blockIdx.x, b = blockIdx.y;
  size_t jrow = (size_t)(b * N_ + jt * 64);
  // stage K tile transposed
  for (int f = tid; f < 2048; f += 512) {
    int row = f >> 5, c4 = (f & 31) * 4;
    float4 kv = *(const float4*)&p.kb[(jrow + row) * 128 + c4];
    buf[(c4 + 0) * 66 + row] = kv.x;
    buf[(c4 + 1) * 66 + row] = kv.y;
    buf[(c4 + 2) * 66 + row] = kv.z;
    buf[(c4 + 3) * 66 + row] = kv.w;
  }
  __syncthreads();
  // phase A
  {
    int l = tid & 63;
    int w = __builtin_amdgcn_readfirstlane(threadIdx.x >> 6);
    int i0 = 2 * w, i1 = 2 * w + 1;
    const float* wb = &p.wcoef[(size_t)b * 128 * 32];
    float d0 = p.cbuf[b * NS_ + i0], d1 = p.cbuf[b * NS_ + i1];
    #pragma unroll 8
    for (int kk = 0; kk < 128; ++kk) {
      float kv = buf[kk * 66 + l];
      float4 wv = *(const float4*)&wb[kk * 32 + 4 * w];  // wave-uniform -> s_load
      d0 = fmaf(fmaf(wv.y, kv, wv.x), kv, d0);
      d1 = fmaf(fmaf(wv.w, kv, wv.z), kv, d1);
    }
    float e0 = expf(-d0) + EPS_;
    float e1 = expf(-d1) + EPS_;
    esum[w * 64 + l] = e0 + e1;
    __syncthreads();
    float tot = 0.f;
    #pragma unroll
    for (int q = 0; q < 8; ++q) tot += esum[q * 64 + l];
    float a0 = e0 / tot, a1v = e1 / tot;
    a1s[i0 * 66 + l] = a0;
    a1s[i1 * 66 + l] = a1v;
    if (p.last) {
      p.attnu[(size_t)(b * NS_ + i0) * N_ + jt * 64 + l] = a0;
      p.attnu[(size_t)(b * NS_ + i1) * N_ + jt * 64 + l] = a1v;
    }
  }
  __syncthreads();
  // stage V tile (reuse buf)
  for (int f = tid; f < 2048; f += 512) {
    int row = f >> 5, c4 = (f & 31) * 4;
    float4 vv = *(const float4*)&p.vb[(jrow + row) * 128 + c4];
    *(float4*)&buf[row * 132 + c4] = vv;
  }
  __syncthreads();
  // phase B
  {
    int ii = tid >> 5, dg = tid & 31;
    float av0 = 0, av1 = 0, av2 = 0, av3 = 0, aw0 = 0, aw1 = 0, aw2 = 0, aw3 = 0, rsum = 0;
    #pragma unroll 4
    for (int j = 0; j < 64; ++j) {
      float a = a1s[ii * 66 + j];
      const float4 v4 = *(const float4*)&buf[j * 132 + dg * 4];
      rsum += a;
      float m0 = a * v4.x, m1 = a * v4.y, m2 = a * v4.z, m3 = a * v4.w;
      av0 += m0; av1 += m1; av2 += m2; av3 += m3;
      aw0 = fmaf(m0, v4.x, aw0); aw1 = fmaf(m1, v4.y, aw1);
      aw2 = fmaf(m2, v4.z, aw2); aw3 = fmaf(m3, v4.w, aw3);
    }
    float* pr = &p.part[((size_t)(b * NT_ + jt) * NS_ + ii) * 260];
    *(float4*)&pr[dg * 4] = make_float4(av0, av1, av2, av3);
    *(float4*)&pr[128 + dg * 4] = make_float4(aw0, aw1, aw2, aw3);
    if (dg == 0) pr[256] = rsum;
  }
  __syncthreads();
  // ticket: last 16 arrivers per batch each update one slot
  if (tid == 0) {
    __threadfence();  // release: wbL2 so part writes are visible cross-XCD
    tickL = atomicAdd(&p.tickets[p.step * 4 + b], 1);
  }
  __syncthreads();
  int t = tickL;
  if (t < 48) return;
  int i = t - 48;
  if (tid == 0) {
    while (__hip_atomic_load(&p.tickets[p.step * 4 + b], __ATOMIC_ACQUIRE,
                             __HIP_MEMORY_SCOPE_AGENT) < 64)
      __builtin_amdgcn_s_sleep(8);
  }
  __syncthreads();
  __threadfence();  // acquire: invalidate caches so part reads are fresh
  slotUpdateV(sl, b, i, tid, p);
}

// ---------- oK: out MLP (blocks 0..63) + attn normalize (64..191) ----------
__global__ __launch_bounds__(512) void oK(const float* slots,
    const float* __restrict__ oW1, const float* __restrict__ ob1,
    const float* __restrict__ oW2, const float* __restrict__ ob2,
    const float* attnu, const float* rowsum, float* __restrict__ out) {
  int blk = blockIdx.x, tid = threadIdx.x;
  if (blk >= 64) {
    int idx4 = (blk - 64) * 512 + tid;  // 128 blocks * 512 = 65536 float4
    int base = idx4 * 4;
    int row = base >> 12;
    float rs = rowsum[row];
    float4 v = *(const float4*)&attnu[base];
    v.x /= rs; v.y /= rs; v.z /= rs; v.w /= rs;
    *(float4*)&out[8192 + base] = v;
    return;
  }
  __shared__ __align__(16) float sv[256];
  __shared__ __align__(16) float h1[1024];
  __shared__ float dpart[4][128];
  if (tid < 256) sv[tid] = slots[(size_t)blk * 256 + tid];
  __syncthreads();
  {
    const float4* s4 = (const float4*)sv;
    #pragma unroll
    for (int h = 0; h < 2; ++h) {
      int q = tid + h * 512;
      const float4* w4 = (const float4*)&oW1[(size_t)q * 256];
      float a = ob1[q];
      #pragma unroll 8
      for (int c = 0; c < 64; ++c) {
        float4 wv = w4[c], xv = s4[c];
        a = fmaf(wv.x, xv.x, a); a = fmaf(wv.y, xv.y, a);
        a = fmaf(wv.z, xv.z, a); a = fmaf(wv.w, xv.w, a);
      }
      h1[q] = fmaxf(a, 0.f);
    }
  }
  __syncthreads();
  {
    int qg = tid >> 7, d = tid & 127;
    const float4* h4 = (const float4*)&h1[qg * 256];
    const float4* w4 = (const float4*)&oW2[(size_t)d * 1024 + qg * 256];
    float dp = 0.f;
    #pragma unroll 8
    for (int c = 0; c < 64; ++c) {
      float4 wv = w4[c], hv = h4[c];
      dp = fmaf(wv.x, hv.x, dp); dp = fmaf(wv.y, hv.y, dp);
      dp = fmaf(wv.z, hv.z, dp); dp = fmaf(wv.w, hv.w, dp);
    }
    dpart[qg][d] = dp;
  }
  __syncthreads();
  if (tid < 128)
    out[(size_t)blk * 128 + tid] =
        ob2[tid] + dpart[0][tid] + dpart[1][tid] + dpart[2][tid] + dpart[3][tid];
}

extern "C" void kernel_launch(void* const* d_in, const int* in_sizes, int n_in,
                              void* d_out, int out_size, void* d_ws, size_t ws_size,
                              hipStream_t stream) {
  const float* slots_in = (const float*)d_in[0];
  const float* inputs   = (const float*)d_in[1];
  const float* Wq  = (const float*)d_in[2];
  const float* Wk  = (const float*)d_in[3];
  const float* Wv  = (const float*)d_in[4];
  const float* Wih = (const float*)d_in[5];
  const float* Whh = (const float*)d_in[6];
  const float* bih = (const float*)d_in[7];
  const float* bhh = (const float*)d_in[8];
  const float* mW1 = (const float*)d_in[9];
  const float* mb1 = (const float*)d_in[10];
  const float* mW2 = (const float*)d_in[11];
  const float* mb2 = (const float*)d_in[12];
  const float* g_in  = (const float*)d_in[13];
  const float* be_in = (const float*)d_in[14];
  const float* g_sl  = (const float*)d_in[15];
  const float* be_sl = (const float*)d_in[16];
  const float* g_mu  = (const float*)d_in[17];
  const float* be_mu = (const float*)d_in[18];
  const float* oW1 = (const float*)d_in[19];
  const float* ob1 = (const float*)d_in[20];
  const float* oW2 = (const float*)d_in[21];
  const float* ob2 = (const float*)d_in[22];
  float* ws  = (float*)d_ws;
  float* out = (float*)d_out;
  (void)in_sizes; (void)n_in; (void)out_size; (void)ws_size;
  int* tickets = (int*)(ws + OFF_TICK);

  hipLaunchKernelGGL(tK, dim3(64), dim3(256), 0, stream, Wk, Wv, ws, tickets);
  hipLaunchKernelGGL(kvK, dim3(320), dim3(512), 0, stream,
                     inputs, ws + OFF_WTKV, g_in, be_in,
                     slots_in, g_sl, be_sl, Wq,
                     ws + OFF_K, ws + OFF_V, ws + OFF_MU, ws + OFF_WCOEF, ws + OFF_C);

  PP p;
  p.kb = ws + OFF_K; p.vb = ws + OFF_V;
  p.wcoef = ws + OFF_WCOEF; p.cbuf = ws + OFF_C;
  p.part = ws + OFF_PART; p.attnu = ws + OFF_ATTNU;
  p.tickets = tickets;
  p.Wih = Wih; p.Whh = Whh; p.bih = bih; p.bhh = bhh;
  p.mW1 = mW1; p.mb1 = mb1; p.mW2 = mW2; p.mb2 = mb2;
  p.gmu = g_mu; p.bmu = be_mu; p.gsl = g_sl; p.bsl = be_sl;
  p.Wq = Wq;
  p.slots = ws + OFF_SLOTS; p.mu = ws + OFF_MU; p.rowsum = ws + OFF_RS;
  for (int s = 0; s < 4; ++s) {
    p.last = (s == 3) ? 1 : 0;
    p.step = s;
    hipLaunchKernelGGL(pK, dim3(64, 4), dim3(512), 0, stream, p);
  }
  hipLaunchKernelGGL(oK, dim3(192), dim3(512), 0, stream,
                     ws + OFF_SLOTS, oW1, ob1, oW2, ob2,
                     ws + OFF_ATTNU, ws + OFF_RS, out);
}

// Round 5
// 300.386 us; speedup vs baseline: 3.2474x; 1.3187x over previous
//
#include <hip/hip_runtime.h>
#include <math.h>

#define B_ 4
#define N_ 4096
#define D_ 128
#define NS_ 16
#define NT_ 64
#define SCALE_ 0.08838834764831843f
#define EPS_ 1e-10f

// workspace offsets (floats)
#define OFF_K      ((size_t)0)
#define OFF_V      (OFF_K + (size_t)B_*N_*D_)
#define OFF_WTKV   (OFF_V + (size_t)B_*N_*D_)
#define OFF_MU     (OFF_WTKV + 128*256)
#define OFF_WCOEF  (OFF_MU + (size_t)B_*NS_*128)
#define OFF_C      (OFF_WCOEF + (size_t)B_*128*32)
#define OFF_PART   (OFF_C + 64)
#define OFF_ATTNU  (OFF_PART + (size_t)B_*NT_*NS_*260)

// slot scratch offsets (floats, all 16B-aligned)
#define S_ZS    0
#define S_S2    256
#define S_GI    384
#define S_GH    768
#define S_UU    1152
#define S_H2    1280
#define S_A1S   1408
#define S_SNEW  1920
#define S_QM    2176
#define S_QL    2304
#define S_RED   2432
#define S_PPART 2944
#define S_QPART 3456
#define S_TOT   3968

// slot-phase weights bundle
struct SW {
  const float* Wih; const float* Whh; const float* bih; const float* bhh;
  const float* mW1; const float* mb1; const float* mW2; const float* mb2;
  const float* gmu; const float* bmu; const float* gsl; const float* bsl;
  const float* Wq;
};

__device__ __forceinline__ float bRed512(float v, float* red, int tid) {
  red[tid] = v;
  __syncthreads();
  if (tid < 256) red[tid] += red[tid + 256];
  __syncthreads();
  if (tid < 128) red[tid] += red[tid + 128];
  __syncthreads();
  if (tid < 64) {
    float x = red[tid] + red[tid + 64];
    #pragma unroll
    for (int off = 32; off > 0; off >>= 1) x += __shfl_down(x, off, 64);
    if (tid == 0) red[0] = x;
  }
  __syncthreads();
  float r = red[0];
  __syncthreads();
  return r;
}

// input: sl[S_A1S..+255] = LN'd slot row; writes wcoef/cbuf for (b,i)
__device__ __forceinline__ void slotTailV(float* sl, int b, int i, int tid,
    const float* __restrict__ Wq, float* wcoef, float* cbuf) {
  {
    int half = tid >> 8;
    int rest = tid & 255;
    int wh = rest >> 7;
    int o = rest & 127;
    const float4* s4 = (const float4*)&sl[S_A1S + wh * 128 + half * 64];
    const float4* w4 = (const float4*)&Wq[(size_t)o * 128 + half * 64];
    float acc = 0.f;
    #pragma unroll
    for (int c = 0; c < 16; ++c) {
      float4 wv = w4[c], svv = s4[c];
      acc = fmaf(wv.x, svv.x, acc); acc = fmaf(wv.y, svv.y, acc);
      acc = fmaf(wv.z, svv.z, acc); acc = fmaf(wv.w, svv.w, acc);
    }
    sl[S_QPART + half * 256 + rest] = acc;
  }
  __syncthreads();
  if (tid < 256) {
    float q = sl[S_QPART + tid] + sl[S_QPART + 256 + tid];
    if (tid < 128) sl[S_QM + tid] = q; else sl[S_QL + (tid - 128)] = q;
  }
  __syncthreads();
  float cp = 0.f;
  if (tid < 128) {
    float iv = expf(-2.f * sl[S_QL + tid]);
    float a1 = SCALE_ * iv;
    float a2 = -2.f * SCALE_ * iv * sl[S_QM + tid];
    float* wrow = &wcoef[((size_t)b * 128 + tid) * 32];
    wrow[2 * i] = a2;
    wrow[2 * i + 1] = a1;
    cp = SCALE_ * iv * sl[S_QM + tid] * sl[S_QM + tid];
  }
  float ctot = bRed512(cp, sl + S_RED, tid);
  if (tid == 0) cbuf[b * NS_ + i] = ctot;
}

// FINAL=0: full update incl. next-step prep (mu/wcoef/cbuf). FINAL=1: stop at snew.
template <int FINAL>
__device__ void slotUpdateV(float* sl, int b, int i, int tid,
    const float* __restrict__ part, float* mu, float* wcoef, float* cbuf, SW w) {
  size_t pbase = ((size_t)(b * NT_) * NS_ + i) * 260;
  const size_t pstr = (size_t)NS_ * 260;
  {
    int th = tid >> 8, e = tid & 255;
    float s = 0.f;
    #pragma unroll 8
    for (int t = 0; t < 32; ++t) s += part[pbase + (size_t)(th * 32 + t) * pstr + e];
    sl[S_PPART + th * 256 + e] = s;
  }
  float rp = (tid < 64) ? part[pbase + (size_t)tid * pstr + 256] : 0.f;
  float rt = bRed512(rp, sl + S_RED, tid);  // internal syncs cover ppart visibility
  if (tid < 128) sl[S_ZS + tid] = (sl[S_PPART + tid] + sl[S_PPART + 256 + tid]) / rt;
  else if (tid < 256) sl[S_S2 + tid - 128] = (sl[S_PPART + tid] + sl[S_PPART + 256 + tid]) / rt;
  else if (tid < 384) sl[S_ZS + tid - 128] = mu[(size_t)(b * NS_ + i) * 128 + (tid - 256)];
  __syncthreads();
  // GRU gates, row-major W with float4
  if (tid < 384) {
    const float4* wI = (const float4*)&w.Wih[(size_t)tid * 128];
    const float4* wH = (const float4*)&w.Whh[(size_t)tid * 128];
    const float4* x4 = (const float4*)&sl[S_ZS];
    const float4* h4 = (const float4*)&sl[S_ZS + 128];
    float aI = 0.f, aH = 0.f;
    #pragma unroll 8
    for (int c = 0; c < 32; ++c) {
      float4 wi = wI[c], xv = x4[c];
      aI = fmaf(wi.x, xv.x, aI); aI = fmaf(wi.y, xv.y, aI);
      aI = fmaf(wi.z, xv.z, aI); aI = fmaf(wi.w, xv.w, aI);
      float4 wh = wH[c], hv = h4[c];
      aH = fmaf(wh.x, hv.x, aH); aH = fmaf(wh.y, hv.y, aH);
      aH = fmaf(wh.z, hv.z, aH); aH = fmaf(wh.w, hv.w, aH);
    }
    sl[S_GI + tid] = aI + w.bih[tid];
    sl[S_GH + tid] = aH + w.bhh[tid];
  }
  __syncthreads();
  if (tid < 128) {
    float r = 1.f / (1.f + expf(-(sl[S_GI + tid] + sl[S_GH + tid])));
    float z = 1.f / (1.f + expf(-(sl[S_GI + 128 + tid] + sl[S_GH + 128 + tid])));
    float nn = tanhf(sl[S_GI + 256 + tid] + r * sl[S_GH + 256 + tid]);
    sl[S_UU + tid] = (1.f - z) * nn + z * sl[S_ZS + 128 + tid];
  }
  __syncthreads();
  // LN(u)
  float uv = (tid < 128) ? sl[S_UU + tid] : 0.f;
  float m = bRed512(uv, sl + S_RED, tid) * (1.f / 128.f);
  float dv = (tid < 128) ? (sl[S_UU + tid] - m) : 0.f;
  float var = bRed512(dv * dv, sl + S_RED, tid) * (1.f / 128.f);
  float rsq = rsqrtf(var + 1e-5f);
  if (tid < 128) sl[S_H2 + tid] = dv * rsq * w.gmu[tid] + w.bmu[tid];
  __syncthreads();
  // MLP up
  {
    const float4* w4 = (const float4*)&w.mW1[(size_t)tid * 128];
    const float4* h4 = (const float4*)&sl[S_H2];
    float a = w.mb1[tid];
    #pragma unroll 8
    for (int c = 0; c < 32; ++c) {
      float4 wv = w4[c], hv = h4[c];
      a = fmaf(wv.x, hv.x, a); a = fmaf(wv.y, hv.y, a);
      a = fmaf(wv.z, hv.z, a); a = fmaf(wv.w, hv.w, a);
    }
    sl[S_A1S + tid] = fmaxf(a, 0.f);
  }
  __syncthreads();
  // MLP down, K split 4
  {
    int qg = tid >> 7, d = tid & 127;
    const float4* a4 = (const float4*)&sl[S_A1S + qg * 128];
    const float4* w4 = (const float4*)&w.mW2[(size_t)d * 512 + qg * 128];
    float dp = 0.f;
    #pragma unroll 8
    for (int c = 0; c < 32; ++c) {
      float4 wv = w4[c], av = a4[c];
      dp = fmaf(wv.x, av.x, dp); dp = fmaf(wv.y, av.y, dp);
      dp = fmaf(wv.z, av.z, dp); dp = fmaf(wv.w, av.w, dp);
    }
    sl[S_QPART + qg * 128 + d] = dp;
  }
  __syncthreads();
  if (tid < 128) {
    float o = w.mb2[tid] + sl[S_QPART + tid] + sl[S_QPART + 128 + tid] +
              sl[S_QPART + 256 + tid] + sl[S_QPART + 384 + tid];
    float uf = sl[S_UU + tid] + o;
    float xsv = sl[S_ZS + tid];
    float arg = sl[S_S2 + tid] - 2.f * uf * xsv + uf * uf + EPS_;
    float lsv = 0.5f * logf(fmaxf(arg, 1e-30f));
    sl[S_SNEW + tid] = uf;
    sl[S_SNEW + 128 + tid] = lsv;
  }
  __syncthreads();
  if (FINAL) return;  // snew in LDS is the product
  // next-step LN over new slot row
  float x = (tid < 256) ? sl[S_SNEW + tid] : 0.f;
  float m2 = bRed512(x, sl + S_RED, tid) * (1.f / 256.f);
  float d2 = (tid < 256) ? (sl[S_SNEW + tid] - m2) : 0.f;
  float v2 = bRed512(d2 * d2, sl + S_RED, tid) * (1.f / 256.f);
  float rs2 = rsqrtf(v2 + 1e-5f);
  if (tid < 256) {
    float slv = d2 * rs2 * w.gsl[tid] + w.bsl[tid];
    sl[S_A1S + tid] = slv;
    if (tid < 128) mu[(size_t)(b * NS_ + i) * 128 + tid] = slv;
  }
  __syncthreads();
  slotTailV(sl, b, i, tid, w.Wq, wcoef, cbuf);
}

// ---------- tK: k/v weight transpose (wt[k][c], c<128 -> Wk, else Wv) ----------
__global__ __launch_bounds__(256) void tK(const float* __restrict__ Wk,
    const float* __restrict__ Wv, float* __restrict__ ws) {
  int tid = blockIdx.x * blockDim.x + threadIdx.x;
  int stride = gridDim.x * blockDim.x;
  for (int idx = tid; idx < 128 * 256; idx += stride) {
    int kk = idx >> 8, c = idx & 255;
    ws[OFF_WTKV + idx] = (c < 128) ? Wk[c * 128 + kk] : Wv[(c - 128) * 128 + kk];
  }
}

// ---------- kvK: LN(inputs)+k/v GEMM (blocks 0..255) + initial slot prep (256..319) ----------
__global__ __launch_bounds__(512) void kvK(const float* __restrict__ inp,
    const float* __restrict__ wt, const float* __restrict__ gin, const float* __restrict__ bin,
    const float* __restrict__ slots_in, SW w,
    float* __restrict__ kb, float* __restrict__ vb,
    float* __restrict__ mu, float* wcoef, float* cbuf) {
  __shared__ __align__(16) float shm[8896];
  int tid = threadIdx.x;
  int blk = blockIdx.x;
  if (blk < 256) {
    float* xs = shm;            // [64][129]
    float* red = shm + 8256;    // [64][8]
    float* mrow = shm + 8768;
    float* rrow = shm + 8832;
    int rowbase = blk * 64;
    #pragma unroll
    for (int it = 0; it < 4; ++it) {
      int f = tid + it * 512;
      int row = f >> 5, c4 = (f & 31) * 4;
      const float4 v = *(const float4*)&inp[(size_t)(rowbase + row) * 128 + c4];
      float* xr = &xs[row * 129 + c4];
      xr[0] = v.x; xr[1] = v.y; xr[2] = v.z; xr[3] = v.w;
    }
    __syncthreads();
    int row = tid >> 3, part = tid & 7;
    float s = 0.f;
    #pragma unroll
    for (int e = 0; e < 16; ++e) s += xs[row * 129 + part * 16 + e];
    red[row * 8 + part] = s;
    __syncthreads();
    if (part == 0) {
      float m = 0.f;
      #pragma unroll
      for (int q = 0; q < 8; ++q) m += red[row * 8 + q];
      mrow[row] = m * (1.f / 128.f);
    }
    __syncthreads();
    float m = mrow[row];
    s = 0.f;
    #pragma unroll
    for (int e = 0; e < 16; ++e) { float d = xs[row * 129 + part * 16 + e] - m; s += d * d; }
    red[row * 8 + part] = s;
    __syncthreads();
    if (part == 0) {
      float v = 0.f;
      #pragma unroll
      for (int q = 0; q < 8; ++q) v += red[row * 8 + q];
      rrow[row] = rsqrtf(v * (1.f / 128.f) + 1e-5f);
    }
    __syncthreads();
    float rs = rrow[row];
    #pragma unroll
    for (int e = 0; e < 16; ++e) {
      int c = part * 16 + e;
      xs[row * 129 + c] = (xs[row * 129 + c] - m) * rs * gin[c] + bin[c];
    }
    __syncthreads();
    int l = tid & 63;
    int wv = __builtin_amdgcn_readfirstlane(threadIdx.x >> 6);
    for (int pass = 0; pass < 2; ++pass) {
      int cbase = pass * 128 + wv * 16;
      float acc[16];
      #pragma unroll
      for (int e = 0; e < 16; ++e) acc[e] = 0.f;
      #pragma unroll 4
      for (int kk = 0; kk < 128; ++kk) {
        float a = xs[l * 129 + kk];
        const float* wr = &wt[kk * 256 + cbase];  // wave-uniform -> s_load
        #pragma unroll
        for (int e = 0; e < 16; ++e) acc[e] = fmaf(a, wr[e], acc[e]);
      }
      float* outp = (cbase < 128) ? kb : vb;
      int col = cbase & 127;
      size_t o = (size_t)(rowbase + l) * 128 + col;
      #pragma unroll
      for (int e4 = 0; e4 < 4; ++e4)
        *(float4*)&outp[o + e4 * 4] =
            make_float4(acc[e4 * 4], acc[e4 * 4 + 1], acc[e4 * 4 + 2], acc[e4 * 4 + 3]);
    }
  } else {
    float* sl = shm;
    int sb = blk - 256;
    int b2 = sb >> 4, i = sb & 15;
    float x = (tid < 256) ? slots_in[(size_t)(b2 * NS_ + i) * 256 + tid] : 0.f;
    float m = bRed512(x, sl + S_RED, tid) * (1.f / 256.f);
    float d = (tid < 256) ? (x - m) : 0.f;
    float var = bRed512(d * d, sl + S_RED, tid) * (1.f / 256.f);
    float rs = rsqrtf(var + 1e-5f);
    if (tid < 256) {
      float slv = d * rs * w.gsl[tid] + w.bsl[tid];
      sl[S_A1S + tid] = slv;
      if (tid < 128) mu[(size_t)(b2 * NS_ + i) * 128 + tid] = slv;
    }
    __syncthreads();
    slotTailV(sl, b2, i, tid, w.Wq, wcoef, cbuf);
  }
}

// ---------- pK: token pass per step ----------
__global__ __launch_bounds__(512) void pK(const float* __restrict__ kb,
    const float* __restrict__ vb, const float* __restrict__ wcoef,
    const float* __restrict__ cbuf, float* __restrict__ part,
    float* __restrict__ attnu, int last) {
  __shared__ __align__(16) float buf[8448];   // K as [64][129], then V as [64][132]
  __shared__ float a1s[16 * 66];
  __shared__ float esum[8 * 64];
  int tid = threadIdx.x;
  int jt = blockIdx.x, b = blockIdx.y;
  size_t jrow = (size_t)(b * N_ + jt * 64);
  // stage K tile row-major [64][129] (write 4 scalars; read lane-stride 129 -> conflict-free)
  #pragma unroll
  for (int it = 0; it < 4; ++it) {
    int f = tid + it * 512;
    int row = f >> 5, c4 = (f & 31) * 4;
    float4 kv = *(const float4*)&kb[(jrow + row) * 128 + c4];
    float* kr = &buf[row * 129 + c4];
    kr[0] = kv.x; kr[1] = kv.y; kr[2] = kv.z; kr[3] = kv.w;
  }
  __syncthreads();
  // phase A: dots; lanes = tokens, wave w owns slots {2w,2w+1}; even/odd-k split for ILP
  {
    int l = tid & 63;
    int w = __builtin_amdgcn_readfirstlane(threadIdx.x >> 6);
    int i0 = 2 * w, i1 = 2 * w + 1;
    const float* wb = &wcoef[(size_t)b * 128 * 32];
    float d0a = cbuf[b * NS_ + i0], d1a = cbuf[b * NS_ + i1];
    float d0b = 0.f, d1b = 0.f;
    #pragma unroll 4
    for (int kk = 0; kk < 128; kk += 2) {
      float kv0 = buf[l * 129 + kk];
      float kv1 = buf[l * 129 + kk + 1];
      float4 wv0 = *(const float4*)&wb[kk * 32 + 4 * w];        // wave-uniform -> s_load
      float4 wv1 = *(const float4*)&wb[(kk + 1) * 32 + 4 * w];
      d0a = fmaf(fmaf(wv0.y, kv0, wv0.x), kv0, d0a);
      d1a = fmaf(fmaf(wv0.w, kv0, wv0.z), kv0, d1a);
      d0b = fmaf(fmaf(wv1.y, kv1, wv1.x), kv1, d0b);
      d1b = fmaf(fmaf(wv1.w, kv1, wv1.z), kv1, d1b);
    }
    float e0 = expf(-(d0a + d0b)) + EPS_;
    float e1 = expf(-(d1a + d1b)) + EPS_;
    esum[w * 64 + l] = e0 + e1;
    __syncthreads();
    float tot = 0.f;
    #pragma unroll
    for (int q = 0; q < 8; ++q) tot += esum[q * 64 + l];
    float a0 = e0 / tot, a1v = e1 / tot;
    a1s[i0 * 66 + l] = a0;
    a1s[i1 * 66 + l] = a1v;
    if (last) {
      attnu[(size_t)(b * NS_ + i0) * N_ + jt * 64 + l] = a0;
      attnu[(size_t)(b * NS_ + i1) * N_ + jt * 64 + l] = a1v;
    }
  }
  __syncthreads();
  // stage V tile (reuse buf) as [64][132]
  #pragma unroll
  for (int it = 0; it < 4; ++it) {
    int f = tid + it * 512;
    int row = f >> 5, c4 = (f & 31) * 4;
    float4 vv = *(const float4*)&vb[(jrow + row) * 128 + c4];
    *(float4*)&buf[row * 132 + c4] = vv;
  }
  __syncthreads();
  // phase B: partial Sv, Sv2, rowsum
  {
    int ii = tid >> 5, dg = tid & 31;
    float av0 = 0, av1 = 0, av2 = 0, av3 = 0, aw0 = 0, aw1 = 0, aw2 = 0, aw3 = 0, rsum = 0;
    #pragma unroll 4
    for (int j = 0; j < 64; ++j) {
      float a = a1s[ii * 66 + j];
      const float4 v4 = *(const float4*)&buf[j * 132 + dg * 4];
      rsum += a;
      float m0 = a * v4.x, m1 = a * v4.y, m2 = a * v4.z, m3 = a * v4.w;
      av0 += m0; av1 += m1; av2 += m2; av3 += m3;
      aw0 = fmaf(m0, v4.x, aw0); aw1 = fmaf(m1, v4.y, aw1);
      aw2 = fmaf(m2, v4.z, aw2); aw3 = fmaf(m3, v4.w, aw3);
    }
    float* pr = &part[((size_t)(b * NT_ + jt) * NS_ + ii) * 260];
    *(float4*)&pr[dg * 4] = make_float4(av0, av1, av2, av3);
    *(float4*)&pr[128 + dg * 4] = make_float4(aw0, aw1, aw2, aw3);
    if (dg == 0) pr[256] = rsum;
  }
}

// ---------- rK: per-slot update (steps 0..2), 64 blocks ----------
__global__ __launch_bounds__(512) void rK(const float* __restrict__ part,
    float* mu, float* wcoef, float* cbuf, SW w) {
  __shared__ __align__(16) float sl[S_TOT];
  int tid = threadIdx.x;
  int b = blockIdx.x >> 4, i = blockIdx.x & 15;
  slotUpdateV<0>(sl, b, i, tid, part, mu, wcoef, cbuf, w);
}

// ---------- oK: final slot update + out MLP (blocks 0..63) + attn normalize (64..191) ----------
__global__ __launch_bounds__(512) void oK(const float* __restrict__ part,
    float* mu, SW w,
    const float* __restrict__ oW1, const float* __restrict__ ob1,
    const float* __restrict__ oW2, const float* __restrict__ ob2,
    const float* __restrict__ attnu, float* __restrict__ out) {
  __shared__ __align__(16) float sl[S_TOT];
  int blk = blockIdx.x, tid = threadIdx.x;
  const size_t pstr = (size_t)NS_ * 260;
  if (blk >= 64) {
    // attn normalize: block covers half of one (b,i) row; rowsum from part partials
    int r = (blk - 64) >> 1, half = (blk - 64) & 1;
    int b = r >> 4, i = r & 15;
    size_t pbase = ((size_t)(b * NT_) * NS_ + i) * 260;
    if (tid < 64) {
      float v = part[pbase + (size_t)tid * pstr + 256];
      #pragma unroll
      for (int off = 32; off > 0; off >>= 1) v += __shfl_down(v, off, 64);
      if (tid == 0) sl[0] = v;
    }
    __syncthreads();
    float rs = sl[0];
    int base = r * 4096 + (half * 512 + tid) * 4;
    float4 v = *(const float4*)&attnu[base];
    v.x /= rs; v.y /= rs; v.z /= rs; v.w /= rs;
    *(float4*)&out[8192 + base] = v;
    return;
  }
  int b = blk >> 4, i = blk & 15;
  slotUpdateV<1>(sl, b, i, tid, part, mu, (float*)nullptr, (float*)nullptr, w);
  // out MLP from snew (sl[S_SNEW..+255]); h1 -> sl[0..1023]; dpart -> sl[S_RED..]
  {
    const float4* s4 = (const float4*)&sl[S_SNEW];
    #pragma unroll
    for (int h = 0; h < 2; ++h) {
      int q = tid + h * 512;
      const float4* w4 = (const float4*)&oW1[(size_t)q * 256];
      float a = ob1[q];
      #pragma unroll 8
      for (int c = 0; c < 64; ++c) {
        float4 wv = w4[c], xv = s4[c];
        a = fmaf(wv.x, xv.x, a); a = fmaf(wv.y, xv.y, a);
        a = fmaf(wv.z, xv.z, a); a = fmaf(wv.w, xv.w, a);
      }
      sl[q] = fmaxf(a, 0.f);  // overwrite dead scratch [0..1023]
    }
  }
  __syncthreads();
  {
    int qg = tid >> 7, d = tid & 127;
    const float4* h4 = (const float4*)&sl[qg * 256];
    const float4* w4 = (const float4*)&oW2[(size_t)d * 1024 + qg * 256];
    float dp = 0.f;
    #pragma unroll 8
    for (int c = 0; c < 64; ++c) {
      float4 wv = w4[c], hv = h4[c];
      dp = fmaf(wv.x, hv.x, dp); dp = fmaf(wv.y, hv.y, dp);
      dp = fmaf(wv.z, hv.z, dp); dp = fmaf(wv.w, hv.w, dp);
    }
    sl[S_RED + qg * 128 + d] = dp;
  }
  __syncthreads();
  if (tid < 128)
    out[(size_t)blk * 128 + tid] = ob2[tid] + sl[S_RED + tid] + sl[S_RED + 128 + tid] +
                                   sl[S_RED + 256 + tid] + sl[S_RED + 384 + tid];
}

extern "C" void kernel_launch(void* const* d_in, const int* in_sizes, int n_in,
                              void* d_out, int out_size, void* d_ws, size_t ws_size,
                              hipStream_t stream) {
  const float* slots_in = (const float*)d_in[0];
  const float* inputs   = (const float*)d_in[1];
  const float* Wq  = (const float*)d_in[2];
  const float* Wk  = (const float*)d_in[3];
  const float* Wv  = (const float*)d_in[4];
  const float* Wih = (const float*)d_in[5];
  const float* Whh = (const float*)d_in[6];
  const float* bih = (const float*)d_in[7];
  const float* bhh = (const float*)d_in[8];
  const float* mW1 = (const float*)d_in[9];
  const float* mb1 = (const float*)d_in[10];
  const float* mW2 = (const float*)d_in[11];
  const float* mb2 = (const float*)d_in[12];
  const float* g_in  = (const float*)d_in[13];
  const float* be_in = (const float*)d_in[14];
  const float* g_sl  = (const float*)d_in[15];
  const float* be_sl = (const float*)d_in[16];
  const float* g_mu  = (const float*)d_in[17];
  const float* be_mu = (const float*)d_in[18];
  const float* oW1 = (const float*)d_in[19];
  const float* ob1 = (const float*)d_in[20];
  const float* oW2 = (const float*)d_in[21];
  const float* ob2 = (const float*)d_in[22];
  float* ws  = (float*)d_ws;
  float* out = (float*)d_out;
  (void)in_sizes; (void)n_in; (void)out_size; (void)ws_size;

  SW w;
  w.Wih = Wih; w.Whh = Whh; w.bih = bih; w.bhh = bhh;
  w.mW1 = mW1; w.mb1 = mb1; w.mW2 = mW2; w.mb2 = mb2;
  w.gmu = g_mu; w.bmu = be_mu; w.gsl = g_sl; w.bsl = be_sl;
  w.Wq = Wq;

  hipLaunchKernelGGL(tK, dim3(64), dim3(256), 0, stream, Wk, Wv, ws);
  hipLaunchKernelGGL(kvK, dim3(320), dim3(512), 0, stream,
                     inputs, ws + OFF_WTKV, g_in, be_in, slots_in, w,
                     ws + OFF_K, ws + OFF_V, ws + OFF_MU, ws + OFF_WCOEF, ws + OFF_C);
  for (int s = 0; s < 4; ++s) {
    hipLaunchKernelGGL(pK, dim3(64, 4), dim3(512), 0, stream,
                       ws + OFF_K, ws + OFF_V, ws + OFF_WCOEF, ws + OFF_C,
                       ws + OFF_PART, ws + OFF_ATTNU, (s == 3) ? 1 : 0);
    if (s < 3) {
      hipLaunchKernelGGL(rK, dim3(64), dim3(512), 0, stream,
                         ws + OFF_PART, ws + OFF_MU, ws + OFF_WCOEF, ws + OFF_C, w);
    }
  }
  hipLaunchKernelGGL(oK, dim3(192), dim3(512), 0, stream,
                     ws + OFF_PART, ws + OFF_MU, w, oW1, ob1, oW2, ob2,
                     ws + OFF_ATTNU, out);
}

// Round 6
// 234.277 us; speedup vs baseline: 4.1637x; 1.2822x over previous
//
#include <hip/hip_runtime.h>
#include <math.h>

#define B_ 4
#define N_ 4096
#define D_ 128
#define NS_ 16
#define NT_ 64
#define SCALE_ 0.08838834764831843f
#define EPS_ 1e-10f

// workspace offsets (floats)
#define OFF_K      ((size_t)0)
#define OFF_V      (OFF_K + (size_t)B_*N_*D_)
#define OFF_WTKV   (OFF_V + (size_t)B_*N_*D_)
#define OFF_WQT    (OFF_WTKV + 128*256)
#define OFF_WC     (OFF_WQT + 128*128)
#define OFF_MW1T   (OFF_WC + 256*512)
#define OFF_MW2T   (OFF_MW1T + 128*512)
#define OFF_OW1T   (OFF_MW2T + 512*128)
#define OFF_OW2T   (OFF_OW1T + 256*1024)
#define OFF_MU     (OFF_OW2T + 1024*128)
#define OFF_WCOEF  (OFF_MU + (size_t)B_*NS_*128)
#define OFF_C      (OFF_WCOEF + (size_t)B_*128*32)
#define OFF_PART   (OFF_C + 64)
#define OFF_ATTNU  (OFF_PART + (size_t)B_*NT_*NS_*260)

// slot scratch offsets (floats)
#define S_ZS    0     /* 256 */
#define S_S2    256   /* 128 */
#define S_OUTG  384   /* 512 */
#define S_UU    896   /* 128 */
#define S_H2    1024  /* 128 */
#define S_A1S   1152  /* 512 */
#define S_SNEW  1664  /* 256 */
#define S_QM    1920  /* 128 */
#define S_QL    2048  /* 128 */
#define S_RED   2176  /* 512 */
#define S_PPART 2688  /* 512 */
#define S_QPART 3200  /* 512 */
#define S_TOT   3712

// transposed-weight + bias bundle (all matvecs coalesced column access)
struct SW {
  const float* wc;    // [256][512] unified GRU
  const float* mw1T;  // [128][512]
  const float* mw2T;  // [512][128]
  const float* wqT;   // [128][128]
  const float* bih; const float* bhh;
  const float* mb1; const float* mb2;
  const float* gmu; const float* bmu;
  const float* gsl; const float* bsl;
};

__device__ __forceinline__ float bRed512(float v, float* red, int tid) {
  red[tid] = v;
  __syncthreads();
  if (tid < 256) red[tid] += red[tid + 256];
  __syncthreads();
  if (tid < 128) red[tid] += red[tid + 128];
  __syncthreads();
  if (tid < 64) {
    float x = red[tid] + red[tid + 64];
    #pragma unroll
    for (int off = 32; off > 0; off >>= 1) x += __shfl_down(x, off, 64);
    if (tid == 0) red[0] = x;
  }
  __syncthreads();
  float r = red[0];
  __syncthreads();
  return r;
}

// input: sl[S_A1S..+255] = LN'd slot row. Coalesced wqT columns.
__device__ __forceinline__ void slotTailT(float* sl, int b, int i, int tid,
    const float* __restrict__ wqT, float* wcoef, float* cbuf) {
  {
    int kg = tid >> 8;          // K half (64 rows each)
    int rest = tid & 255;       // 0..127 -> qm, 128..255 -> ql
    int wh = rest >> 7;
    int o = rest & 127;
    float acc = 0.f;
    #pragma unroll 8
    for (int dd = 0; dd < 64; ++dd)
      acc = fmaf(sl[S_A1S + wh * 128 + kg * 64 + dd], wqT[(kg * 64 + dd) * 128 + o], acc);
    sl[S_QPART + kg * 256 + rest] = acc;
  }
  __syncthreads();
  if (tid < 256) {
    float q = sl[S_QPART + tid] + sl[S_QPART + 256 + tid];
    if (tid < 128) sl[S_QM + tid] = q; else sl[S_QL + (tid - 128)] = q;
  }
  __syncthreads();
  float cp = 0.f;
  if (tid < 128) {
    float iv = expf(-2.f * sl[S_QL + tid]);
    float a1 = SCALE_ * iv;
    float a2 = -2.f * SCALE_ * iv * sl[S_QM + tid];
    float* wrow = &wcoef[((size_t)b * 128 + tid) * 32];
    wrow[2 * i] = a2;
    wrow[2 * i + 1] = a1;
    cp = SCALE_ * iv * sl[S_QM + tid] * sl[S_QM + tid];
  }
  float ctot = bRed512(cp, sl + S_RED, tid);
  if (tid == 0) cbuf[b * NS_ + i] = ctot;
}

// FINAL=0: full update incl. next-step prep. FINAL=1: stop with snew in LDS.
template <int FINAL>
__device__ void slotUpdateT(float* sl, int b, int i, int tid,
    const float* __restrict__ part, float* mu, float* wcoef, float* cbuf, SW w) {
  size_t pbase = ((size_t)(b * NT_) * NS_ + i) * 260;
  const size_t pstr = (size_t)NS_ * 260;
  {
    int th = tid >> 8, e = tid & 255;
    float s = 0.f;
    #pragma unroll 8
    for (int t = 0; t < 32; ++t) s += part[pbase + (size_t)(th * 32 + t) * pstr + e];
    sl[S_PPART + th * 256 + e] = s;
  }
  float rp = (tid < 64) ? part[pbase + (size_t)tid * pstr + 256] : 0.f;
  float rt = bRed512(rp, sl + S_RED, tid);  // internal syncs cover ppart visibility
  if (tid < 128) sl[S_ZS + tid] = (sl[S_PPART + tid] + sl[S_PPART + 256 + tid]) / rt;
  else if (tid < 256) sl[S_S2 + tid - 128] = (sl[S_PPART + tid] + sl[S_PPART + 256 + tid]) / rt;
  else if (tid < 384) sl[S_ZS + tid - 128] = mu[(size_t)(b * NS_ + i) * 128 + (tid - 256)];
  __syncthreads();
  // unified GRU matvec: outg[q] = [xs|hm] . WC[:,q]  (coalesced, 2 chains)
  {
    float a0 = 0.f, a1 = 0.f;
    #pragma unroll 8
    for (int dd = 0; dd < 128; ++dd) {
      a0 = fmaf(sl[S_ZS + dd], w.wc[dd * 512 + tid], a0);
      a1 = fmaf(sl[S_ZS + 128 + dd], w.wc[(128 + dd) * 512 + tid], a1);
    }
    sl[S_OUTG + tid] = a0 + a1;
  }
  __syncthreads();
  if (tid < 128) {
    float r = 1.f / (1.f + expf(-(sl[S_OUTG + tid] + w.bih[tid] + w.bhh[tid])));
    float z = 1.f / (1.f + expf(-(sl[S_OUTG + 128 + tid] + w.bih[128 + tid] + w.bhh[128 + tid])));
    float nn = tanhf(sl[S_OUTG + 256 + tid] + w.bih[256 + tid] +
                     r * (sl[S_OUTG + 384 + tid] + w.bhh[256 + tid]));
    sl[S_UU + tid] = (1.f - z) * nn + z * sl[S_ZS + 128 + tid];
  }
  __syncthreads();
  // LN(u)
  float uv = (tid < 128) ? sl[S_UU + tid] : 0.f;
  float m = bRed512(uv, sl + S_RED, tid) * (1.f / 128.f);
  float dv = (tid < 128) ? (sl[S_UU + tid] - m) : 0.f;
  float var = bRed512(dv * dv, sl + S_RED, tid) * (1.f / 128.f);
  float rsq = rsqrtf(var + 1e-5f);
  if (tid < 128) sl[S_H2 + tid] = dv * rsq * w.gmu[tid] + w.bmu[tid];
  __syncthreads();
  // MLP up: a1S[q] = relu(h2 . mW1T[:,q] + mb1[q])  (coalesced, 2 chains)
  {
    float a0 = 0.f, a1 = 0.f;
    #pragma unroll 8
    for (int dd = 0; dd < 64; ++dd) {
      a0 = fmaf(sl[S_H2 + dd], w.mw1T[dd * 512 + tid], a0);
      a1 = fmaf(sl[S_H2 + 64 + dd], w.mw1T[(64 + dd) * 512 + tid], a1);
    }
    sl[S_A1S + tid] = fmaxf(a0 + a1 + w.mb1[tid], 0.f);
  }
  __syncthreads();
  // MLP down: K split 4, coalesced, 2 chains
  {
    int qg = tid >> 7, d = tid & 127;
    float b0 = 0.f, b1 = 0.f;
    #pragma unroll 8
    for (int qq = 0; qq < 64; ++qq) {
      b0 = fmaf(sl[S_A1S + qg * 128 + qq], w.mw2T[(qg * 128 + qq) * 128 + d], b0);
      b1 = fmaf(sl[S_A1S + qg * 128 + 64 + qq], w.mw2T[(qg * 128 + 64 + qq) * 128 + d], b1);
    }
    sl[S_QPART + qg * 128 + d] = b0 + b1;
  }
  __syncthreads();
  if (tid < 128) {
    float o = w.mb2[tid] + sl[S_QPART + tid] + sl[S_QPART + 128 + tid] +
              sl[S_QPART + 256 + tid] + sl[S_QPART + 384 + tid];
    float uf = sl[S_UU + tid] + o;
    float xsv = sl[S_ZS + tid];
    float arg = sl[S_S2 + tid] - 2.f * uf * xsv + uf * uf + EPS_;
    float lsv = 0.5f * logf(fmaxf(arg, 1e-30f));
    sl[S_SNEW + tid] = uf;
    sl[S_SNEW + 128 + tid] = lsv;
  }
  __syncthreads();
  if (FINAL) return;  // snew in LDS is the product
  // next-step LN over new slot row
  float x = (tid < 256) ? sl[S_SNEW + tid] : 0.f;
  float m2 = bRed512(x, sl + S_RED, tid) * (1.f / 256.f);
  float d2 = (tid < 256) ? (sl[S_SNEW + tid] - m2) : 0.f;
  float v2 = bRed512(d2 * d2, sl + S_RED, tid) * (1.f / 256.f);
  float rs2 = rsqrtf(v2 + 1e-5f);
  if (tid < 256) {
    float slv = d2 * rs2 * w.gsl[tid] + w.bsl[tid];
    sl[S_A1S + tid] = slv;
    if (tid < 128) mu[(size_t)(b * NS_ + i) * 128 + tid] = slv;
  }
  __syncthreads();
  slotTailT(sl, b, i, tid, w.wqT, wcoef, cbuf);
}

// ---------- tK: build all transposed weights (write-coalesced) ----------
__global__ __launch_bounds__(256) void tK(
    const float* __restrict__ Wq, const float* __restrict__ Wk, const float* __restrict__ Wv,
    const float* __restrict__ Wih, const float* __restrict__ Whh,
    const float* __restrict__ mW1, const float* __restrict__ mW2,
    const float* __restrict__ oW1, const float* __restrict__ oW2,
    float* __restrict__ ws) {
  int tid = blockIdx.x * blockDim.x + threadIdx.x;
  int stride = gridDim.x * blockDim.x;
  for (int idx = tid; idx < 128 * 256; idx += stride) {
    int kk = idx >> 8, c = idx & 255;
    ws[OFF_WTKV + idx] = (c < 128) ? Wk[c * 128 + kk] : Wv[(c - 128) * 128 + kk];
  }
  for (int idx = tid; idx < 128 * 128; idx += stride) {
    int kk = idx >> 7, o = idx & 127;
    ws[OFF_WQT + idx] = Wq[o * 128 + kk];
  }
  for (int idx = tid; idx < 256 * 512; idx += stride) {
    int dd = idx >> 9, q = idx & 511;
    float v;
    if (dd < 128) {
      v = (q < 384) ? Wih[q * 128 + dd] : 0.f;
    } else {
      int dh = dd - 128;
      if (q < 256) v = Whh[q * 128 + dh];
      else if (q < 384) v = 0.f;
      else v = Whh[(q - 128) * 128 + dh];
    }
    ws[OFF_WC + idx] = v;
  }
  for (int idx = tid; idx < 128 * 512; idx += stride) {
    int dd = idx >> 9, q = idx & 511;
    ws[OFF_MW1T + idx] = mW1[q * 128 + dd];
  }
  for (int idx = tid; idx < 512 * 128; idx += stride) {
    int q = idx >> 7, d = idx & 127;
    ws[OFF_MW2T + idx] = mW2[d * 512 + q];
  }
  for (int idx = tid; idx < 256 * 1024; idx += stride) {
    int dd = idx >> 10, q = idx & 1023;
    ws[OFF_OW1T + idx] = oW1[q * 256 + dd];
  }
  for (int idx = tid; idx < 1024 * 128; idx += stride) {
    int q = idx >> 7, d = idx & 127;
    ws[OFF_OW2T + idx] = oW2[d * 1024 + q];
  }
}

// ---------- kvK: LN(inputs)+k/v GEMM (0..255) + initial slot prep (256..319) ----------
__global__ __launch_bounds__(512) void kvK(const float* __restrict__ inp,
    const float* __restrict__ wt, const float* __restrict__ gin, const float* __restrict__ bin,
    const float* __restrict__ slots_in, SW w,
    float* __restrict__ kb, float* __restrict__ vb,
    float* __restrict__ mu, float* wcoef, float* cbuf) {
  __shared__ __align__(16) float shm[8896];
  int tid = threadIdx.x;
  int blk = blockIdx.x;
  if (blk < 256) {
    float* xs = shm;            // [64][129]
    float* red = shm + 8256;    // [64][8]
    float* mrow = shm + 8768;
    float* rrow = shm + 8832;
    int rowbase = blk * 64;
    #pragma unroll
    for (int it = 0; it < 4; ++it) {
      int f = tid + it * 512;
      int row = f >> 5, c4 = (f & 31) * 4;
      const float4 v = *(const float4*)&inp[(size_t)(rowbase + row) * 128 + c4];
      float* xr = &xs[row * 129 + c4];
      xr[0] = v.x; xr[1] = v.y; xr[2] = v.z; xr[3] = v.w;
    }
    __syncthreads();
    int row = tid >> 3, part = tid & 7;
    float s = 0.f;
    #pragma unroll
    for (int e = 0; e < 16; ++e) s += xs[row * 129 + part * 16 + e];
    red[row * 8 + part] = s;
    __syncthreads();
    if (part == 0) {
      float m = 0.f;
      #pragma unroll
      for (int q = 0; q < 8; ++q) m += red[row * 8 + q];
      mrow[row] = m * (1.f / 128.f);
    }
    __syncthreads();
    float m = mrow[row];
    s = 0.f;
    #pragma unroll
    for (int e = 0; e < 16; ++e) { float d = xs[row * 129 + part * 16 + e] - m; s += d * d; }
    red[row * 8 + part] = s;
    __syncthreads();
    if (part == 0) {
      float v = 0.f;
      #pragma unroll
      for (int q = 0; q < 8; ++q) v += red[row * 8 + q];
      rrow[row] = rsqrtf(v * (1.f / 128.f) + 1e-5f);
    }
    __syncthreads();
    float rs = rrow[row];
    #pragma unroll
    for (int e = 0; e < 16; ++e) {
      int c = part * 16 + e;
      xs[row * 129 + c] = (xs[row * 129 + c] - m) * rs * gin[c] + bin[c];
    }
    __syncthreads();
    int l = tid & 63;
    int wv = __builtin_amdgcn_readfirstlane(threadIdx.x >> 6);
    for (int pass = 0; pass < 2; ++pass) {
      int cbase = pass * 128 + wv * 16;
      float acc[16];
      #pragma unroll
      for (int e = 0; e < 16; ++e) acc[e] = 0.f;
      #pragma unroll 4
      for (int kk = 0; kk < 128; ++kk) {
        float a = xs[l * 129 + kk];
        const float* wr = &wt[kk * 256 + cbase];  // wave-uniform -> s_load
        #pragma unroll
        for (int e = 0; e < 16; ++e) acc[e] = fmaf(a, wr[e], acc[e]);
      }
      float* outp = (cbase < 128) ? kb : vb;
      int col = cbase & 127;
      size_t o = (size_t)(rowbase + l) * 128 + col;
      #pragma unroll
      for (int e4 = 0; e4 < 4; ++e4)
        *(float4*)&outp[o + e4 * 4] =
            make_float4(acc[e4 * 4], acc[e4 * 4 + 1], acc[e4 * 4 + 2], acc[e4 * 4 + 3]);
    }
  } else {
    float* sl = shm;
    int sb = blk - 256;
    int b2 = sb >> 4, i = sb & 15;
    float x = (tid < 256) ? slots_in[(size_t)(b2 * NS_ + i) * 256 + tid] : 0.f;
    float m = bRed512(x, sl + S_RED, tid) * (1.f / 256.f);
    float d = (tid < 256) ? (x - m) : 0.f;
    float var = bRed512(d * d, sl + S_RED, tid) * (1.f / 256.f);
    float rs = rsqrtf(var + 1e-5f);
    if (tid < 256) {
      float slv = d * rs * w.gsl[tid] + w.bsl[tid];
      sl[S_A1S + tid] = slv;
      if (tid < 128) mu[(size_t)(b2 * NS_ + i) * 128 + tid] = slv;
    }
    __syncthreads();
    slotTailT(sl, b2, i, tid, w.wqT, wcoef, cbuf);
  }
}

// ---------- pK: token pass per step ----------
__global__ __launch_bounds__(512) void pK(const float* __restrict__ kb,
    const float* __restrict__ vb, const float* __restrict__ wcoef,
    const float* __restrict__ cbuf, float* __restrict__ part,
    float* __restrict__ attnu, int last) {
  __shared__ __align__(16) float buf[8448];   // K as [64][129], then V as [64][132]
  __shared__ float a1s[16 * 66];
  __shared__ float esum[8 * 64];
  int tid = threadIdx.x;
  int jt = blockIdx.x, b = blockIdx.y;
  size_t jrow = (size_t)(b * N_ + jt * 64);
  #pragma unroll
  for (int it = 0; it < 4; ++it) {
    int f = tid + it * 512;
    int row = f >> 5, c4 = (f & 31) * 4;
    float4 kv = *(const float4*)&kb[(jrow + row) * 128 + c4];
    float* kr = &buf[row * 129 + c4];
    kr[0] = kv.x; kr[1] = kv.y; kr[2] = kv.z; kr[3] = kv.w;
  }
  __syncthreads();
  {
    int l = tid & 63;
    int w = __builtin_amdgcn_readfirstlane(threadIdx.x >> 6);
    int i0 = 2 * w, i1 = 2 * w + 1;
    const float* wb = &wcoef[(size_t)b * 128 * 32];
    float d0a = cbuf[b * NS_ + i0], d1a = cbuf[b * NS_ + i1];
    float d0b = 0.f, d1b = 0.f;
    #pragma unroll 4
    for (int kk = 0; kk < 128; kk += 2) {
      float kv0 = buf[l * 129 + kk];
      float kv1 = buf[l * 129 + kk + 1];
      float4 wv0 = *(const float4*)&wb[kk * 32 + 4 * w];
      float4 wv1 = *(const float4*)&wb[(kk + 1) * 32 + 4 * w];
      d0a = fmaf(fmaf(wv0.y, kv0, wv0.x), kv0, d0a);
      d1a = fmaf(fmaf(wv0.w, kv0, wv0.z), kv0, d1a);
      d0b = fmaf(fmaf(wv1.y, kv1, wv1.x), kv1, d0b);
      d1b = fmaf(fmaf(wv1.w, kv1, wv1.z), kv1, d1b);
    }
    float e0 = expf(-(d0a + d0b)) + EPS_;
    float e1 = expf(-(d1a + d1b)) + EPS_;
    esum[w * 64 + l] = e0 + e1;
    __syncthreads();
    float tot = 0.f;
    #pragma unroll
    for (int q = 0; q < 8; ++q) tot += esum[q * 64 + l];
    float a0 = e0 / tot, a1v = e1 / tot;
    a1s[i0 * 66 + l] = a0;
    a1s[i1 * 66 + l] = a1v;
    if (last) {
      attnu[(size_t)(b * NS_ + i0) * N_ + jt * 64 + l] = a0;
      attnu[(size_t)(b * NS_ + i1) * N_ + jt * 64 + l] = a1v;
    }
  }
  __syncthreads();
  #pragma unroll
  for (int it = 0; it < 4; ++it) {
    int f = tid + it * 512;
    int row = f >> 5, c4 = (f & 31) * 4;
    float4 vv = *(const float4*)&vb[(jrow + row) * 128 + c4];
    *(float4*)&buf[row * 132 + c4] = vv;
  }
  __syncthreads();
  {
    int ii = tid >> 5, dg = tid & 31;
    float av0 = 0, av1 = 0, av2 = 0, av3 = 0, aw0 = 0, aw1 = 0, aw2 = 0, aw3 = 0, rsum = 0;
    #pragma unroll 4
    for (int j = 0; j < 64; ++j) {
      float a = a1s[ii * 66 + j];
      const float4 v4 = *(const float4*)&buf[j * 132 + dg * 4];
      rsum += a;
      float m0 = a * v4.x, m1 = a * v4.y, m2 = a * v4.z, m3 = a * v4.w;
      av0 += m0; av1 += m1; av2 += m2; av3 += m3;
      aw0 = fmaf(m0, v4.x, aw0); aw1 = fmaf(m1, v4.y, aw1);
      aw2 = fmaf(m2, v4.z, aw2); aw3 = fmaf(m3, v4.w, aw3);
    }
    float* pr = &part[((size_t)(b * NT_ + jt) * NS_ + ii) * 260];
    *(float4*)&pr[dg * 4] = make_float4(av0, av1, av2, av3);
    *(float4*)&pr[128 + dg * 4] = make_float4(aw0, aw1, aw2, aw3);
    if (dg == 0) pr[256] = rsum;
  }
}

// ---------- rK: per-slot update (steps 0..2), 64 blocks ----------
__global__ __launch_bounds__(512, 2) void rK(const float* __restrict__ part,
    float* mu, float* wcoef, float* cbuf, SW w) {
  __shared__ __align__(16) float sl[S_TOT];
  int tid = threadIdx.x;
  int b = blockIdx.x >> 4, i = blockIdx.x & 15;
  slotUpdateT<0>(sl, b, i, tid, part, mu, wcoef, cbuf, w);
}

// ---------- oK: final slot update + out MLP (0..63) + attn normalize (64..191) ----------
__global__ __launch_bounds__(512, 2) void oK(const float* __restrict__ part,
    float* mu, SW w,
    const float* __restrict__ ow1T, const float* __restrict__ ob1,
    const float* __restrict__ ow2T, const float* __restrict__ ob2,
    const float* __restrict__ attnu, float* __restrict__ out) {
  __shared__ __align__(16) float sl[S_TOT];
  int blk = blockIdx.x, tid = threadIdx.x;
  const size_t pstr = (size_t)NS_ * 260;
  if (blk >= 64) {
    int r = (blk - 64) >> 1, half = (blk - 64) & 1;
    int b = r >> 4, i = r & 15;
    size_t pbase = ((size_t)(b * NT_) * NS_ + i) * 260;
    if (tid < 64) {
      float v = part[pbase + (size_t)tid * pstr + 256];
      #pragma unroll
      for (int off = 32; off > 0; off >>= 1) v += __shfl_down(v, off, 64);
      if (tid == 0) sl[0] = v;
    }
    __syncthreads();
    float rs = sl[0];
    int base = r * 4096 + (half * 512 + tid) * 4;
    float4 v = *(const float4*)&attnu[base];
    v.x /= rs; v.y /= rs; v.z /= rs; v.w /= rs;
    *(float4*)&out[8192 + base] = v;
    return;
  }
  int b = blk >> 4, i = blk & 15;
  slotUpdateT<1>(sl, b, i, tid, part, mu, (float*)nullptr, (float*)nullptr, w);
  // out MLP from snew; h1 -> sl[0..1023] (dead scratch); coalesced ow1T columns
  {
    const float* sn = sl + S_SNEW;
    #pragma unroll
    for (int h = 0; h < 2; ++h) {
      int q = tid + h * 512;
      float a0 = 0.f, a1 = 0.f;
      #pragma unroll 8
      for (int dd = 0; dd < 128; ++dd) {
        a0 = fmaf(sn[dd], ow1T[dd * 1024 + q], a0);
        a1 = fmaf(sn[128 + dd], ow1T[(128 + dd) * 1024 + q], a1);
      }
      sl[q] = fmaxf(a0 + a1 + ob1[q], 0.f);
    }
  }
  __syncthreads();
  {
    int qg = tid >> 7, d = tid & 127;
    float b0 = 0.f, b1 = 0.f;
    #pragma unroll 8
    for (int qq = 0; qq < 128; ++qq) {
      b0 = fmaf(sl[qg * 256 + qq], ow2T[(qg * 256 + qq) * 128 + d], b0);
      b1 = fmaf(sl[qg * 256 + 128 + qq], ow2T[(qg * 256 + 128 + qq) * 128 + d], b1);
    }
    sl[S_QPART + qg * 128 + d] = b0 + b1;
  }
  __syncthreads();
  if (tid < 128)
    out[(size_t)blk * 128 + tid] = ob2[tid] + sl[S_QPART + tid] + sl[S_QPART + 128 + tid] +
                                   sl[S_QPART + 256 + tid] + sl[S_QPART + 384 + tid];
}

extern "C" void kernel_launch(void* const* d_in, const int* in_sizes, int n_in,
                              void* d_out, int out_size, void* d_ws, size_t ws_size,
                              hipStream_t stream) {
  const float* slots_in = (const float*)d_in[0];
  const float* inputs   = (const float*)d_in[1];
  const float* Wq  = (const float*)d_in[2];
  const float* Wk  = (const float*)d_in[3];
  const float* Wv  = (const float*)d_in[4];
  const float* Wih = (const float*)d_in[5];
  const float* Whh = (const float*)d_in[6];
  const float* bih = (const float*)d_in[7];
  const float* bhh = (const float*)d_in[8];
  const float* mW1 = (const float*)d_in[9];
  const float* mb1 = (const float*)d_in[10];
  const float* mW2 = (const float*)d_in[11];
  const float* mb2 = (const float*)d_in[12];
  const float* g_in  = (const float*)d_in[13];
  const float* be_in = (const float*)d_in[14];
  const float* g_sl  = (const float*)d_in[15];
  const float* be_sl = (const float*)d_in[16];
  const float* g_mu  = (const float*)d_in[17];
  const float* be_mu = (const float*)d_in[18];
  const float* oW1 = (const float*)d_in[19];
  const float* ob1 = (const float*)d_in[20];
  const float* oW2 = (const float*)d_in[21];
  const float* ob2 = (const float*)d_in[22];
  float* ws  = (float*)d_ws;
  float* out = (float*)d_out;
  (void)in_sizes; (void)n_in; (void)out_size; (void)ws_size;

  SW w;
  w.wc = ws + OFF_WC; w.mw1T = ws + OFF_MW1T; w.mw2T = ws + OFF_MW2T; w.wqT = ws + OFF_WQT;
  w.bih = bih; w.bhh = bhh; w.mb1 = mb1; w.mb2 = mb2;
  w.gmu = g_mu; w.bmu = be_mu; w.gsl = g_sl; w.bsl = be_sl;

  hipLaunchKernelGGL(tK, dim3(128), dim3(256), 0, stream,
                     Wq, Wk, Wv, Wih, Whh, mW1, mW2, oW1, oW2, ws);
  hipLaunchKernelGGL(kvK, dim3(320), dim3(512), 0, stream,
                     inputs, ws + OFF_WTKV, g_in, be_in, slots_in, w,
                     ws + OFF_K, ws + OFF_V, ws + OFF_MU, ws + OFF_WCOEF, ws + OFF_C);
  for (int s = 0; s < 4; ++s) {
    hipLaunchKernelGGL(pK, dim3(64, 4), dim3(512), 0, stream,
                       ws + OFF_K, ws + OFF_V, ws + OFF_WCOEF, ws + OFF_C,
                       ws + OFF_PART, ws + OFF_ATTNU, (s == 3) ? 1 : 0);
    if (s < 3) {
      hipLaunchKernelGGL(rK, dim3(64), dim3(512), 0, stream,
                         ws + OFF_PART, ws + OFF_MU, ws + OFF_WCOEF, ws + OFF_C, w);
    }
  }
  hipLaunchKernelGGL(oK, dim3(192), dim3(512), 0, stream,
                     ws + OFF_PART, ws + OFF_MU, w, oW1 /*unused*/ == oW1 ? ws + OFF_OW1T : nullptr,
                     ob1, ws + OFF_OW2T, ob2, ws + OFF_ATTNU, out);
}

// Round 7
// 208.320 us; speedup vs baseline: 4.6825x; 1.1246x over previous
//
#include <hip/hip_runtime.h>
#include <math.h>

#define B_ 4
#define N_ 4096
#define D_ 128
#define NS_ 16
#define NT_ 64
#define SCALE_ 0.08838834764831843f
#define EPS_ 1e-10f

// workspace offsets (floats)
#define OFF_K      ((size_t)0)
#define OFF_V      (OFF_K + (size_t)B_*N_*D_)
#define OFF_WTKV   (OFF_V + (size_t)B_*N_*D_)
#define OFF_WQT    (OFF_WTKV + 128*256)
#define OFF_WC     (OFF_WQT + 128*128)
#define OFF_MW1T   (OFF_WC + 256*512)
#define OFF_MW2T   (OFF_MW1T + 128*512)
#define OFF_OW1T   (OFF_MW2T + 512*128)
#define OFF_OW2T   (OFF_OW1T + 256*1024)
#define OFF_MU     (OFF_OW2T + 1024*128)
#define OFF_WCOEF  (OFF_MU + (size_t)B_*NS_*128)
#define OFF_C      (OFF_WCOEF + (size_t)B_*128*32)
#define OFF_PART   (OFF_C + 64)
#define OFF_ATTNU  (OFF_PART + (size_t)B_*NT_*NS_*260)

// slot scratch offsets (floats)
#define S_ZS    0     /* 256 */
#define S_S2    256   /* 128 */
#define S_UU    384   /* 128 */
#define S_H2    512   /* 128 */
#define S_A1S   640   /* 512 */
#define S_SNEW  1152  /* 256 */
#define S_QM    1408  /* 128 */
#define S_QL    1536  /* 128 */
#define S_RED   1664  /* 1024 (also h1 in oK) */
#define S_P1    2688  /* 1024 partial scratch */
#define S_TOT   3712

// transposed-weight + bias bundle
struct SW {
  const float* wc;    // [256][512] unified GRU
  const float* mw1T;  // [128][512]
  const float* mw2T;  // [512][128]
  const float* wqT;   // [128][128]
  const float* bih; const float* bhh;
  const float* mb1; const float* mb2;
  const float* gmu; const float* bmu;
  const float* gsl; const float* bsl;
};

template <int T>
__device__ __forceinline__ float bRedT(float v, float* red, int tid) {
  red[tid] = v;
  __syncthreads();
  if (T >= 1024) {
    if (tid < 512) red[tid] += red[tid + 512];
    __syncthreads();
  }
  if (tid < 256) red[tid] += red[tid + 256];
  __syncthreads();
  if (tid < 128) red[tid] += red[tid + 128];
  __syncthreads();
  if (tid < 64) {
    float x = red[tid] + red[tid + 64];
    #pragma unroll
    for (int off = 32; off > 0; off >>= 1) x += __shfl_down(x, off, 64);
    if (tid == 0) red[0] = x;
  }
  __syncthreads();
  float r = red[0];
  __syncthreads();
  return r;
}

// input: sl[S_A1S..+255] = LN'd slot row. Coalesced wqT columns. T = block threads.
template <int T>
__device__ __forceinline__ void slotTailT(float* sl, int b, int i, int tid,
    const float* __restrict__ wqT, float* wcoef, float* cbuf) {
  constexpr int KG = T / 256;
  constexpr int DD = 128 / KG;
  {
    int rest = tid & 255, kg = tid >> 8;
    int wh = rest >> 7, o = rest & 127;
    float acc = 0.f;
    #pragma unroll
    for (int dd = 0; dd < DD; ++dd)
      acc = fmaf(sl[S_A1S + wh * 128 + kg * DD + dd], wqT[(kg * DD + dd) * 128 + o], acc);
    sl[S_P1 + kg * 256 + rest] = acc;
  }
  __syncthreads();
  if (tid < 256) {
    float q = 0.f;
    #pragma unroll
    for (int g = 0; g < KG; ++g) q += sl[S_P1 + g * 256 + tid];
    if (tid < 128) sl[S_QM + tid] = q; else sl[S_QL + (tid - 128)] = q;
  }
  __syncthreads();
  float cp = 0.f;
  if (tid < 128) {
    float iv = expf(-2.f * sl[S_QL + tid]);
    float a1 = SCALE_ * iv;
    float a2 = -2.f * SCALE_ * iv * sl[S_QM + tid];
    float* wrow = &wcoef[((size_t)b * 128 + tid) * 32];
    wrow[2 * i] = a2;
    wrow[2 * i + 1] = a1;
    cp = SCALE_ * iv * sl[S_QM + tid] * sl[S_QM + tid];
  }
  float ctot = bRedT<T>(cp, sl + S_RED, tid);
  if (tid == 0) cbuf[b * NS_ + i] = ctot;
}

// 1024-thread slot update. FINAL=0: full incl. next-step prep. FINAL=1: stop with snew in LDS.
template <int FINAL>
__device__ void slotUpdateT(float* sl, int b, int i, int tid,
    const float* __restrict__ part, float* mu, float* wcoef, float* cbuf, SW w) {
  size_t pbase = ((size_t)(b * NT_) * NS_ + i) * 260;
  const size_t pstr = (size_t)NS_ * 260;
  // part reduce: 4 groups x 16 tiles
  {
    int g = tid >> 8, e = tid & 255;
    float s = 0.f;
    #pragma unroll 16
    for (int t = 0; t < 16; ++t) s += part[pbase + (size_t)(g * 16 + t) * pstr + e];
    sl[S_P1 + g * 256 + e] = s;
  }
  float rp = (tid < 64) ? part[pbase + (size_t)tid * pstr + 256] : 0.f;
  float rt = bRedT<1024>(rp, sl + S_RED, tid);  // internal syncs cover S_P1 writes
  if (tid < 256) {
    float s = sl[S_P1 + tid] + sl[S_P1 + 256 + tid] + sl[S_P1 + 512 + tid] + sl[S_P1 + 768 + tid];
    if (tid < 128) sl[S_ZS + tid] = s / rt; else sl[S_S2 + tid - 128] = s / rt;
  } else if (tid < 384) {
    sl[S_ZS + tid - 128] = mu[(size_t)(b * NS_ + i) * 128 + (tid - 256)];
  }
  __syncthreads();
  // GRU matvec: 512 outputs, 2-way K-split, 2 chains each
  {
    int q = tid & 511, kg = tid >> 9;
    const float* wcol = w.wc + (size_t)(kg * 128) * 512 + q;
    const float* xz = sl + S_ZS + kg * 128;
    float a0 = 0.f, a1 = 0.f;
    #pragma unroll 16
    for (int dd = 0; dd < 128; dd += 2) {
      a0 = fmaf(xz[dd], wcol[dd * 512], a0);
      a1 = fmaf(xz[dd + 1], wcol[(dd + 1) * 512], a1);
    }
    sl[S_P1 + kg * 512 + q] = a0 + a1;
  }
  __syncthreads();
  if (tid < 128) {
    float o_r = sl[S_P1 + tid] + sl[S_P1 + 512 + tid];
    float o_z = sl[S_P1 + 128 + tid] + sl[S_P1 + 640 + tid];
    float o_n = sl[S_P1 + 256 + tid] + sl[S_P1 + 768 + tid];
    float o_g = sl[S_P1 + 384 + tid] + sl[S_P1 + 896 + tid];
    float r = 1.f / (1.f + expf(-(o_r + w.bih[tid] + w.bhh[tid])));
    float z = 1.f / (1.f + expf(-(o_z + w.bih[128 + tid] + w.bhh[128 + tid])));
    float nn = tanhf(o_n + w.bih[256 + tid] + r * (o_g + w.bhh[256 + tid]));
    sl[S_UU + tid] = (1.f - z) * nn + z * sl[S_ZS + 128 + tid];
  }
  __syncthreads();
  // LN(u)
  float uv = (tid < 128) ? sl[S_UU + tid] : 0.f;
  float m = bRedT<1024>(uv, sl + S_RED, tid) * (1.f / 128.f);
  float dv = (tid < 128) ? (sl[S_UU + tid] - m) : 0.f;
  float var = bRedT<1024>(dv * dv, sl + S_RED, tid) * (1.f / 128.f);
  float rsq = rsqrtf(var + 1e-5f);
  if (tid < 128) sl[S_H2 + tid] = dv * rsq * w.gmu[tid] + w.bmu[tid];
  __syncthreads();
  // MLP up: 512 outputs, 2-way K-split, 2 chains
  {
    int q = tid & 511, kg = tid >> 9;
    const float* h = sl + S_H2 + kg * 64;
    float a0 = 0.f, a1 = 0.f;
    #pragma unroll 16
    for (int dd = 0; dd < 64; dd += 2) {
      a0 = fmaf(h[dd], w.mw1T[(kg * 64 + dd) * 512 + q], a0);
      a1 = fmaf(h[dd + 1], w.mw1T[(kg * 64 + dd + 1) * 512 + q], a1);
    }
    sl[S_P1 + kg * 512 + q] = a0 + a1;
  }
  __syncthreads();
  if (tid < 512)
    sl[S_A1S + tid] = fmaxf(sl[S_P1 + tid] + sl[S_P1 + 512 + tid] + w.mb1[tid], 0.f);
  __syncthreads();
  // MLP down: 128 outputs, 8-way K-split
  {
    int d = tid & 127, qg = tid >> 7;
    const float* a = sl + S_A1S + qg * 64;
    float b0 = 0.f, b1 = 0.f;
    #pragma unroll 16
    for (int qq = 0; qq < 64; qq += 2) {
      b0 = fmaf(a[qq], w.mw2T[(qg * 64 + qq) * 128 + d], b0);
      b1 = fmaf(a[qq + 1], w.mw2T[(qg * 64 + qq + 1) * 128 + d], b1);
    }
    sl[S_P1 + qg * 128 + d] = b0 + b1;
  }
  __syncthreads();
  if (tid < 128) {
    float o = w.mb2[tid];
    #pragma unroll
    for (int g = 0; g < 8; ++g) o += sl[S_P1 + g * 128 + tid];
    float uf = sl[S_UU + tid] + o;
    float xsv = sl[S_ZS + tid];
    float arg = sl[S_S2 + tid] - 2.f * uf * xsv + uf * uf + EPS_;
    float lsv = 0.5f * logf(fmaxf(arg, 1e-30f));
    sl[S_SNEW + tid] = uf;
    sl[S_SNEW + 128 + tid] = lsv;
  }
  __syncthreads();
  if (FINAL) return;  // snew in LDS is the product
  // next-step LN over new slot row
  float x = (tid < 256) ? sl[S_SNEW + tid] : 0.f;
  float m2 = bRedT<1024>(x, sl + S_RED, tid) * (1.f / 256.f);
  float d2 = (tid < 256) ? (sl[S_SNEW + tid] - m2) : 0.f;
  float v2 = bRedT<1024>(d2 * d2, sl + S_RED, tid) * (1.f / 256.f);
  float rs2 = rsqrtf(v2 + 1e-5f);
  if (tid < 256) {
    float slv = d2 * rs2 * w.gsl[tid] + w.bsl[tid];
    sl[S_A1S + tid] = slv;
    if (tid < 128) mu[(size_t)(b * NS_ + i) * 128 + tid] = slv;
  }
  __syncthreads();
  slotTailT<1024>(sl, b, i, tid, w.wqT, wcoef, cbuf);
}

// ---------- tK: build all transposed weights (write-coalesced) ----------
__global__ __launch_bounds__(256) void tK(
    const float* __restrict__ Wq, const float* __restrict__ Wk, const float* __restrict__ Wv,
    const float* __restrict__ Wih, const float* __restrict__ Whh,
    const float* __restrict__ mW1, const float* __restrict__ mW2,
    const float* __restrict__ oW1, const float* __restrict__ oW2,
    float* __restrict__ ws) {
  int tid = blockIdx.x * blockDim.x + threadIdx.x;
  int stride = gridDim.x * blockDim.x;
  for (int idx = tid; idx < 128 * 256; idx += stride) {
    int kk = idx >> 8, c = idx & 255;
    ws[OFF_WTKV + idx] = (c < 128) ? Wk[c * 128 + kk] : Wv[(c - 128) * 128 + kk];
  }
  for (int idx = tid; idx < 128 * 128; idx += stride) {
    int kk = idx >> 7, o = idx & 127;
    ws[OFF_WQT + idx] = Wq[o * 128 + kk];
  }
  for (int idx = tid; idx < 256 * 512; idx += stride) {
    int dd = idx >> 9, q = idx & 511;
    float v;
    if (dd < 128) {
      v = (q < 384) ? Wih[q * 128 + dd] : 0.f;
    } else {
      int dh = dd - 128;
      if (q < 256) v = Whh[q * 128 + dh];
      else if (q < 384) v = 0.f;
      else v = Whh[(q - 128) * 128 + dh];
    }
    ws[OFF_WC + idx] = v;
  }
  for (int idx = tid; idx < 128 * 512; idx += stride) {
    int dd = idx >> 9, q = idx & 511;
    ws[OFF_MW1T + idx] = mW1[q * 128 + dd];
  }
  for (int idx = tid; idx < 512 * 128; idx += stride) {
    int q = idx >> 7, d = idx & 127;
    ws[OFF_MW2T + idx] = mW2[d * 512 + q];
  }
  for (int idx = tid; idx < 256 * 1024; idx += stride) {
    int dd = idx >> 10, q = idx & 1023;
    ws[OFF_OW1T + idx] = oW1[q * 256 + dd];
  }
  for (int idx = tid; idx < 1024 * 128; idx += stride) {
    int q = idx >> 7, d = idx & 127;
    ws[OFF_OW2T + idx] = oW2[d * 1024 + q];
  }
}

// ---------- kvK: LN(inputs)+k/v GEMM (0..255) + initial slot prep (256..319) ----------
__global__ __launch_bounds__(512) void kvK(const float* __restrict__ inp,
    const float* __restrict__ wt, const float* __restrict__ gin, const float* __restrict__ bin,
    const float* __restrict__ slots_in, SW w,
    float* __restrict__ kb, float* __restrict__ vb,
    float* __restrict__ mu, float* wcoef, float* cbuf) {
  __shared__ __align__(16) float shm[8896];
  int tid = threadIdx.x;
  int blk = blockIdx.x;
  if (blk < 256) {
    float* xs = shm;            // [64][129]
    float* red = shm + 8256;    // [64][8]
    float* mrow = shm + 8768;
    float* rrow = shm + 8832;
    int rowbase = blk * 64;
    #pragma unroll
    for (int it = 0; it < 4; ++it) {
      int f = tid + it * 512;
      int row = f >> 5, c4 = (f & 31) * 4;
      const float4 v = *(const float4*)&inp[(size_t)(rowbase + row) * 128 + c4];
      float* xr = &xs[row * 129 + c4];
      xr[0] = v.x; xr[1] = v.y; xr[2] = v.z; xr[3] = v.w;
    }
    __syncthreads();
    int row = tid >> 3, part = tid & 7;
    float s = 0.f;
    #pragma unroll
    for (int e = 0; e < 16; ++e) s += xs[row * 129 + part * 16 + e];
    red[row * 8 + part] = s;
    __syncthreads();
    if (part == 0) {
      float m = 0.f;
      #pragma unroll
      for (int q = 0; q < 8; ++q) m += red[row * 8 + q];
      mrow[row] = m * (1.f / 128.f);
    }
    __syncthreads();
    float m = mrow[row];
    s = 0.f;
    #pragma unroll
    for (int e = 0; e < 16; ++e) { float d = xs[row * 129 + part * 16 + e] - m; s += d * d; }
    red[row * 8 + part] = s;
    __syncthreads();
    if (part == 0) {
      float v = 0.f;
      #pragma unroll
      for (int q = 0; q < 8; ++q) v += red[row * 8 + q];
      rrow[row] = rsqrtf(v * (1.f / 128.f) + 1e-5f);
    }
    __syncthreads();
    float rs = rrow[row];
    #pragma unroll
    for (int e = 0; e < 16; ++e) {
      int c = part * 16 + e;
      xs[row * 129 + c] = (xs[row * 129 + c] - m) * rs * gin[c] + bin[c];
    }
    __syncthreads();
    int l = tid & 63;
    int wv = __builtin_amdgcn_readfirstlane(threadIdx.x >> 6);
    for (int pass = 0; pass < 2; ++pass) {
      int cbase = pass * 128 + wv * 16;
      float acc[16];
      #pragma unroll
      for (int e = 0; e < 16; ++e) acc[e] = 0.f;
      #pragma unroll 4
      for (int kk = 0; kk < 128; ++kk) {
        float a = xs[l * 129 + kk];
        const float* wr = &wt[kk * 256 + cbase];  // wave-uniform -> s_load
        #pragma unroll
        for (int e = 0; e < 16; ++e) acc[e] = fmaf(a, wr[e], acc[e]);
      }
      float* outp = (cbase < 128) ? kb : vb;
      int col = cbase & 127;
      size_t o = (size_t)(rowbase + l) * 128 + col;
      #pragma unroll
      for (int e4 = 0; e4 < 4; ++e4)
        *(float4*)&outp[o + e4 * 4] =
            make_float4(acc[e4 * 4], acc[e4 * 4 + 1], acc[e4 * 4 + 2], acc[e4 * 4 + 3]);
    }
  } else {
    float* sl = shm;
    int sb = blk - 256;
    int b2 = sb >> 4, i = sb & 15;
    float x = (tid < 256) ? slots_in[(size_t)(b2 * NS_ + i) * 256 + tid] : 0.f;
    float m = bRedT<512>(x, sl + S_RED, tid) * (1.f / 256.f);
    float d = (tid < 256) ? (x - m) : 0.f;
    float var = bRedT<512>(d * d, sl + S_RED, tid) * (1.f / 256.f);
    float rs = rsqrtf(var + 1e-5f);
    if (tid < 256) {
      float slv = d * rs * w.gsl[tid] + w.bsl[tid];
      sl[S_A1S + tid] = slv;
      if (tid < 128) mu[(size_t)(b2 * NS_ + i) * 128 + tid] = slv;
    }
    __syncthreads();
    slotTailT<512>(sl, b2, i, tid, w.wqT, wcoef, cbuf);
  }
}

// ---------- pK: token pass per step ----------
__global__ __launch_bounds__(512) void pK(const float* __restrict__ kb,
    const float* __restrict__ vb, const float* __restrict__ wcoef,
    const float* __restrict__ cbuf, float* __restrict__ part,
    float* __restrict__ attnu, int last) {
  __shared__ __align__(16) float buf[8448];   // K as [64][129], then V as [64][132]
  __shared__ float a1s[16 * 66];
  __shared__ float esum[8 * 64];
  int tid = threadIdx.x;
  int jt = blockIdx.x, b = blockIdx.y;
  size_t jrow = (size_t)(b * N_ + jt * 64);
  #pragma unroll
  for (int it = 0; it < 4; ++it) {
    int f = tid + it * 512;
    int row = f >> 5, c4 = (f & 31) * 4;
    float4 kv = *(const float4*)&kb[(jrow + row) * 128 + c4];
    float* kr = &buf[row * 129 + c4];
    kr[0] = kv.x; kr[1] = kv.y; kr[2] = kv.z; kr[3] = kv.w;
  }
  __syncthreads();
  {
    int l = tid & 63;
    int w = __builtin_amdgcn_readfirstlane(threadIdx.x >> 6);
    int i0 = 2 * w, i1 = 2 * w + 1;
    const float* wb = &wcoef[(size_t)b * 128 * 32];
    float d0a = cbuf[b * NS_ + i0], d1a = cbuf[b * NS_ + i1];
    float d0b = 0.f, d1b = 0.f;
    #pragma unroll 4
    for (int kk = 0; kk < 128; kk += 2) {
      float kv0 = buf[l * 129 + kk];
      float kv1 = buf[l * 129 + kk + 1];
      float4 wv0 = *(const float4*)&wb[kk * 32 + 4 * w];
      float4 wv1 = *(const float4*)&wb[(kk + 1) * 32 + 4 * w];
      d0a = fmaf(fmaf(wv0.y, kv0, wv0.x), kv0, d0a);
      d1a = fmaf(fmaf(wv0.w, kv0, wv0.z), kv0, d1a);
      d0b = fmaf(fmaf(wv1.y, kv1, wv1.x), kv1, d0b);
      d1b = fmaf(fmaf(wv1.w, kv1, wv1.z), kv1, d1b);
    }
    float e0 = expf(-(d0a + d0b)) + EPS_;
    float e1 = expf(-(d1a + d1b)) + EPS_;
    esum[w * 64 + l] = e0 + e1;
    __syncthreads();
    float tot = 0.f;
    #pragma unroll
    for (int q = 0; q < 8; ++q) tot += esum[q * 64 + l];
    float a0 = e0 / tot, a1v = e1 / tot;
    a1s[i0 * 66 + l] = a0;
    a1s[i1 * 66 + l] = a1v;
    if (last) {
      attnu[(size_t)(b * NS_ + i0) * N_ + jt * 64 + l] = a0;
      attnu[(size_t)(b * NS_ + i1) * N_ + jt * 64 + l] = a1v;
    }
  }
  __syncthreads();
  #pragma unroll
  for (int it = 0; it < 4; ++it) {
    int f = tid + it * 512;
    int row = f >> 5, c4 = (f & 31) * 4;
    float4 vv = *(const float4*)&vb[(jrow + row) * 128 + c4];
    *(float4*)&buf[row * 132 + c4] = vv;
  }
  __syncthreads();
  {
    int ii = tid >> 5, dg = tid & 31;
    float av0 = 0, av1 = 0, av2 = 0, av3 = 0, aw0 = 0, aw1 = 0, aw2 = 0, aw3 = 0, rsum = 0;
    #pragma unroll 4
    for (int j = 0; j < 64; ++j) {
      float a = a1s[ii * 66 + j];
      const float4 v4 = *(const float4*)&buf[j * 132 + dg * 4];
      rsum += a;
      float m0 = a * v4.x, m1 = a * v4.y, m2 = a * v4.z, m3 = a * v4.w;
      av0 += m0; av1 += m1; av2 += m2; av3 += m3;
      aw0 = fmaf(m0, v4.x, aw0); aw1 = fmaf(m1, v4.y, aw1);
      aw2 = fmaf(m2, v4.z, aw2); aw3 = fmaf(m3, v4.w, aw3);
    }
    float* pr = &part[((size_t)(b * NT_ + jt) * NS_ + ii) * 260];
    *(float4*)&pr[dg * 4] = make_float4(av0, av1, av2, av3);
    *(float4*)&pr[128 + dg * 4] = make_float4(aw0, aw1, aw2, aw3);
    if (dg == 0) pr[256] = rsum;
  }
}

// ---------- rK: per-slot update (steps 0..2), 64 blocks x 1024 ----------
__global__ __launch_bounds__(1024, 1) void rK(const float* __restrict__ part,
    float* mu, float* wcoef, float* cbuf, SW w) {
  __shared__ __align__(16) float sl[S_TOT];
  int tid = threadIdx.x;
  int b = blockIdx.x >> 4, i = blockIdx.x & 15;
  slotUpdateT<0>(sl, b, i, tid, part, mu, wcoef, cbuf, w);
}

// ---------- oK: final slot update + out MLP (0..63) + attn normalize (64..127) ----------
__global__ __launch_bounds__(1024, 1) void oK(const float* __restrict__ part,
    float* mu, SW w,
    const float* __restrict__ ow1T, const float* __restrict__ ob1,
    const float* __restrict__ ow2T, const float* __restrict__ ob2,
    const float* __restrict__ attnu, float* __restrict__ out) {
  __shared__ __align__(16) float sl[S_TOT];
  int blk = blockIdx.x, tid = threadIdx.x;
  const size_t pstr = (size_t)NS_ * 260;
  if (blk >= 64) {
    int r = blk - 64;                   // (b,i) row 0..63
    int b = r >> 4, i = r & 15;
    size_t pbase = ((size_t)(b * NT_) * NS_ + i) * 260;
    if (tid < 64) {
      float v = part[pbase + (size_t)tid * pstr + 256];
      #pragma unroll
      for (int off = 32; off > 0; off >>= 1) v += __shfl_down(v, off, 64);
      if (tid == 0) sl[0] = v;
    }
    __syncthreads();
    float rs = sl[0];
    int base = r * 4096 + tid * 4;
    float4 v = *(const float4*)&attnu[base];
    v.x /= rs; v.y /= rs; v.z /= rs; v.w /= rs;
    *(float4*)&out[8192 + base] = v;
    return;
  }
  int b = blk >> 4, i = blk & 15;
  slotUpdateT<1>(sl, b, i, tid, part, mu, (float*)nullptr, (float*)nullptr, w);
  // out-MLP up: 1024 outputs, 1/thread, 2 chains; h1 -> S_RED
  {
    const float* sn = sl + S_SNEW;
    float a0 = 0.f, a1 = 0.f;
    #pragma unroll 16
    for (int dd = 0; dd < 128; ++dd) {
      a0 = fmaf(sn[dd], ow1T[dd * 1024 + tid], a0);
      a1 = fmaf(sn[128 + dd], ow1T[(128 + dd) * 1024 + tid], a1);
    }
    sl[S_RED + tid] = fmaxf(a0 + a1 + ob1[tid], 0.f);
  }
  __syncthreads();
  // out-MLP down: 128 outputs, 8-way K-split
  {
    int d = tid & 127, qg = tid >> 7;
    const float* h = sl + S_RED + qg * 128;
    float b0 = 0.f, b1 = 0.f;
    #pragma unroll 16
    for (int qq = 0; qq < 128; qq += 2) {
      b0 = fmaf(h[qq], ow2T[(qg * 128 + qq) * 128 + d], b0);
      b1 = fmaf(h[qq + 1], ow2T[(qg * 128 + qq + 1) * 128 + d], b1);
    }
    sl[S_P1 + qg * 128 + d] = b0 + b1;
  }
  __syncthreads();
  if (tid < 128) {
    float o = ob2[tid];
    #pragma unroll
    for (int g = 0; g < 8; ++g) o += sl[S_P1 + g * 128 + tid];
    out[(size_t)blk * 128 + tid] = o;
  }
}

extern "C" void kernel_launch(void* const* d_in, const int* in_sizes, int n_in,
                              void* d_out, int out_size, void* d_ws, size_t ws_size,
                              hipStream_t stream) {
  const float* slots_in = (const float*)d_in[0];
  const float* inputs   = (const float*)d_in[1];
  const float* Wq  = (const float*)d_in[2];
  const float* Wk  = (const float*)d_in[3];
  const float* Wv  = (const float*)d_in[4];
  const float* Wih = (const float*)d_in[5];
  const float* Whh = (const float*)d_in[6];
  const float* bih = (const float*)d_in[7];
  const float* bhh = (const float*)d_in[8];
  const float* mW1 = (const float*)d_in[9];
  const float* mb1 = (const float*)d_in[10];
  const float* mW2 = (const float*)d_in[11];
  const float* mb2 = (const float*)d_in[12];
  const float* g_in  = (const float*)d_in[13];
  const float* be_in = (const float*)d_in[14];
  const float* g_sl  = (const float*)d_in[15];
  const float* be_sl = (const float*)d_in[16];
  const float* g_mu  = (const float*)d_in[17];
  const float* be_mu = (const float*)d_in[18];
  const float* oW1 = (const float*)d_in[19];
  const float* ob1 = (const float*)d_in[20];
  const float* oW2 = (const float*)d_in[21];
  const float* ob2 = (const float*)d_in[22];
  float* ws  = (float*)d_ws;
  float* out = (float*)d_out;
  (void)in_sizes; (void)n_in; (void)out_size; (void)ws_size;

  SW w;
  w.wc = ws + OFF_WC; w.mw1T = ws + OFF_MW1T; w.mw2T = ws + OFF_MW2T; w.wqT = ws + OFF_WQT;
  w.bih = bih; w.bhh = bhh; w.mb1 = mb1; w.mb2 = mb2;
  w.gmu = g_mu; w.bmu = be_mu; w.gsl = g_sl; w.bsl = be_sl;

  hipLaunchKernelGGL(tK, dim3(128), dim3(256), 0, stream,
                     Wq, Wk, Wv, Wih, Whh, mW1, mW2, oW1, oW2, ws);
  hipLaunchKernelGGL(kvK, dim3(320), dim3(512), 0, stream,
                     inputs, ws + OFF_WTKV, g_in, be_in, slots_in, w,
                     ws + OFF_K, ws + OFF_V, ws + OFF_MU, ws + OFF_WCOEF, ws + OFF_C);
  for (int s = 0; s < 4; ++s) {
    hipLaunchKernelGGL(pK, dim3(64, 4), dim3(512), 0, stream,
                       ws + OFF_K, ws + OFF_V, ws + OFF_WCOEF, ws + OFF_C,
                       ws + OFF_PART, ws + OFF_ATTNU, (s == 3) ? 1 : 0);
    if (s < 3) {
      hipLaunchKernelGGL(rK, dim3(64), dim3(1024), 0, stream,
                         ws + OFF_PART, ws + OFF_MU, ws + OFF_WCOEF, ws + OFF_C, w);
    }
  }
  hipLaunchKernelGGL(oK, dim3(128), dim3(1024), 0, stream,
                     ws + OFF_PART, ws + OFF_MU, w, ws + OFF_OW1T, ob1,
                     ws + OFF_OW2T, ob2, ws + OFF_ATTNU, out);
}

// Round 8
// 180.364 us; speedup vs baseline: 5.4083x; 1.1550x over previous
//
#include <hip/hip_runtime.h>
#include <math.h>

#define B_ 4
#define N_ 4096
#define D_ 128
#define NS_ 16
#define NT_ 64
#define SCALE_ 0.08838834764831843f
#define EPS_ 1e-10f

// workspace offsets (in 4-byte words)
#define OFF_K      ((size_t)0)
#define OFF_V      (OFF_K + (size_t)B_*N_*D_)
#define OFF_WTKV   (OFF_V + (size_t)B_*N_*D_)   /* f32 [128][256] */
#define OFF_WCP    (OFF_WTKV + 128*256)          /* uint [128][512] packed bf16 pairs */
#define OFF_M1P    (OFF_WCP + 128*512)           /* uint [64][512] */
#define OFF_M2P    (OFF_M1P + 64*512)            /* uint [256][128] */
#define OFF_WQP    (OFF_M2P + 256*128)           /* uint [64][128] */
#define OFF_O1P    (OFF_WQP + 64*128)            /* uint [128][1024] */
#define OFF_O2P    (OFF_O1P + 128*1024)          /* uint [512][128] */
#define OFF_MU     (OFF_O2P + 512*128)
#define OFF_WCOEF  (OFF_MU + (size_t)B_*NS_*128)
#define OFF_C      (OFF_WCOEF + (size_t)B_*128*32)
#define OFF_PART   (OFF_C + 64)
#define OFF_ATTNU  (OFF_PART + (size_t)B_*NT_*NS_*260)

// slot scratch offsets (floats)
#define S_ZS    0     /* 256 */
#define S_S2    256   /* 128 */
#define S_UU    384   /* 128 */
#define S_H2    512   /* 128 */
#define S_A1S   640   /* 512 */
#define S_SNEW  1152  /* 256 */
#define S_QM    1408  /* 128 */
#define S_QL    1536  /* 128 */
#define S_RED   1664  /* 1024 (also h1 in oK) */
#define S_P1    2688  /* 1024 partial scratch */
#define S_TOT   3712

__device__ __forceinline__ float bf_lo(unsigned p) { return __uint_as_float(p << 16); }
__device__ __forceinline__ float bf_hi(unsigned p) { return __uint_as_float(p & 0xffff0000u); }
__device__ __forceinline__ unsigned packbf(float lo, float hi) {
  unsigned ul = __float_as_uint(lo), uh = __float_as_uint(hi);
  ul = (ul + 0x7fffu + ((ul >> 16) & 1u)) >> 16;
  uh = (uh + 0x7fffu + ((uh >> 16) & 1u)) >> 16;
  return (ul & 0xffffu) | (uh << 16);
}

// packed-weight + bias bundle
struct SW {
  const unsigned* wcP;   // [128][512] GRU (K=256 packed in pairs)
  const unsigned* m1P;   // [64][512]
  const unsigned* m2P;   // [256][128]
  const unsigned* wqP;   // [64][128]
  const float* bih; const float* bhh;
  const float* mb1; const float* mb2;
  const float* gmu; const float* bmu;
  const float* gsl; const float* bsl;
};

template <int T>
__device__ __forceinline__ float bRedT(float v, float* red, int tid) {
  red[tid] = v;
  __syncthreads();
  if (T >= 1024) {
    if (tid < 512) red[tid] += red[tid + 512];
    __syncthreads();
  }
  if (tid < 256) red[tid] += red[tid + 256];
  __syncthreads();
  if (tid < 128) red[tid] += red[tid + 128];
  __syncthreads();
  if (tid < 64) {
    float x = red[tid] + red[tid + 64];
    #pragma unroll
    for (int off = 32; off > 0; off >>= 1) x += __shfl_down(x, off, 64);
    if (tid == 0) red[0] = x;
  }
  __syncthreads();
  float r = red[0];
  __syncthreads();
  return r;
}

// input: sl[S_A1S..+255] = LN'd slot row. T = block threads (512 or 1024).
template <int T>
__device__ __forceinline__ void slotTailT(float* sl, int b, int i, int tid,
    const unsigned* __restrict__ wqP, float* wcoef, float* cbuf) {
  constexpr int KG = T / 256;    // 2 or 4
  constexpr int RR = 64 / KG;    // packed rows per group
  {
    int rest = tid & 255, kg = tid >> 8;
    int wh = rest >> 7, o = rest & 127;
    const unsigned* wq = wqP + (size_t)(kg * RR) * 128 + o;
    const float* s = sl + S_A1S + wh * 128 + kg * (128 / KG);
    float a0 = 0.f, a1 = 0.f;
    #pragma unroll
    for (int r = 0; r < RR; ++r) {
      unsigned p = wq[r * 128];
      a0 = fmaf(s[2 * r], bf_lo(p), a0);
      a1 = fmaf(s[2 * r + 1], bf_hi(p), a1);
    }
    sl[S_P1 + kg * 256 + rest] = a0 + a1;
  }
  __syncthreads();
  if (tid < 256) {
    float q = 0.f;
    #pragma unroll
    for (int g = 0; g < KG; ++g) q += sl[S_P1 + g * 256 + tid];
    if (tid < 128) sl[S_QM + tid] = q; else sl[S_QL + (tid - 128)] = q;
  }
  __syncthreads();
  float cp = 0.f;
  if (tid < 128) {
    float iv = expf(-2.f * sl[S_QL + tid]);
    float a1 = SCALE_ * iv;
    float a2 = -2.f * SCALE_ * iv * sl[S_QM + tid];
    float* wrow = &wcoef[((size_t)b * 128 + tid) * 32];
    wrow[2 * i] = a2;
    wrow[2 * i + 1] = a1;
    cp = SCALE_ * iv * sl[S_QM + tid] * sl[S_QM + tid];
  }
  float ctot = bRedT<T>(cp, sl + S_RED, tid);
  if (tid == 0) cbuf[b * NS_ + i] = ctot;
}

// 1024-thread slot update. FINAL=0: full incl. next-step prep. FINAL=1: stop with snew in LDS.
template <int FINAL>
__device__ void slotUpdateT(float* sl, int b, int i, int tid,
    const float* __restrict__ part, float* mu, float* wcoef, float* cbuf, SW w) {
  size_t pbase = ((size_t)(b * NT_) * NS_ + i) * 260;
  const size_t pstr = (size_t)NS_ * 260;
  // part reduce: 4 groups x 16 tiles
  {
    int g = tid >> 8, e = tid & 255;
    float s = 0.f;
    #pragma unroll 16
    for (int t = 0; t < 16; ++t) s += part[pbase + (size_t)(g * 16 + t) * pstr + e];
    sl[S_P1 + g * 256 + e] = s;
  }
  float rp = (tid < 64) ? part[pbase + (size_t)tid * pstr + 256] : 0.f;
  float rt = bRedT<1024>(rp, sl + S_RED, tid);  // internal syncs cover S_P1 writes
  if (tid < 256) {
    float s = sl[S_P1 + tid] + sl[S_P1 + 256 + tid] + sl[S_P1 + 512 + tid] + sl[S_P1 + 768 + tid];
    if (tid < 128) sl[S_ZS + tid] = s / rt; else sl[S_S2 + tid - 128] = s / rt;
  } else if (tid < 384) {
    sl[S_ZS + tid - 128] = mu[(size_t)(b * NS_ + i) * 128 + (tid - 256)];
  }
  __syncthreads();
  // GRU matvec: 512 outputs, 2-way K-split, packed bf16 pairs
  {
    int q = tid & 511, kg = tid >> 9;
    const unsigned* wcol = w.wcP + (size_t)(kg * 64) * 512 + q;
    const float* xz = sl + S_ZS + kg * 128;
    float a0 = 0.f, a1 = 0.f;
    #pragma unroll 16
    for (int r = 0; r < 64; ++r) {
      unsigned p = wcol[r * 512];
      a0 = fmaf(xz[2 * r], bf_lo(p), a0);
      a1 = fmaf(xz[2 * r + 1], bf_hi(p), a1);
    }
    sl[S_P1 + kg * 512 + q] = a0 + a1;
  }
  __syncthreads();
  if (tid < 128) {
    float o_r = sl[S_P1 + tid] + sl[S_P1 + 512 + tid];
    float o_z = sl[S_P1 + 128 + tid] + sl[S_P1 + 640 + tid];
    float o_n = sl[S_P1 + 256 + tid] + sl[S_P1 + 768 + tid];
    float o_g = sl[S_P1 + 384 + tid] + sl[S_P1 + 896 + tid];
    float r = 1.f / (1.f + expf(-(o_r + w.bih[tid] + w.bhh[tid])));
    float z = 1.f / (1.f + expf(-(o_z + w.bih[128 + tid] + w.bhh[128 + tid])));
    float nn = tanhf(o_n + w.bih[256 + tid] + r * (o_g + w.bhh[256 + tid]));
    sl[S_UU + tid] = (1.f - z) * nn + z * sl[S_ZS + 128 + tid];
  }
  __syncthreads();
  // LN(u)
  float uv = (tid < 128) ? sl[S_UU + tid] : 0.f;
  float m = bRedT<1024>(uv, sl + S_RED, tid) * (1.f / 128.f);
  float dv = (tid < 128) ? (sl[S_UU + tid] - m) : 0.f;
  float var = bRedT<1024>(dv * dv, sl + S_RED, tid) * (1.f / 128.f);
  float rsq = rsqrtf(var + 1e-5f);
  if (tid < 128) sl[S_H2 + tid] = dv * rsq * w.gmu[tid] + w.bmu[tid];
  __syncthreads();
  // MLP up: 512 outputs, 2-way K-split, packed
  {
    int q = tid & 511, kg = tid >> 9;
    const unsigned* wc1 = w.m1P + (size_t)(kg * 32) * 512 + q;
    const float* h = sl + S_H2 + kg * 64;
    float a0 = 0.f, a1 = 0.f;
    #pragma unroll
    for (int r = 0; r < 32; ++r) {
      unsigned p = wc1[r * 512];
      a0 = fmaf(h[2 * r], bf_lo(p), a0);
      a1 = fmaf(h[2 * r + 1], bf_hi(p), a1);
    }
    sl[S_P1 + kg * 512 + q] = a0 + a1;
  }
  __syncthreads();
  if (tid < 512)
    sl[S_A1S + tid] = fmaxf(sl[S_P1 + tid] + sl[S_P1 + 512 + tid] + w.mb1[tid], 0.f);
  __syncthreads();
  // MLP down: 128 outputs, 8-way K-split, packed
  {
    int d = tid & 127, qg = tid >> 7;
    const unsigned* wc2 = w.m2P + (size_t)(qg * 32) * 128 + d;
    const float* a = sl + S_A1S + qg * 64;
    float b0 = 0.f, b1 = 0.f;
    #pragma unroll
    for (int r = 0; r < 32; ++r) {
      unsigned p = wc2[r * 128];
      b0 = fmaf(a[2 * r], bf_lo(p), b0);
      b1 = fmaf(a[2 * r + 1], bf_hi(p), b1);
    }
    sl[S_P1 + qg * 128 + d] = b0 + b1;
  }
  __syncthreads();
  if (tid < 128) {
    float o = w.mb2[tid];
    #pragma unroll
    for (int g = 0; g < 8; ++g) o += sl[S_P1 + g * 128 + tid];
    float uf = sl[S_UU + tid] + o;
    float xsv = sl[S_ZS + tid];
    float arg = sl[S_S2 + tid] - 2.f * uf * xsv + uf * uf + EPS_;
    float lsv = 0.5f * logf(fmaxf(arg, 1e-30f));
    sl[S_SNEW + tid] = uf;
    sl[S_SNEW + 128 + tid] = lsv;
  }
  __syncthreads();
  if (FINAL) return;  // snew in LDS is the product
  // next-step LN over new slot row
  float x = (tid < 256) ? sl[S_SNEW + tid] : 0.f;
  float m2 = bRedT<1024>(x, sl + S_RED, tid) * (1.f / 256.f);
  float d2 = (tid < 256) ? (sl[S_SNEW + tid] - m2) : 0.f;
  float v2 = bRedT<1024>(d2 * d2, sl + S_RED, tid) * (1.f / 256.f);
  float rs2 = rsqrtf(v2 + 1e-5f);
  if (tid < 256) {
    float slv = d2 * rs2 * w.gsl[tid] + w.bsl[tid];
    sl[S_A1S + tid] = slv;
    if (tid < 128) mu[(size_t)(b * NS_ + i) * 128 + tid] = slv;
  }
  __syncthreads();
  slotTailT<1024>(sl, b, i, tid, w.wqP, wcoef, cbuf);
}

// ---------- tK: k/v weight transpose (f32) + bf16-pack all slot/out weights ----------
__global__ __launch_bounds__(256) void tK(
    const float* __restrict__ Wq, const float* __restrict__ Wk, const float* __restrict__ Wv,
    const float* __restrict__ Wih, const float* __restrict__ Whh,
    const float* __restrict__ mW1, const float* __restrict__ mW2,
    const float* __restrict__ oW1, const float* __restrict__ oW2,
    float* __restrict__ ws) {
  int tid = blockIdx.x * blockDim.x + threadIdx.x;
  int stride = gridDim.x * blockDim.x;
  unsigned* wcP = (unsigned*)(ws + OFF_WCP);
  unsigned* m1P = (unsigned*)(ws + OFF_M1P);
  unsigned* m2P = (unsigned*)(ws + OFF_M2P);
  unsigned* wqP = (unsigned*)(ws + OFF_WQP);
  unsigned* o1P = (unsigned*)(ws + OFF_O1P);
  unsigned* o2P = (unsigned*)(ws + OFF_O2P);
  for (int idx = tid; idx < 128 * 256; idx += stride) {
    int kk = idx >> 8, c = idx & 255;
    ws[OFF_WTKV + idx] = (c < 128) ? Wk[c * 128 + kk] : Wv[(c - 128) * 128 + kk];
  }
  // wcP[r][q]: dd = 2r, 2r+1 of the virtual WC[256][512]
  for (int idx = tid; idx < 128 * 512; idx += stride) {
    int r = idx >> 9, q = idx & 511;
    float lo, hi;
    if (r < 64) {
      int dd = 2 * r;
      lo = (q < 384) ? Wih[q * 128 + dd] : 0.f;
      hi = (q < 384) ? Wih[q * 128 + dd + 1] : 0.f;
    } else {
      int dh = 2 * (r - 64);
      if (q < 256)      { lo = Whh[q * 128 + dh]; hi = Whh[q * 128 + dh + 1]; }
      else if (q < 384) { lo = 0.f; hi = 0.f; }
      else              { lo = Whh[(q - 128) * 128 + dh]; hi = Whh[(q - 128) * 128 + dh + 1]; }
    }
    wcP[idx] = packbf(lo, hi);
  }
  for (int idx = tid; idx < 64 * 512; idx += stride) {
    int r = idx >> 9, q = idx & 511;
    m1P[idx] = packbf(mW1[q * 128 + 2 * r], mW1[q * 128 + 2 * r + 1]);
  }
  for (int idx = tid; idx < 256 * 128; idx += stride) {
    int r = idx >> 7, d = idx & 127;
    m2P[idx] = packbf(mW2[d * 512 + 2 * r], mW2[d * 512 + 2 * r + 1]);
  }
  for (int idx = tid; idx < 64 * 128; idx += stride) {
    int r = idx >> 7, o = idx & 127;
    wqP[idx] = packbf(Wq[o * 128 + 2 * r], Wq[o * 128 + 2 * r + 1]);
  }
  for (int idx = tid; idx < 128 * 1024; idx += stride) {
    int r = idx >> 10, q = idx & 1023;
    o1P[idx] = packbf(oW1[q * 256 + 2 * r], oW1[q * 256 + 2 * r + 1]);
  }
  for (int idx = tid; idx < 512 * 128; idx += stride) {
    int r = idx >> 7, d = idx & 127;
    o2P[idx] = packbf(oW2[d * 1024 + 2 * r], oW2[d * 1024 + 2 * r + 1]);
  }
}

// ---------- kvK: LN(inputs)+k/v GEMM (0..255) + initial slot prep (256..319) ----------
__global__ __launch_bounds__(512) void kvK(const float* __restrict__ inp,
    const float* __restrict__ wt, const float* __restrict__ gin, const float* __restrict__ bin,
    const float* __restrict__ slots_in, SW w,
    float* __restrict__ kb, float* __restrict__ vb,
    float* __restrict__ mu, float* wcoef, float* cbuf) {
  __shared__ __align__(16) float shm[8896];
  int tid = threadIdx.x;
  int blk = blockIdx.x;
  if (blk < 256) {
    float* xs = shm;            // [64][129]
    float* red = shm + 8256;    // [64][8]
    float* mrow = shm + 8768;
    float* rrow = shm + 8832;
    int rowbase = blk * 64;
    #pragma unroll
    for (int it = 0; it < 4; ++it) {
      int f = tid + it * 512;
      int row = f >> 5, c4 = (f & 31) * 4;
      const float4 v = *(const float4*)&inp[(size_t)(rowbase + row) * 128 + c4];
      float* xr = &xs[row * 129 + c4];
      xr[0] = v.x; xr[1] = v.y; xr[2] = v.z; xr[3] = v.w;
    }
    __syncthreads();
    int row = tid >> 3, part = tid & 7;
    float s = 0.f;
    #pragma unroll
    for (int e = 0; e < 16; ++e) s += xs[row * 129 + part * 16 + e];
    red[row * 8 + part] = s;
    __syncthreads();
    if (part == 0) {
      float m = 0.f;
      #pragma unroll
      for (int q = 0; q < 8; ++q) m += red[row * 8 + q];
      mrow[row] = m * (1.f / 128.f);
    }
    __syncthreads();
    float m = mrow[row];
    s = 0.f;
    #pragma unroll
    for (int e = 0; e < 16; ++e) { float d = xs[row * 129 + part * 16 + e] - m; s += d * d; }
    red[row * 8 + part] = s;
    __syncthreads();
    if (part == 0) {
      float v = 0.f;
      #pragma unroll
      for (int q = 0; q < 8; ++q) v += red[row * 8 + q];
      rrow[row] = rsqrtf(v * (1.f / 128.f) + 1e-5f);
    }
    __syncthreads();
    float rs = rrow[row];
    #pragma unroll
    for (int e = 0; e < 16; ++e) {
      int c = part * 16 + e;
      xs[row * 129 + c] = (xs[row * 129 + c] - m) * rs * gin[c] + bin[c];
    }
    __syncthreads();
    int l = tid & 63;
    int wv = __builtin_amdgcn_readfirstlane(threadIdx.x >> 6);
    for (int pass = 0; pass < 2; ++pass) {
      int cbase = pass * 128 + wv * 16;
      float acc[16];
      #pragma unroll
      for (int e = 0; e < 16; ++e) acc[e] = 0.f;
      #pragma unroll 4
      for (int kk = 0; kk < 128; ++kk) {
        float a = xs[l * 129 + kk];
        const float* wr = &wt[kk * 256 + cbase];  // wave-uniform -> s_load
        #pragma unroll
        for (int e = 0; e < 16; ++e) acc[e] = fmaf(a, wr[e], acc[e]);
      }
      float* outp = (cbase < 128) ? kb : vb;
      int col = cbase & 127;
      size_t o = (size_t)(rowbase + l) * 128 + col;
      #pragma unroll
      for (int e4 = 0; e4 < 4; ++e4)
        *(float4*)&outp[o + e4 * 4] =
            make_float4(acc[e4 * 4], acc[e4 * 4 + 1], acc[e4 * 4 + 2], acc[e4 * 4 + 3]);
    }
  } else {
    float* sl = shm;
    int sb = blk - 256;
    int b2 = sb >> 4, i = sb & 15;
    float x = (tid < 256) ? slots_in[(size_t)(b2 * NS_ + i) * 256 + tid] : 0.f;
    float m = bRedT<512>(x, sl + S_RED, tid) * (1.f / 256.f);
    float d = (tid < 256) ? (x - m) : 0.f;
    float var = bRedT<512>(d * d, sl + S_RED, tid) * (1.f / 256.f);
    float rs = rsqrtf(var + 1e-5f);
    if (tid < 256) {
      float slv = d * rs * w.gsl[tid] + w.bsl[tid];
      sl[S_A1S + tid] = slv;
      if (tid < 128) mu[(size_t)(b2 * NS_ + i) * 128 + tid] = slv;
    }
    __syncthreads();
    slotTailT<512>(sl, b2, i, tid, w.wqP, wcoef, cbuf);
  }
}

// ---------- pK: token pass per step ----------
__global__ __launch_bounds__(512) void pK(const float* __restrict__ kb,
    const float* __restrict__ vb, const float* __restrict__ wcoef,
    const float* __restrict__ cbuf, float* __restrict__ part,
    float* __restrict__ attnu, int last) {
  __shared__ __align__(16) float buf[8448];   // K as [64][129], then V as [64][132]
  __shared__ float a1s[16 * 66];
  __shared__ float esum[8 * 64];
  int tid = threadIdx.x;
  int jt = blockIdx.x, b = blockIdx.y;
  size_t jrow = (size_t)(b * N_ + jt * 64);
  #pragma unroll
  for (int it = 0; it < 4; ++it) {
    int f = tid + it * 512;
    int row = f >> 5, c4 = (f & 31) * 4;
    float4 kv = *(const float4*)&kb[(jrow + row) * 128 + c4];
    float* kr = &buf[row * 129 + c4];
    kr[0] = kv.x; kr[1] = kv.y; kr[2] = kv.z; kr[3] = kv.w;
  }
  __syncthreads();
  {
    int l = tid & 63;
    int w = __builtin_amdgcn_readfirstlane(threadIdx.x >> 6);
    int i0 = 2 * w, i1 = 2 * w + 1;
    const float* wb = &wcoef[(size_t)b * 128 * 32];
    float d0a = cbuf[b * NS_ + i0], d1a = cbuf[b * NS_ + i1];
    float d0b = 0.f, d1b = 0.f;
    #pragma unroll 4
    for (int kk = 0; kk < 128; kk += 2) {
      float kv0 = buf[l * 129 + kk];
      float kv1 = buf[l * 129 + kk + 1];
      float4 wv0 = *(const float4*)&wb[kk * 32 + 4 * w];
      float4 wv1 = *(const float4*)&wb[(kk + 1) * 32 + 4 * w];
      d0a = fmaf(fmaf(wv0.y, kv0, wv0.x), kv0, d0a);
      d1a = fmaf(fmaf(wv0.w, kv0, wv0.z), kv0, d1a);
      d0b = fmaf(fmaf(wv1.y, kv1, wv1.x), kv1, d0b);
      d1b = fmaf(fmaf(wv1.w, kv1, wv1.z), kv1, d1b);
    }
    float e0 = expf(-(d0a + d0b)) + EPS_;
    float e1 = expf(-(d1a + d1b)) + EPS_;
    esum[w * 64 + l] = e0 + e1;
    __syncthreads();
    float tot = 0.f;
    #pragma unroll
    for (int q = 0; q < 8; ++q) tot += esum[q * 64 + l];
    float a0 = e0 / tot, a1v = e1 / tot;
    a1s[i0 * 66 + l] = a0;
    a1s[i1 * 66 + l] = a1v;
    if (last) {
      attnu[(size_t)(b * NS_ + i0) * N_ + jt * 64 + l] = a0;
      attnu[(size_t)(b * NS_ + i1) * N_ + jt * 64 + l] = a1v;
    }
  }
  __syncthreads();
  #pragma unroll
  for (int it = 0; it < 4; ++it) {
    int f = tid + it * 512;
    int row = f >> 5, c4 = (f & 31) * 4;
    float4 vv = *(const float4*)&vb[(jrow + row) * 128 + c4];
    *(float4*)&buf[row * 132 + c4] = vv;
  }
  __syncthreads();
  {
    int ii = tid >> 5, dg = tid & 31;
    float av0 = 0, av1 = 0, av2 = 0, av3 = 0, aw0 = 0, aw1 = 0, aw2 = 0, aw3 = 0, rsum = 0;
    #pragma unroll 4
    for (int j = 0; j < 64; ++j) {
      float a = a1s[ii * 66 + j];
      const float4 v4 = *(const float4*)&buf[j * 132 + dg * 4];
      rsum += a;
      float m0 = a * v4.x, m1 = a * v4.y, m2 = a * v4.z, m3 = a * v4.w;
      av0 += m0; av1 += m1; av2 += m2; av3 += m3;
      aw0 = fmaf(m0, v4.x, aw0); aw1 = fmaf(m1, v4.y, aw1);
      aw2 = fmaf(m2, v4.z, aw2); aw3 = fmaf(m3, v4.w, aw3);
    }
    float* pr = &part[((size_t)(b * NT_ + jt) * NS_ + ii) * 260];
    *(float4*)&pr[dg * 4] = make_float4(av0, av1, av2, av3);
    *(float4*)&pr[128 + dg * 4] = make_float4(aw0, aw1, aw2, aw3);
    if (dg == 0) pr[256] = rsum;
  }
}

// ---------- rK: per-slot update (steps 0..2), 64 blocks x 1024 ----------
__global__ __launch_bounds__(1024, 1) void rK(const float* __restrict__ part,
    float* mu, float* wcoef, float* cbuf, SW w) {
  __shared__ __align__(16) float sl[S_TOT];
  int tid = threadIdx.x;
  int b = blockIdx.x >> 4, i = blockIdx.x & 15;
  slotUpdateT<0>(sl, b, i, tid, part, mu, wcoef, cbuf, w);
}

// ---------- oK: final slot update + out MLP (0..63) + attn normalize (64..127) ----------
__global__ __launch_bounds__(1024, 1) void oK(const float* __restrict__ part,
    float* mu, SW w,
    const unsigned* __restrict__ o1P, const float* __restrict__ ob1,
    const unsigned* __restrict__ o2P, const float* __restrict__ ob2,
    const float* __restrict__ attnu, float* __restrict__ out) {
  __shared__ __align__(16) float sl[S_TOT];
  int blk = blockIdx.x, tid = threadIdx.x;
  const size_t pstr = (size_t)NS_ * 260;
  if (blk >= 64) {
    int r = blk - 64;                   // (b,i) row 0..63
    int b = r >> 4, i = r & 15;
    size_t pbase = ((size_t)(b * NT_) * NS_ + i) * 260;
    if (tid < 64) {
      float v = part[pbase + (size_t)tid * pstr + 256];
      #pragma unroll
      for (int off = 32; off > 0; off >>= 1) v += __shfl_down(v, off, 64);
      if (tid == 0) sl[0] = v;
    }
    __syncthreads();
    float rs = sl[0];
    int base = r * 4096 + tid * 4;
    float4 v = *(const float4*)&attnu[base];
    v.x /= rs; v.y /= rs; v.z /= rs; v.w /= rs;
    *(float4*)&out[8192 + base] = v;
    return;
  }
  int b = blk >> 4, i = blk & 15;
  slotUpdateT<1>(sl, b, i, tid, part, mu, (float*)nullptr, (float*)nullptr, w);
  // out-MLP up: 1024 outputs, 1/thread, packed bf16; h1 -> S_RED
  {
    const float* sn = sl + S_SNEW;
    float a0 = 0.f, a1 = 0.f;
    #pragma unroll 16
    for (int r = 0; r < 64; ++r) {
      unsigned p0 = o1P[r * 1024 + tid];
      unsigned p1 = o1P[(64 + r) * 1024 + tid];
      a0 = fmaf(sn[2 * r], bf_lo(p0), a0);
      a0 = fmaf(sn[2 * r + 1], bf_hi(p0), a0);
      a1 = fmaf(sn[128 + 2 * r], bf_lo(p1), a1);
      a1 = fmaf(sn[128 + 2 * r + 1], bf_hi(p1), a1);
    }
    sl[S_RED + tid] = fmaxf(a0 + a1 + ob1[tid], 0.f);
  }
  __syncthreads();
  // out-MLP down: 128 outputs, 8-way K-split, packed
  {
    int d = tid & 127, qg = tid >> 7;
    const unsigned* wc2 = o2P + (size_t)(qg * 64) * 128 + d;
    const float* h = sl + S_RED + qg * 128;
    float b0 = 0.f, b1 = 0.f;
    #pragma unroll 16
    for (int r = 0; r < 64; ++r) {
      unsigned p = wc2[r * 128];
      b0 = fmaf(h[2 * r], bf_lo(p), b0);
      b1 = fmaf(h[2 * r + 1], bf_hi(p), b1);
    }
    sl[S_P1 + qg * 128 + d] = b0 + b1;
  }
  __syncthreads();
  if (tid < 128) {
    float o = ob2[tid];
    #pragma unroll
    for (int g = 0; g < 8; ++g) o += sl[S_P1 + g * 128 + tid];
    out[(size_t)blk * 128 + tid] = o;
  }
}

extern "C" void kernel_launch(void* const* d_in, const int* in_sizes, int n_in,
                              void* d_out, int out_size, void* d_ws, size_t ws_size,
                              hipStream_t stream) {
  const float* slots_in = (const float*)d_in[0];
  const float* inputs   = (const float*)d_in[1];
  const float* Wq  = (const float*)d_in[2];
  const float* Wk  = (const float*)d_in[3];
  const float* Wv  = (const float*)d_in[4];
  const float* Wih = (const float*)d_in[5];
  const float* Whh = (const float*)d_in[6];
  const float* bih = (const float*)d_in[7];
  const float* bhh = (const float*)d_in[8];
  const float* mW1 = (const float*)d_in[9];
  const float* mb1 = (const float*)d_in[10];
  const float* mW2 = (const float*)d_in[11];
  const float* mb2 = (const float*)d_in[12];
  const float* g_in  = (const float*)d_in[13];
  const float* be_in = (const float*)d_in[14];
  const float* g_sl  = (const float*)d_in[15];
  const float* be_sl = (const float*)d_in[16];
  const float* g_mu  = (const float*)d_in[17];
  const float* be_mu = (const float*)d_in[18];
  const float* oW1 = (const float*)d_in[19];
  const float* ob1 = (const float*)d_in[20];
  const float* oW2 = (const float*)d_in[21];
  const float* ob2 = (const float*)d_in[22];
  float* ws  = (float*)d_ws;
  float* out = (float*)d_out;
  (void)in_sizes; (void)n_in; (void)out_size; (void)ws_size;

  SW w;
  w.wcP = (const unsigned*)(ws + OFF_WCP);
  w.m1P = (const unsigned*)(ws + OFF_M1P);
  w.m2P = (const unsigned*)(ws + OFF_M2P);
  w.wqP = (const unsigned*)(ws + OFF_WQP);
  w.bih = bih; w.bhh = bhh; w.mb1 = mb1; w.mb2 = mb2;
  w.gmu = g_mu; w.bmu = be_mu; w.gsl = g_sl; w.bsl = be_sl;

  hipLaunchKernelGGL(tK, dim3(128), dim3(256), 0, stream,
                     Wq, Wk, Wv, Wih, Whh, mW1, mW2, oW1, oW2, ws);
  hipLaunchKernelGGL(kvK, dim3(320), dim3(512), 0, stream,
                     inputs, ws + OFF_WTKV, g_in, be_in, slots_in, w,
                     ws + OFF_K, ws + OFF_V, ws + OFF_MU, ws + OFF_WCOEF, ws + OFF_C);
  for (int s = 0; s < 4; ++s) {
    hipLaunchKernelGGL(pK, dim3(64, 4), dim3(512), 0, stream,
                       ws + OFF_K, ws + OFF_V, ws + OFF_WCOEF, ws + OFF_C,
                       ws + OFF_PART, ws + OFF_ATTNU, (s == 3) ? 1 : 0);
    if (s < 3) {
      hipLaunchKernelGGL(rK, dim3(64), dim3(1024), 0, stream,
                         ws + OFF_PART, ws + OFF_MU, ws + OFF_WCOEF, ws + OFF_C, w);
    }
  }
  hipLaunchKernelGGL(oK, dim3(128), dim3(1024), 0, stream,
                     ws + OFF_PART, ws + OFF_MU, w,
                     (const unsigned*)(ws + OFF_O1P), ob1,
                     (const unsigned*)(ws + OFF_O2P), ob2, ws + OFF_ATTNU, out);
}

// Round 9
// 169.338 us; speedup vs baseline: 5.7605x; 1.0651x over previous
//
#include <hip/hip_runtime.h>
#include <math.h>

#define B_ 4
#define N_ 4096
#define D_ 128
#define NS_ 16
#define NT_ 64
#define SCALE_ 0.08838834764831843f
#define EPS_ 1e-10f

// workspace offsets (in 4-byte words)
#define OFF_K      ((size_t)0)
#define OFF_V      (OFF_K + (size_t)B_*N_*D_)
#define OFF_WTKV   (OFF_V + (size_t)B_*N_*D_)   /* f32 [128][256] */
#define OFF_WCP    (OFF_WTKV + 128*256)          /* uint [128][512] packed bf16 pairs */
#define OFF_M1P    (OFF_WCP + 128*512)           /* uint [64][512] */
#define OFF_M2P    (OFF_M1P + 64*512)            /* uint [256][128] */
#define OFF_WQP    (OFF_M2P + 256*128)           /* uint [64][128] */
#define OFF_O1P    (OFF_WQP + 64*128)            /* uint [128][1024] */
#define OFF_O2P    (OFF_O1P + 128*1024)          /* uint [512][128] */
#define OFF_MU     (OFF_O2P + 512*128)
#define OFF_WCOEF  (OFF_MU + (size_t)B_*NS_*128)
#define OFF_C      (OFF_WCOEF + (size_t)B_*128*32)
#define OFF_PART   (OFF_C + 64)
#define OFF_ATTNU  (OFF_PART + (size_t)B_*NT_*NS_*260)

// slot scratch offsets (floats)
#define S_ZS    0     /* 256 */
#define S_S2    256   /* 128 */
#define S_UU    384   /* 128 */
#define S_H2    512   /* 128 */
#define S_A1S   640   /* 512 */
#define S_SNEW  1152  /* 256 */
#define S_QM    1408  /* 128 */
#define S_QL    1536  /* 128 */
#define S_RED   1664  /* 1024 (also h1 in oK) */
#define S_P1    2688  /* 1024 partial scratch */
#define S_TOT   3712

__device__ __forceinline__ float bf_lo(unsigned p) { return __uint_as_float(p << 16); }
__device__ __forceinline__ float bf_hi(unsigned p) { return __uint_as_float(p & 0xffff0000u); }
__device__ __forceinline__ unsigned packbf(float lo, float hi) {
  unsigned ul = __float_as_uint(lo), uh = __float_as_uint(hi);
  ul = (ul + 0x7fffu + ((ul >> 16) & 1u)) >> 16;
  uh = (uh + 0x7fffu + ((uh >> 16) & 1u)) >> 16;
  return (ul & 0xffffu) | (uh << 16);
}

// packed-weight + bias bundle
struct SW {
  const unsigned* wcP;   // [128][512] GRU (K=256 packed in pairs)
  const unsigned* m1P;   // [64][512]
  const unsigned* m2P;   // [256][128]
  const unsigned* wqP;   // [64][128]
  const float* bih; const float* bhh;
  const float* mb1; const float* mb2;
  const float* gmu; const float* bmu;
  const float* gsl; const float* bsl;
};

template <int T>
__device__ __forceinline__ float bRedT(float v, float* red, int tid) {
  red[tid] = v;
  __syncthreads();
  if (T >= 1024) {
    if (tid < 512) red[tid] += red[tid + 512];
    __syncthreads();
  }
  if (tid < 256) red[tid] += red[tid + 256];
  __syncthreads();
  if (tid < 128) red[tid] += red[tid + 128];
  __syncthreads();
  if (tid < 64) {
    float x = red[tid] + red[tid + 64];
    #pragma unroll
    for (int off = 32; off > 0; off >>= 1) x += __shfl_down(x, off, 64);
    if (tid == 0) red[0] = x;
  }
  __syncthreads();
  float r = red[0];
  __syncthreads();
  return r;
}

// input: sl[S_A1S..+255] = LN'd slot row. T = block threads (512 or 1024).
template <int T>
__device__ __forceinline__ void slotTailT(float* sl, int b, int i, int tid,
    const unsigned* __restrict__ wqP, float* wcoef, float* cbuf) {
  constexpr int KG = T / 256;    // 2 or 4
  constexpr int RR = 64 / KG;    // packed rows per group
  {
    int rest = tid & 255, kg = tid >> 8;
    int wh = rest >> 7, o = rest & 127;
    const unsigned* wq = wqP + (size_t)(kg * RR) * 128 + o;
    const float* s = sl + S_A1S + wh * 128 + kg * (128 / KG);
    float a0 = 0.f, a1 = 0.f;
    #pragma unroll
    for (int r = 0; r < RR; ++r) {
      unsigned p = wq[r * 128];
      a0 = fmaf(s[2 * r], bf_lo(p), a0);
      a1 = fmaf(s[2 * r + 1], bf_hi(p), a1);
    }
    sl[S_P1 + kg * 256 + rest] = a0 + a1;
  }
  __syncthreads();
  if (tid < 256) {
    float q = 0.f;
    #pragma unroll
    for (int g = 0; g < KG; ++g) q += sl[S_P1 + g * 256 + tid];
    if (tid < 128) sl[S_QM + tid] = q; else sl[S_QL + (tid - 128)] = q;
  }
  __syncthreads();
  float cp = 0.f;
  if (tid < 128) {
    float iv = expf(-2.f * sl[S_QL + tid]);
    float a1 = SCALE_ * iv;
    float a2 = -2.f * SCALE_ * iv * sl[S_QM + tid];
    float* wrow = &wcoef[((size_t)b * 128 + tid) * 32];
    wrow[2 * i] = a2;
    wrow[2 * i + 1] = a1;
    cp = SCALE_ * iv * sl[S_QM + tid] * sl[S_QM + tid];
  }
  float ctot = bRedT<T>(cp, sl + S_RED, tid);
  if (tid == 0) cbuf[b * NS_ + i] = ctot;
}

// 1024-thread slot update. FINAL=0: full incl. next-step prep. FINAL=1: stop with snew in LDS.
template <int FINAL>
__device__ void slotUpdateT(float* sl, int b, int i, int tid,
    const float* __restrict__ part, float* mu, float* wcoef, float* cbuf, SW w) {
  size_t pbase = ((size_t)(b * NT_) * NS_ + i) * 260;
  const size_t pstr = (size_t)NS_ * 260;
  // part reduce: 4 groups x 16 tiles
  {
    int g = tid >> 8, e = tid & 255;
    float s = 0.f;
    #pragma unroll 16
    for (int t = 0; t < 16; ++t) s += part[pbase + (size_t)(g * 16 + t) * pstr + e];
    sl[S_P1 + g * 256 + e] = s;
  }
  float rp = (tid < 64) ? part[pbase + (size_t)tid * pstr + 256] : 0.f;
  float rt = bRedT<1024>(rp, sl + S_RED, tid);  // internal syncs cover S_P1 writes
  if (tid < 256) {
    float s = sl[S_P1 + tid] + sl[S_P1 + 256 + tid] + sl[S_P1 + 512 + tid] + sl[S_P1 + 768 + tid];
    if (tid < 128) sl[S_ZS + tid] = s / rt; else sl[S_S2 + tid - 128] = s / rt;
  } else if (tid < 384) {
    sl[S_ZS + tid - 128] = mu[(size_t)(b * NS_ + i) * 128 + (tid - 256)];
  }
  __syncthreads();
  // GRU matvec: 512 outputs, 2-way K-split, packed bf16 pairs
  {
    int q = tid & 511, kg = tid >> 9;
    const unsigned* wcol = w.wcP + (size_t)(kg * 64) * 512 + q;
    const float* xz = sl + S_ZS + kg * 128;
    float a0 = 0.f, a1 = 0.f;
    #pragma unroll 16
    for (int r = 0; r < 64; ++r) {
      unsigned p = wcol[r * 512];
      a0 = fmaf(xz[2 * r], bf_lo(p), a0);
      a1 = fmaf(xz[2 * r + 1], bf_hi(p), a1);
    }
    sl[S_P1 + kg * 512 + q] = a0 + a1;
  }
  __syncthreads();
  if (tid < 128) {
    float o_r = sl[S_P1 + tid] + sl[S_P1 + 512 + tid];
    float o_z = sl[S_P1 + 128 + tid] + sl[S_P1 + 640 + tid];
    float o_n = sl[S_P1 + 256 + tid] + sl[S_P1 + 768 + tid];
    float o_g = sl[S_P1 + 384 + tid] + sl[S_P1 + 896 + tid];
    float r = 1.f / (1.f + expf(-(o_r + w.bih[tid] + w.bhh[tid])));
    float z = 1.f / (1.f + expf(-(o_z + w.bih[128 + tid] + w.bhh[128 + tid])));
    float nn = tanhf(o_n + w.bih[256 + tid] + r * (o_g + w.bhh[256 + tid]));
    sl[S_UU + tid] = (1.f - z) * nn + z * sl[S_ZS + 128 + tid];
  }
  __syncthreads();
  // LN(u)
  float uv = (tid < 128) ? sl[S_UU + tid] : 0.f;
  float m = bRedT<1024>(uv, sl + S_RED, tid) * (1.f / 128.f);
  float dv = (tid < 128) ? (sl[S_UU + tid] - m) : 0.f;
  float var = bRedT<1024>(dv * dv, sl + S_RED, tid) * (1.f / 128.f);
  float rsq = rsqrtf(var + 1e-5f);
  if (tid < 128) sl[S_H2 + tid] = dv * rsq * w.gmu[tid] + w.bmu[tid];
  __syncthreads();
  // MLP up: 512 outputs, 2-way K-split, packed
  {
    int q = tid & 511, kg = tid >> 9;
    const unsigned* wc1 = w.m1P + (size_t)(kg * 32) * 512 + q;
    const float* h = sl + S_H2 + kg * 64;
    float a0 = 0.f, a1 = 0.f;
    #pragma unroll
    for (int r = 0; r < 32; ++r) {
      unsigned p = wc1[r * 512];
      a0 = fmaf(h[2 * r], bf_lo(p), a0);
      a1 = fmaf(h[2 * r + 1], bf_hi(p), a1);
    }
    sl[S_P1 + kg * 512 + q] = a0 + a1;
  }
  __syncthreads();
  if (tid < 512)
    sl[S_A1S + tid] = fmaxf(sl[S_P1 + tid] + sl[S_P1 + 512 + tid] + w.mb1[tid], 0.f);
  __syncthreads();
  // MLP down: 128 outputs, 8-way K-split, packed
  {
    int d = tid & 127, qg = tid >> 7;
    const unsigned* wc2 = w.m2P + (size_t)(qg * 32) * 128 + d;
    const float* a = sl + S_A1S + qg * 64;
    float b0 = 0.f, b1 = 0.f;
    #pragma unroll
    for (int r = 0; r < 32; ++r) {
      unsigned p = wc2[r * 128];
      b0 = fmaf(a[2 * r], bf_lo(p), b0);
      b1 = fmaf(a[2 * r + 1], bf_hi(p), b1);
    }
    sl[S_P1 + qg * 128 + d] = b0 + b1;
  }
  __syncthreads();
  if (tid < 128) {
    float o = w.mb2[tid];
    #pragma unroll
    for (int g = 0; g < 8; ++g) o += sl[S_P1 + g * 128 + tid];
    float uf = sl[S_UU + tid] + o;
    float xsv = sl[S_ZS + tid];
    float arg = sl[S_S2 + tid] - 2.f * uf * xsv + uf * uf + EPS_;
    float lsv = 0.5f * logf(fmaxf(arg, 1e-30f));
    sl[S_SNEW + tid] = uf;
    sl[S_SNEW + 128 + tid] = lsv;
  }
  __syncthreads();
  if (FINAL) return;  // snew in LDS is the product
  // next-step LN over new slot row
  float x = (tid < 256) ? sl[S_SNEW + tid] : 0.f;
  float m2 = bRedT<1024>(x, sl + S_RED, tid) * (1.f / 256.f);
  float d2 = (tid < 256) ? (sl[S_SNEW + tid] - m2) : 0.f;
  float v2 = bRedT<1024>(d2 * d2, sl + S_RED, tid) * (1.f / 256.f);
  float rs2 = rsqrtf(v2 + 1e-5f);
  if (tid < 256) {
    float slv = d2 * rs2 * w.gsl[tid] + w.bsl[tid];
    sl[S_A1S + tid] = slv;
    if (tid < 128) mu[(size_t)(b * NS_ + i) * 128 + tid] = slv;
  }
  __syncthreads();
  slotTailT<1024>(sl, b, i, tid, w.wqP, wcoef, cbuf);
}

// ---------- tK: k/v weight transpose (f32) + bf16-pack all slot/out weights ----------
__global__ __launch_bounds__(256) void tK(
    const float* __restrict__ Wq, const float* __restrict__ Wk, const float* __restrict__ Wv,
    const float* __restrict__ Wih, const float* __restrict__ Whh,
    const float* __restrict__ mW1, const float* __restrict__ mW2,
    const float* __restrict__ oW1, const float* __restrict__ oW2,
    float* __restrict__ ws) {
  int tid = blockIdx.x * blockDim.x + threadIdx.x;
  int stride = gridDim.x * blockDim.x;
  unsigned* wcP = (unsigned*)(ws + OFF_WCP);
  unsigned* m1P = (unsigned*)(ws + OFF_M1P);
  unsigned* m2P = (unsigned*)(ws + OFF_M2P);
  unsigned* wqP = (unsigned*)(ws + OFF_WQP);
  unsigned* o1P = (unsigned*)(ws + OFF_O1P);
  unsigned* o2P = (unsigned*)(ws + OFF_O2P);
  for (int idx = tid; idx < 128 * 256; idx += stride) {
    int kk = idx >> 8, c = idx & 255;
    ws[OFF_WTKV + idx] = (c < 128) ? Wk[c * 128 + kk] : Wv[(c - 128) * 128 + kk];
  }
  // wcP[r][q]: dd = 2r, 2r+1 of the virtual WC[256][512]
  for (int idx = tid; idx < 128 * 512; idx += stride) {
    int r = idx >> 9, q = idx & 511;
    float lo, hi;
    if (r < 64) {
      int dd = 2 * r;
      lo = (q < 384) ? Wih[q * 128 + dd] : 0.f;
      hi = (q < 384) ? Wih[q * 128 + dd + 1] : 0.f;
    } else {
      int dh = 2 * (r - 64);
      if (q < 256)      { lo = Whh[q * 128 + dh]; hi = Whh[q * 128 + dh + 1]; }
      else if (q < 384) { lo = 0.f; hi = 0.f; }
      else              { lo = Whh[(q - 128) * 128 + dh]; hi = Whh[(q - 128) * 128 + dh + 1]; }
    }
    wcP[idx] = packbf(lo, hi);
  }
  for (int idx = tid; idx < 64 * 512; idx += stride) {
    int r = idx >> 9, q = idx & 511;
    m1P[idx] = packbf(mW1[q * 128 + 2 * r], mW1[q * 128 + 2 * r + 1]);
  }
  for (int idx = tid; idx < 256 * 128; idx += stride) {
    int r = idx >> 7, d = idx & 127;
    m2P[idx] = packbf(mW2[d * 512 + 2 * r], mW2[d * 512 + 2 * r + 1]);
  }
  for (int idx = tid; idx < 64 * 128; idx += stride) {
    int r = idx >> 7, o = idx & 127;
    wqP[idx] = packbf(Wq[o * 128 + 2 * r], Wq[o * 128 + 2 * r + 1]);
  }
  for (int idx = tid; idx < 128 * 1024; idx += stride) {
    int r = idx >> 10, q = idx & 1023;
    o1P[idx] = packbf(oW1[q * 256 + 2 * r], oW1[q * 256 + 2 * r + 1]);
  }
  for (int idx = tid; idx < 512 * 128; idx += stride) {
    int r = idx >> 7, d = idx & 127;
    o2P[idx] = packbf(oW2[d * 1024 + 2 * r], oW2[d * 1024 + 2 * r + 1]);
  }
}

// ---------- kvK: LN(inputs)+k/v GEMM (0..255, single pass) + initial slot prep (256..319) ----------
__global__ __launch_bounds__(1024, 1) void kvK(const float* __restrict__ inp,
    const float* __restrict__ wt, const float* __restrict__ gin, const float* __restrict__ bin,
    const float* __restrict__ slots_in, SW w,
    float* __restrict__ kb, float* __restrict__ vb,
    float* __restrict__ mu, float* wcoef, float* cbuf) {
  __shared__ __align__(16) float shm[9408];
  int tid = threadIdx.x;
  int blk = blockIdx.x;
  if (blk < 256) {
    float* xs = shm;            // [64][129]
    float* red = shm + 8256;    // [64][16]
    float* mrow = shm + 9280;   // 64
    float* rrow = shm + 9344;   // 64
    int rowbase = blk * 64;
    #pragma unroll
    for (int it = 0; it < 2; ++it) {
      int f = tid + it * 1024;
      int row = f >> 5, c4 = (f & 31) * 4;
      const float4 v = *(const float4*)&inp[(size_t)(rowbase + row) * 128 + c4];
      float* xr = &xs[row * 129 + c4];
      xr[0] = v.x; xr[1] = v.y; xr[2] = v.z; xr[3] = v.w;
    }
    __syncthreads();
    // LN: 16 threads/row, 8 elems each
    int row = tid >> 4, prt = tid & 15;
    float s = 0.f;
    #pragma unroll
    for (int e = 0; e < 8; ++e) s += xs[row * 129 + prt * 8 + e];
    red[row * 16 + prt] = s;
    __syncthreads();
    if (prt == 0) {
      float m = 0.f;
      #pragma unroll
      for (int q = 0; q < 16; ++q) m += red[row * 16 + q];
      mrow[row] = m * (1.f / 128.f);
    }
    __syncthreads();
    float m = mrow[row];
    s = 0.f;
    #pragma unroll
    for (int e = 0; e < 8; ++e) { float d = xs[row * 129 + prt * 8 + e] - m; s += d * d; }
    red[row * 16 + prt] = s;
    __syncthreads();
    if (prt == 0) {
      float v = 0.f;
      #pragma unroll
      for (int q = 0; q < 16; ++q) v += red[row * 16 + q];
      rrow[row] = rsqrtf(v * (1.f / 128.f) + 1e-5f);
    }
    __syncthreads();
    float rs = rrow[row];
    #pragma unroll
    for (int e = 0; e < 8; ++e) {
      int c = prt * 8 + e;
      xs[row * 129 + c] = (xs[row * 129 + c] - m) * rs * gin[c] + bin[c];
    }
    __syncthreads();
    // GEMM: 16 waves, wave wv owns 16 of 256 cols, one pass
    int l = tid & 63;
    int wv = __builtin_amdgcn_readfirstlane(threadIdx.x >> 6);
    int cbase = wv * 16;
    float acc[16];
    #pragma unroll
    for (int e = 0; e < 16; ++e) acc[e] = 0.f;
    #pragma unroll 4
    for (int kk = 0; kk < 128; ++kk) {
      float a = xs[l * 129 + kk];
      const float* wr = &wt[kk * 256 + cbase];  // wave-uniform -> s_load
      #pragma unroll
      for (int e = 0; e < 16; ++e) acc[e] = fmaf(a, wr[e], acc[e]);
    }
    float* outp = (cbase < 128) ? kb : vb;
    int col = cbase & 127;
    size_t o = (size_t)(rowbase + l) * 128 + col;
    #pragma unroll
    for (int e4 = 0; e4 < 4; ++e4)
      *(float4*)&outp[o + e4 * 4] =
          make_float4(acc[e4 * 4], acc[e4 * 4 + 1], acc[e4 * 4 + 2], acc[e4 * 4 + 3]);
  } else {
    float* sl = shm;
    int sb = blk - 256;
    int b2 = sb >> 4, i = sb & 15;
    float x = (tid < 256) ? slots_in[(size_t)(b2 * NS_ + i) * 256 + tid] : 0.f;
    float m = bRedT<1024>(x, sl + S_RED, tid) * (1.f / 256.f);
    float d = (tid < 256) ? (x - m) : 0.f;
    float var = bRedT<1024>(d * d, sl + S_RED, tid) * (1.f / 256.f);
    float rs = rsqrtf(var + 1e-5f);
    if (tid < 256) {
      float slv = d * rs * w.gsl[tid] + w.bsl[tid];
      sl[S_A1S + tid] = slv;
      if (tid < 128) mu[(size_t)(b2 * NS_ + i) * 128 + tid] = slv;
    }
    __syncthreads();
    slotTailT<1024>(sl, b2, i, tid, w.wqP, wcoef, cbuf);
  }
}

// ---------- pK: token pass per step (1024 threads, wave-per-slot, V reg-prefetch) ----------
__global__ __launch_bounds__(1024, 1) void pK(const float* __restrict__ kb,
    const float* __restrict__ vb, const float* __restrict__ wcoef,
    const float* __restrict__ cbuf, float* __restrict__ part,
    float* __restrict__ attnu, int last) {
  __shared__ __align__(16) float buf[8448];   // K as [64][129], then V as [64][132]
  __shared__ float a1s[16 * 66];
  __shared__ float esum[16 * 64];
  int tid = threadIdx.x;
  int jt = blockIdx.x, b = blockIdx.y;
  size_t jrow = (size_t)(b * N_ + jt * 64);
  // stage K tile [64][129] (conflict-free phase-A reads at stride 129)
  #pragma unroll
  for (int it = 0; it < 2; ++it) {
    int f = tid + it * 1024;
    int row = f >> 5, c4 = (f & 31) * 4;
    float4 kv = *(const float4*)&kb[(jrow + row) * 128 + c4];
    float* kr = &buf[row * 129 + c4];
    kr[0] = kv.x; kr[1] = kv.y; kr[2] = kv.z; kr[3] = kv.w;
  }
  __syncthreads();
  // prefetch V tile into registers (T14: latency hides under phase A)
  float4 vr0, vr1;
  {
    int f0 = tid, f1 = tid + 1024;
    vr0 = *(const float4*)&vb[(jrow + (f0 >> 5)) * 128 + (f0 & 31) * 4];
    vr1 = *(const float4*)&vb[(jrow + (f1 >> 5)) * 128 + (f1 & 31) * 4];
  }
  // phase A: wave w owns slot w; lanes = tokens
  {
    int l = tid & 63;
    int w = __builtin_amdgcn_readfirstlane(threadIdx.x >> 6);
    const float* wb = &wcoef[(size_t)b * 128 * 32];
    float d0a = cbuf[b * NS_ + w];
    float d0b = 0.f;
    #pragma unroll 8
    for (int kk = 0; kk < 128; kk += 2) {
      float kv0 = buf[l * 129 + kk];
      float kv1 = buf[l * 129 + kk + 1];
      float2 w0 = *(const float2*)&wb[kk * 32 + 2 * w];        // wave-uniform -> s_load
      float2 w1 = *(const float2*)&wb[(kk + 1) * 32 + 2 * w];
      d0a = fmaf(fmaf(w0.y, kv0, w0.x), kv0, d0a);
      d0b = fmaf(fmaf(w1.y, kv1, w1.x), kv1, d0b);
    }
    float e0 = expf(-(d0a + d0b)) + EPS_;
    esum[w * 64 + l] = e0;
    __syncthreads();
    float tot = 0.f;
    #pragma unroll
    for (int q = 0; q < 16; ++q) tot += esum[q * 64 + l];
    float a0 = e0 / tot;
    a1s[w * 66 + l] = a0;
    if (last) {
      attnu[(size_t)(b * NS_ + w) * N_ + jt * 64 + l] = a0;
    }
  }
  __syncthreads();   // phase-A K reads + a1s writes done
  // write prefetched V into buf as [64][132]
  {
    int f0 = tid, f1 = tid + 1024;
    *(float4*)&buf[(f0 >> 5) * 132 + (f0 & 31) * 4] = vr0;
    *(float4*)&buf[(f1 >> 5) * 132 + (f1 & 31) * 4] = vr1;
  }
  __syncthreads();
  // phase B: wave ii owns slot ii; lane dg owns d = {dg, dg+64}
  {
    int ii = __builtin_amdgcn_readfirstlane(threadIdx.x >> 6);
    int dg = tid & 63;
    float av0 = 0.f, av1 = 0.f, aw0 = 0.f, aw1 = 0.f, rsum = 0.f;
    #pragma unroll 4
    for (int j = 0; j < 64; ++j) {
      float a = a1s[ii * 66 + j];          // broadcast
      float v0 = buf[j * 132 + dg];
      float v1 = buf[j * 132 + dg + 64];
      rsum += a;
      float m0 = a * v0, m1 = a * v1;
      av0 += m0; av1 += m1;
      aw0 = fmaf(m0, v0, aw0); aw1 = fmaf(m1, v1, aw1);
    }
    float* pr = &part[((size_t)(b * NT_ + jt) * NS_ + ii) * 260];
    pr[dg] = av0;
    pr[dg + 64] = av1;
    pr[128 + dg] = aw0;
    pr[128 + dg + 64] = aw1;
    if (dg == 0) pr[256] = rsum;
  }
}

// ---------- rK: per-slot update (steps 0..2), 64 blocks x 1024 ----------
__global__ __launch_bounds__(1024, 1) void rK(const float* __restrict__ part,
    float* mu, float* wcoef, float* cbuf, SW w) {
  __shared__ __align__(16) float sl[S_TOT];
  int tid = threadIdx.x;
  int b = blockIdx.x >> 4, i = blockIdx.x & 15;
  slotUpdateT<0>(sl, b, i, tid, part, mu, wcoef, cbuf, w);
}

// ---------- oK: final slot update + out MLP (0..63) + attn normalize (64..127) ----------
__global__ __launch_bounds__(1024, 1) void oK(const float* __restrict__ part,
    float* mu, SW w,
    const unsigned* __restrict__ o1P, const float* __restrict__ ob1,
    const unsigned* __restrict__ o2P, const float* __restrict__ ob2,
    const float* __restrict__ attnu, float* __restrict__ out) {
  __shared__ __align__(16) float sl[S_TOT];
  int blk = blockIdx.x, tid = threadIdx.x;
  const size_t pstr = (size_t)NS_ * 260;
  if (blk >= 64) {
    int r = blk - 64;                   // (b,i) row 0..63
    int b = r >> 4, i = r & 15;
    size_t pbase = ((size_t)(b * NT_) * NS_ + i) * 260;
    if (tid < 64) {
      float v = part[pbase + (size_t)tid * pstr + 256];
      #pragma unroll
      for (int off = 32; off > 0; off >>= 1) v += __shfl_down(v, off, 64);
      if (tid == 0) sl[0] = v;
    }
    __syncthreads();
    float rs = sl[0];
    int base = r * 4096 + tid * 4;
    float4 v = *(const float4*)&attnu[base];
    v.x /= rs; v.y /= rs; v.z /= rs; v.w /= rs;
    *(float4*)&out[8192 + base] = v;
    return;
  }
  int b = blk >> 4, i = blk & 15;
  slotUpdateT<1>(sl, b, i, tid, part, mu, (float*)nullptr, (float*)nullptr, w);
  // out-MLP up: 1024 outputs, 1/thread, packed bf16; h1 -> S_RED
  {
    const float* sn = sl + S_SNEW;
    float a0 = 0.f, a1 = 0.f;
    #pragma unroll 16
    for (int r = 0; r < 64; ++r) {
      unsigned p0 = o1P[r * 1024 + tid];
      unsigned p1 = o1P[(64 + r) * 1024 + tid];
      a0 = fmaf(sn[2 * r], bf_lo(p0), a0);
      a0 = fmaf(sn[2 * r + 1], bf_hi(p0), a0);
      a1 = fmaf(sn[128 + 2 * r], bf_lo(p1), a1);
      a1 = fmaf(sn[128 + 2 * r + 1], bf_hi(p1), a1);
    }
    sl[S_RED + tid] = fmaxf(a0 + a1 + ob1[tid], 0.f);
  }
  __syncthreads();
  // out-MLP down: 128 outputs, 8-way K-split, packed
  {
    int d = tid & 127, qg = tid >> 7;
    const unsigned* wc2 = o2P + (size_t)(qg * 64) * 128 + d;
    const float* h = sl + S_RED + qg * 128;
    float b0 = 0.f, b1 = 0.f;
    #pragma unroll 16
    for (int r = 0; r < 64; ++r) {
      unsigned p = wc2[r * 128];
      b0 = fmaf(h[2 * r], bf_lo(p), b0);
      b1 = fmaf(h[2 * r + 1], bf_hi(p), b1);
    }
    sl[S_P1 + qg * 128 + d] = b0 + b1;
  }
  __syncthreads();
  if (tid < 128) {
    float o = ob2[tid];
    #pragma unroll
    for (int g = 0; g < 8; ++g) o += sl[S_P1 + g * 128 + tid];
    out[(size_t)blk * 128 + tid] = o;
  }
}

extern "C" void kernel_launch(void* const* d_in, const int* in_sizes, int n_in,
                              void* d_out, int out_size, void* d_ws, size_t ws_size,
                              hipStream_t stream) {
  const float* slots_in = (const float*)d_in[0];
  const float* inputs   = (const float*)d_in[1];
  const float* Wq  = (const float*)d_in[2];
  const float* Wk  = (const float*)d_in[3];
  const float* Wv  = (const float*)d_in[4];
  const float* Wih = (const float*)d_in[5];
  const float* Whh = (const float*)d_in[6];
  const float* bih = (const float*)d_in[7];
  const float* bhh = (const float*)d_in[8];
  const float* mW1 = (const float*)d_in[9];
  const float* mb1 = (const float*)d_in[10];
  const float* mW2 = (const float*)d_in[11];
  const float* mb2 = (const float*)d_in[12];
  const float* g_in  = (const float*)d_in[13];
  const float* be_in = (const float*)d_in[14];
  const float* g_sl  = (const float*)d_in[15];
  const float* be_sl = (const float*)d_in[16];
  const float* g_mu  = (const float*)d_in[17];
  const float* be_mu = (const float*)d_in[18];
  const float* oW1 = (const float*)d_in[19];
  const float* ob1 = (const float*)d_in[20];
  const float* oW2 = (const float*)d_in[21];
  const float* ob2 = (const float*)d_in[22];
  float* ws  = (float*)d_ws;
  float* out = (float*)d_out;
  (void)in_sizes; (void)n_in; (void)out_size; (void)ws_size;

  SW w;
  w.wcP = (const unsigned*)(ws + OFF_WCP);
  w.m1P = (const unsigned*)(ws + OFF_M1P);
  w.m2P = (const unsigned*)(ws + OFF_M2P);
  w.wqP = (const unsigned*)(ws + OFF_WQP);
  w.bih = bih; w.bhh = bhh; w.mb1 = mb1; w.mb2 = mb2;
  w.gmu = g_mu; w.bmu = be_mu; w.gsl = g_sl; w.bsl = be_sl;

  hipLaunchKernelGGL(tK, dim3(128), dim3(256), 0, stream,
                     Wq, Wk, Wv, Wih, Whh, mW1, mW2, oW1, oW2, ws);
  hipLaunchKernelGGL(kvK, dim3(320), dim3(1024), 0, stream,
                     inputs, ws + OFF_WTKV, g_in, be_in, slots_in, w,
                     ws + OFF_K, ws + OFF_V, ws + OFF_MU, ws + OFF_WCOEF, ws + OFF_C);
  for (int s = 0; s < 4; ++s) {
    hipLaunchKernelGGL(pK, dim3(64, 4), dim3(1024), 0, stream,
                       ws + OFF_K, ws + OFF_V, ws + OFF_WCOEF, ws + OFF_C,
                       ws + OFF_PART, ws + OFF_ATTNU, (s == 3) ? 1 : 0);
    if (s < 3) {
      hipLaunchKernelGGL(rK, dim3(64), dim3(1024), 0, stream,
                         ws + OFF_PART, ws + OFF_MU, ws + OFF_WCOEF, ws + OFF_C, w);
    }
  }
  hipLaunchKernelGGL(oK, dim3(128), dim3(1024), 0, stream,
                     ws + OFF_PART, ws + OFF_MU, w,
                     (const unsigned*)(ws + OFF_O1P), ob1,
                     (const unsigned*)(ws + OFF_O2P), ob2, ws + OFF_ATTNU, out);
}

// Round 10
// 159.856 us; speedup vs baseline: 6.1021x; 1.0593x over previous
//
#include <hip/hip_runtime.h>
#include <math.h>

#define B_ 4
#define N_ 4096
#define D_ 128
#define NS_ 16
#define NT_ 64
#define SCALE_ 0.08838834764831843f
#define EPS_ 1e-10f

// workspace offsets (in 4-byte words)
#define OFF_K      ((size_t)0)
#define OFF_V      (OFF_K + (size_t)B_*N_*D_)
#define OFF_WTKV   (OFF_V + (size_t)B_*N_*D_)   /* f32 [128][256] */
#define OFF_WCP    (OFF_WTKV + 128*256)          /* uint [128][512] packed bf16 pairs */
#define OFF_M1P    (OFF_WCP + 128*512)           /* uint [64][512] */
#define OFF_M2P    (OFF_M1P + 64*512)            /* uint [256][128] */
#define OFF_WQP    (OFF_M2P + 256*128)           /* uint [64][128] */
#define OFF_O1P    (OFF_WQP + 64*128)            /* uint [128][1024] */
#define OFF_O2P    (OFF_O1P + 128*1024)          /* uint [512][128] */
#define OFF_MU     (OFF_O2P + 512*128)
#define OFF_WCOEF  (OFF_MU + (size_t)B_*NS_*128)
#define OFF_C      (OFF_WCOEF + (size_t)B_*128*32)
#define OFF_PART   (OFF_C + 64)
#define OFF_ATTNU  (OFF_PART + (size_t)B_*NT_*NS_*260)

// slot scratch offsets (floats)
#define S_ZS    0     /* 256 */
#define S_S2    256   /* 128 */
#define S_UU    384   /* 128 */
#define S_H2    512   /* 128 */
#define S_A1S   640   /* 512 */
#define S_SNEW  1152  /* 256 */
#define S_QM    1408  /* 128 */
#define S_QL    1536  /* 128 */
#define S_RED   1664  /* 32 scratch */
#define S_P1    2688  /* 1024 partial scratch */
#define S_TOT   3712

__device__ __forceinline__ float bf_lo(unsigned p) { return __uint_as_float(p << 16); }
__device__ __forceinline__ float bf_hi(unsigned p) { return __uint_as_float(p & 0xffff0000u); }
__device__ __forceinline__ unsigned packbf(float lo, float hi) {
  unsigned ul = __float_as_uint(lo), uh = __float_as_uint(hi);
  ul = (ul + 0x7fffu + ((ul >> 16) & 1u)) >> 16;
  uh = (uh + 0x7fffu + ((uh >> 16) & 1u)) >> 16;
  return (ul & 0xffffu) | (uh << 16);
}

__device__ __forceinline__ float waveRed1(float a) {
  #pragma unroll
  for (int off = 32; off > 0; off >>= 1) a += __shfl_down(a, off, 64);
  return a;  // valid in lane 0
}
__device__ __forceinline__ float2 waveRed2(float a, float b) {
  #pragma unroll
  for (int off = 32; off > 0; off >>= 1) {
    a += __shfl_down(a, off, 64);
    b += __shfl_down(b, off, 64);
  }
  return make_float2(a, b);  // valid in lane 0
}

// packed-weight + bias bundle
struct SW {
  const unsigned* wcP;   // [128][512] GRU (K=256 packed in pairs)
  const unsigned* m1P;   // [64][512]
  const unsigned* m2P;   // [256][128]
  const unsigned* wqP;   // [64][128]
  const float* bih; const float* bhh;
  const float* mb1; const float* mb2;
  const float* gmu; const float* bmu;
  const float* gsl; const float* bsl;
};

// input: sl[S_A1S..+255] = LN'd slot row. 1024 threads.
// Barriers: 3 (matvec publish, qm/ql publish, ctot publish).
__device__ __forceinline__ void slotTail1024(float* sl, int b, int i, int tid,
    const unsigned* __restrict__ wqP, float* wcoef, float* cbuf) {
  float* red = sl + S_RED;
  {
    int rest = tid & 255, kg = tid >> 8;
    int wh = rest >> 7, o = rest & 127;
    const unsigned* wq = wqP + (size_t)(kg * 16) * 128 + o;
    const float* s = sl + S_A1S + wh * 128 + kg * 32;
    float a0 = 0.f, a1 = 0.f;
    #pragma unroll
    for (int r = 0; r < 16; ++r) {
      unsigned p = wq[r * 128];
      a0 = fmaf(s[2 * r], bf_lo(p), a0);
      a1 = fmaf(s[2 * r + 1], bf_hi(p), a1);
    }
    sl[S_P1 + kg * 256 + rest] = a0 + a1;
  }
  __syncthreads();
  if (tid < 256) {
    float q = sl[S_P1 + tid] + sl[S_P1 + 256 + tid] + sl[S_P1 + 512 + tid] + sl[S_P1 + 768 + tid];
    if (tid < 128) sl[S_QM + tid] = q; else sl[S_QL + (tid - 128)] = q;
  }
  __syncthreads();
  float cp = 0.f;
  if (tid < 128) {
    float iv = expf(-2.f * sl[S_QL + tid]);
    float a1 = SCALE_ * iv;
    float a2 = -2.f * SCALE_ * iv * sl[S_QM + tid];
    float* wrow = &wcoef[((size_t)b * 128 + tid) * 32];
    wrow[2 * i] = a2;
    wrow[2 * i + 1] = a1;
    cp = SCALE_ * iv * sl[S_QM + tid] * sl[S_QM + tid];
    float r = waveRed1(cp);
    if ((tid & 63) == 0) red[16 + (tid >> 6)] = r;
  }
  __syncthreads();
  if (tid == 0) cbuf[b * NS_ + i] = red[16] + red[17];
}

// 1024-thread slot update. FINAL=0: full incl. next-step prep. FINAL=1: stop with snew in LDS.
template <int FINAL>
__device__ void slotUpdateT(float* sl, int b, int i, int tid,
    const float* __restrict__ part, float* mu, float* wcoef, float* cbuf, SW w) {
  float* red = sl + S_RED;
  size_t pbase = ((size_t)(b * NT_) * NS_ + i) * 260;
  const size_t pstr = (size_t)NS_ * 260;
  // part reduce: 4 groups x 16 tiles
  {
    int g = tid >> 8, e = tid & 255;
    float s = 0.f;
    #pragma unroll 16
    for (int t = 0; t < 16; ++t) s += part[pbase + (size_t)(g * 16 + t) * pstr + e];
    sl[S_P1 + g * 256 + e] = s;
  }
  if (tid < 64) {
    float rtv = waveRed1(part[pbase + (size_t)tid * pstr + 256]);
    if (tid == 0) red[0] = rtv;
  }
  __syncthreads();  // B1: publishes S_P1 partials + red[0]
  float rt = red[0];
  if (tid < 256) {
    float s = sl[S_P1 + tid] + sl[S_P1 + 256 + tid] + sl[S_P1 + 512 + tid] + sl[S_P1 + 768 + tid];
    if (tid < 128) sl[S_ZS + tid] = s / rt; else sl[S_S2 + tid - 128] = s / rt;
  } else if (tid < 384) {
    sl[S_ZS + tid - 128] = mu[(size_t)(b * NS_ + i) * 128 + (tid - 256)];
  }
  __syncthreads();  // B2
  // GRU matvec: 512 outputs, 2-way K-split, packed bf16 pairs
  {
    int q = tid & 511, kg = tid >> 9;
    const unsigned* wcol = w.wcP + (size_t)(kg * 64) * 512 + q;
    const float* xz = sl + S_ZS + kg * 128;
    float a0 = 0.f, a1 = 0.f;
    #pragma unroll 16
    for (int r = 0; r < 64; ++r) {
      unsigned p = wcol[r * 512];
      a0 = fmaf(xz[2 * r], bf_lo(p), a0);
      a1 = fmaf(xz[2 * r + 1], bf_hi(p), a1);
    }
    sl[S_P1 + kg * 512 + q] = a0 + a1;
  }
  __syncthreads();  // B3
  float uu_reg = 0.f;
  if (tid < 128) {
    float o_r = sl[S_P1 + tid] + sl[S_P1 + 512 + tid];
    float o_z = sl[S_P1 + 128 + tid] + sl[S_P1 + 640 + tid];
    float o_n = sl[S_P1 + 256 + tid] + sl[S_P1 + 768 + tid];
    float o_g = sl[S_P1 + 384 + tid] + sl[S_P1 + 896 + tid];
    float r = 1.f / (1.f + expf(-(o_r + w.bih[tid] + w.bhh[tid])));
    float z = 1.f / (1.f + expf(-(o_z + w.bih[128 + tid] + w.bhh[128 + tid])));
    float nn = tanhf(o_n + w.bih[256 + tid] + r * (o_g + w.bhh[256 + tid]));
    uu_reg = (1.f - z) * nn + z * sl[S_ZS + 128 + tid];
    sl[S_UU + tid] = uu_reg;
    float2 r2 = waveRed2(uu_reg, uu_reg * uu_reg);
    if ((tid & 63) == 0) { red[4 + (tid >> 6) * 2] = r2.x; red[5 + (tid >> 6) * 2] = r2.y; }
  }
  __syncthreads();  // B4: publishes S_UU + red[4..7]
  if (tid < 128) {
    float sum = red[4] + red[6], sq = red[5] + red[7];
    float m = sum * (1.f / 128.f);
    float var = sq * (1.f / 128.f) - m * m;
    float rsq = rsqrtf(var + 1e-5f);
    sl[S_H2 + tid] = (uu_reg - m) * rsq * w.gmu[tid] + w.bmu[tid];
  }
  __syncthreads();  // B5
  // MLP up: 512 outputs, 2-way K-split, packed
  {
    int q = tid & 511, kg = tid >> 9;
    const unsigned* wc1 = w.m1P + (size_t)(kg * 32) * 512 + q;
    const float* h = sl + S_H2 + kg * 64;
    float a0 = 0.f, a1 = 0.f;
    #pragma unroll
    for (int r = 0; r < 32; ++r) {
      unsigned p = wc1[r * 512];
      a0 = fmaf(h[2 * r], bf_lo(p), a0);
      a1 = fmaf(h[2 * r + 1], bf_hi(p), a1);
    }
    sl[S_P1 + kg * 512 + q] = a0 + a1;
  }
  __syncthreads();  // B6
  if (tid < 512)
    sl[S_A1S + tid] = fmaxf(sl[S_P1 + tid] + sl[S_P1 + 512 + tid] + w.mb1[tid], 0.f);
  __syncthreads();  // B7
  // MLP down: 128 outputs, 8-way K-split, packed
  {
    int d = tid & 127, qg = tid >> 7;
    const unsigned* wc2 = w.m2P + (size_t)(qg * 32) * 128 + d;
    const float* a = sl + S_A1S + qg * 64;
    float b0 = 0.f, b1 = 0.f;
    #pragma unroll
    for (int r = 0; r < 32; ++r) {
      unsigned p = wc2[r * 128];
      b0 = fmaf(a[2 * r], bf_lo(p), b0);
      b1 = fmaf(a[2 * r + 1], bf_hi(p), b1);
    }
    sl[S_P1 + qg * 128 + d] = b0 + b1;
  }
  __syncthreads();  // B8
  if (tid < 128) {
    float o = w.mb2[tid];
    #pragma unroll
    for (int g = 0; g < 8; ++g) o += sl[S_P1 + g * 128 + tid];
    float uf = sl[S_UU + tid] + o;
    float xsv = sl[S_ZS + tid];
    float arg = sl[S_S2 + tid] - 2.f * uf * xsv + uf * uf + EPS_;
    float lsv = 0.5f * logf(fmaxf(arg, 1e-30f));
    sl[S_SNEW + tid] = uf;
    sl[S_SNEW + 128 + tid] = lsv;
  }
  __syncthreads();  // B9
  if (FINAL) return;  // snew in LDS is the product
  // next-step LN over new slot row (fused sum/sumsq)
  float xv = 0.f;
  if (tid < 256) {
    xv = sl[S_SNEW + tid];
    float2 r2 = waveRed2(xv, xv * xv);
    if ((tid & 63) == 0) { red[8 + (tid >> 6) * 2] = r2.x; red[9 + (tid >> 6) * 2] = r2.y; }
  }
  __syncthreads();  // B10
  if (tid < 256) {
    float sum = red[8] + red[10] + red[12] + red[14];
    float sq = red[9] + red[11] + red[13] + red[15];
    float m2 = sum * (1.f / 256.f);
    float var2 = sq * (1.f / 256.f) - m2 * m2;
    float rs2 = rsqrtf(var2 + 1e-5f);
    float slv = (xv - m2) * rs2 * w.gsl[tid] + w.bsl[tid];
    sl[S_A1S + tid] = slv;
    if (tid < 128) mu[(size_t)(b * NS_ + i) * 128 + tid] = slv;
  }
  __syncthreads();  // B11
  slotTail1024(sl, b, i, tid, w.wqP, wcoef, cbuf);
}

// ---------- tK: k/v weight transpose (f32) + slot-weight packing ----------
__global__ __launch_bounds__(256) void tK(
    const float* __restrict__ Wq, const float* __restrict__ Wk, const float* __restrict__ Wv,
    const float* __restrict__ Wih, const float* __restrict__ Whh,
    const float* __restrict__ mW1, const float* __restrict__ mW2,
    float* __restrict__ ws) {
  int tid = blockIdx.x * blockDim.x + threadIdx.x;
  int stride = gridDim.x * blockDim.x;
  unsigned* wcP = (unsigned*)(ws + OFF_WCP);
  unsigned* m1P = (unsigned*)(ws + OFF_M1P);
  unsigned* m2P = (unsigned*)(ws + OFF_M2P);
  unsigned* wqP = (unsigned*)(ws + OFF_WQP);
  for (int idx = tid; idx < 128 * 256; idx += stride) {
    int kk = idx >> 8, c = idx & 255;
    ws[OFF_WTKV + idx] = (c < 128) ? Wk[c * 128 + kk] : Wv[(c - 128) * 128 + kk];
  }
  // wcP[r][q]: dd = 2r, 2r+1 of the virtual WC[256][512]
  for (int idx = tid; idx < 128 * 512; idx += stride) {
    int r = idx >> 9, q = idx & 511;
    float lo, hi;
    if (r < 64) {
      int dd = 2 * r;
      lo = (q < 384) ? Wih[q * 128 + dd] : 0.f;
      hi = (q < 384) ? Wih[q * 128 + dd + 1] : 0.f;
    } else {
      int dh = 2 * (r - 64);
      if (q < 256)      { lo = Whh[q * 128 + dh]; hi = Whh[q * 128 + dh + 1]; }
      else if (q < 384) { lo = 0.f; hi = 0.f; }
      else              { lo = Whh[(q - 128) * 128 + dh]; hi = Whh[(q - 128) * 128 + dh + 1]; }
    }
    wcP[idx] = packbf(lo, hi);
  }
  for (int idx = tid; idx < 64 * 512; idx += stride) {
    int r = idx >> 9, q = idx & 511;
    m1P[idx] = packbf(mW1[q * 128 + 2 * r], mW1[q * 128 + 2 * r + 1]);
  }
  for (int idx = tid; idx < 256 * 128; idx += stride) {
    int r = idx >> 7, d = idx & 127;
    m2P[idx] = packbf(mW2[d * 512 + 2 * r], mW2[d * 512 + 2 * r + 1]);
  }
  for (int idx = tid; idx < 64 * 128; idx += stride) {
    int r = idx >> 7, o = idx & 127;
    wqP[idx] = packbf(Wq[o * 128 + 2 * r], Wq[o * 128 + 2 * r + 1]);
  }
}

// ---------- kvK: LN+k/v GEMM (0..255) + slot prep (256..319) + out-weight packing (320..383) ----------
__global__ __launch_bounds__(1024, 1) void kvK(const float* __restrict__ inp,
    const float* __restrict__ wt, const float* __restrict__ gin, const float* __restrict__ bin,
    const float* __restrict__ slots_in, SW w,
    const float* __restrict__ oW1, const float* __restrict__ oW2,
    unsigned* __restrict__ o1P, unsigned* __restrict__ o2P,
    float* __restrict__ kb, float* __restrict__ vb,
    float* __restrict__ mu, float* wcoef, float* cbuf) {
  __shared__ __align__(16) float shm[9408];
  int tid = threadIdx.x;
  int blk = blockIdx.x;
  if (blk < 256) {
    float* xs = shm;            // [64][129]
    float* red = shm + 8256;    // [64][16]
    float* mrow = shm + 9280;   // 64
    float* rrow = shm + 9344;   // 64
    int rowbase = blk * 64;
    #pragma unroll
    for (int it = 0; it < 2; ++it) {
      int f = tid + it * 1024;
      int row = f >> 5, c4 = (f & 31) * 4;
      const float4 v = *(const float4*)&inp[(size_t)(rowbase + row) * 128 + c4];
      float* xr = &xs[row * 129 + c4];
      xr[0] = v.x; xr[1] = v.y; xr[2] = v.z; xr[3] = v.w;
    }
    __syncthreads();
    // LN: 16 threads/row, fused sum/sumsq
    int row = tid >> 4, prt = tid & 15;
    float s = 0.f, s2 = 0.f;
    #pragma unroll
    for (int e = 0; e < 8; ++e) {
      float v = xs[row * 129 + prt * 8 + e];
      s += v; s2 = fmaf(v, v, s2);
    }
    red[row * 16 + prt] = s;
    __syncthreads();
    if (prt == 0) {
      float m = 0.f;
      #pragma unroll
      for (int q = 0; q < 16; ++q) m += red[row * 16 + q];
      mrow[row] = m * (1.f / 128.f);
    }
    __syncthreads();
    float m = mrow[row];
    red[row * 16 + prt] = s2;
    __syncthreads();
    if (prt == 0) {
      float v = 0.f;
      #pragma unroll
      for (int q = 0; q < 16; ++q) v += red[row * 16 + q];
      float var = v * (1.f / 128.f) - m * m;
      rrow[row] = rsqrtf(var + 1e-5f);
    }
    __syncthreads();
    float rs = rrow[row];
    #pragma unroll
    for (int e = 0; e < 8; ++e) {
      int c = prt * 8 + e;
      xs[row * 129 + c] = (xs[row * 129 + c] - m) * rs * gin[c] + bin[c];
    }
    __syncthreads();
    // GEMM: 16 waves, wave wv owns 16 of 256 cols
    int l = tid & 63;
    int wv = __builtin_amdgcn_readfirstlane(threadIdx.x >> 6);
    int cbase = wv * 16;
    float acc[16];
    #pragma unroll
    for (int e = 0; e < 16; ++e) acc[e] = 0.f;
    #pragma unroll 4
    for (int kk = 0; kk < 128; ++kk) {
      float a = xs[l * 129 + kk];
      const float* wr = &wt[kk * 256 + cbase];  // wave-uniform -> s_load
      #pragma unroll
      for (int e = 0; e < 16; ++e) acc[e] = fmaf(a, wr[e], acc[e]);
    }
    float* outp = (cbase < 128) ? kb : vb;
    int col = cbase & 127;
    size_t o = (size_t)(rowbase + l) * 128 + col;
    #pragma unroll
    for (int e4 = 0; e4 < 4; ++e4)
      *(float4*)&outp[o + e4 * 4] =
          make_float4(acc[e4 * 4], acc[e4 * 4 + 1], acc[e4 * 4 + 2], acc[e4 * 4 + 3]);
  } else if (blk < 320) {
    float* sl = shm;
    float* red = sl + S_RED;
    int sb = blk - 256;
    int b2 = sb >> 4, i = sb & 15;
    float xv = 0.f;
    if (tid < 256) {
      xv = slots_in[(size_t)(b2 * NS_ + i) * 256 + tid];
      float2 r2 = waveRed2(xv, xv * xv);
      if ((tid & 63) == 0) { red[8 + (tid >> 6) * 2] = r2.x; red[9 + (tid >> 6) * 2] = r2.y; }
    }
    __syncthreads();
    if (tid < 256) {
      float sum = red[8] + red[10] + red[12] + red[14];
      float sq = red[9] + red[11] + red[13] + red[15];
      float m = sum * (1.f / 256.f);
      float var = sq * (1.f / 256.f) - m * m;
      float rs = rsqrtf(var + 1e-5f);
      float slv = (xv - m) * rs * w.gsl[tid] + w.bsl[tid];
      sl[S_A1S + tid] = slv;
      if (tid < 128) mu[(size_t)(b2 * NS_ + i) * 128 + tid] = slv;
    }
    __syncthreads();
    slotTail1024(sl, b2, i, tid, w.wqP, wcoef, cbuf);
  } else {
    // out-MLP weight packing: 64 blocks
    int pb = blk - 320;
    #pragma unroll
    for (int t = 0; t < 2; ++t) {
      int idx = pb * 2048 + t * 1024 + tid;
      int r = idx >> 10, q = idx & 1023;
      o1P[idx] = packbf(oW1[q * 256 + 2 * r], oW1[q * 256 + 2 * r + 1]);
    }
    {
      int idx = pb * 1024 + tid;
      int r = idx >> 7, d = idx & 127;
      o2P[idx] = packbf(oW2[d * 1024 + 2 * r], oW2[d * 1024 + 2 * r + 1]);
    }
  }
}

// ---------- pK: token pass per step (1024 threads, wave-per-slot, V reg-prefetch) ----------
__global__ __launch_bounds__(1024, 1) void pK(const float* __restrict__ kb,
    const float* __restrict__ vb, const float* __restrict__ wcoef,
    const float* __restrict__ cbuf, float* __restrict__ part,
    float* __restrict__ attnu, int last) {
  __shared__ __align__(16) float buf[8448];   // K as [64][129], then V as [64][132]
  __shared__ float a1s[16 * 66];
  __shared__ float esum[16 * 64];
  int tid = threadIdx.x;
  int jt = blockIdx.x, b = blockIdx.y;
  size_t jrow = (size_t)(b * N_ + jt * 64);
  #pragma unroll
  for (int it = 0; it < 2; ++it) {
    int f = tid + it * 1024;
    int row = f >> 5, c4 = (f & 31) * 4;
    float4 kv = *(const float4*)&kb[(jrow + row) * 128 + c4];
    float* kr = &buf[row * 129 + c4];
    kr[0] = kv.x; kr[1] = kv.y; kr[2] = kv.z; kr[3] = kv.w;
  }
  __syncthreads();
  // prefetch V tile into registers (latency hides under phase A)
  float4 vr0, vr1;
  {
    int f0 = tid, f1 = tid + 1024;
    vr0 = *(const float4*)&vb[(jrow + (f0 >> 5)) * 128 + (f0 & 31) * 4];
    vr1 = *(const float4*)&vb[(jrow + (f1 >> 5)) * 128 + (f1 & 31) * 4];
  }
  // phase A: wave w owns slot w; lanes = tokens
  {
    int l = tid & 63;
    int w = __builtin_amdgcn_readfirstlane(threadIdx.x >> 6);
    const float* wb = &wcoef[(size_t)b * 128 * 32];
    float d0a = cbuf[b * NS_ + w];
    float d0b = 0.f;
    #pragma unroll 8
    for (int kk = 0; kk < 128; kk += 2) {
      float kv0 = buf[l * 129 + kk];
      float kv1 = buf[l * 129 + kk + 1];
      float2 w0 = *(const float2*)&wb[kk * 32 + 2 * w];        // wave-uniform -> s_load
      float2 w1 = *(const float2*)&wb[(kk + 1) * 32 + 2 * w];
      d0a = fmaf(fmaf(w0.y, kv0, w0.x), kv0, d0a);
      d0b = fmaf(fmaf(w1.y, kv1, w1.x), kv1, d0b);
    }
    float e0 = expf(-(d0a + d0b)) + EPS_;
    esum[w * 64 + l] = e0;
    __syncthreads();
    float tot = 0.f;
    #pragma unroll
    for (int q = 0; q < 16; ++q) tot += esum[q * 64 + l];
    float a0 = e0 / tot;
    a1s[w * 66 + l] = a0;
    if (last) {
      attnu[(size_t)(b * NS_ + w) * N_ + jt * 64 + l] = a0;
    }
  }
  __syncthreads();   // phase-A K reads + a1s writes done
  {
    int f0 = tid, f1 = tid + 1024;
    *(float4*)&buf[(f0 >> 5) * 132 + (f0 & 31) * 4] = vr0;
    *(float4*)&buf[(f1 >> 5) * 132 + (f1 & 31) * 4] = vr1;
  }
  __syncthreads();
  // phase B: wave ii owns slot ii; lane dg owns d = {dg, dg+64}
  {
    int ii = __builtin_amdgcn_readfirstlane(threadIdx.x >> 6);
    int dg = tid & 63;
    float av0 = 0.f, av1 = 0.f, aw0 = 0.f, aw1 = 0.f, rsum = 0.f;
    #pragma unroll 4
    for (int j = 0; j < 64; ++j) {
      float a = a1s[ii * 66 + j];          // broadcast
      float v0 = buf[j * 132 + dg];
      float v1 = buf[j * 132 + dg + 64];
      rsum += a;
      float m0 = a * v0, m1 = a * v1;
      av0 += m0; av1 += m1;
      aw0 = fmaf(m0, v0, aw0); aw1 = fmaf(m1, v1, aw1);
    }
    float* pr = &part[((size_t)(b * NT_ + jt) * NS_ + ii) * 260];
    pr[dg] = av0;
    pr[dg + 64] = av1;
    pr[128 + dg] = aw0;
    pr[128 + dg + 64] = aw1;
    if (dg == 0) pr[256] = rsum;
  }
}

// ---------- rK: per-slot update (steps 0..2), 64 blocks x 1024 ----------
__global__ __launch_bounds__(1024, 1) void rK(const float* __restrict__ part,
    float* mu, float* wcoef, float* cbuf, SW w) {
  __shared__ __align__(16) float sl[S_TOT];
  int tid = threadIdx.x;
  int b = blockIdx.x >> 4, i = blockIdx.x & 15;
  slotUpdateT<0>(sl, b, i, tid, part, mu, wcoef, cbuf, w);
}

// ---------- oK: final slot update + out MLP (0..63) + attn normalize (64..127) ----------
__global__ __launch_bounds__(1024, 1) void oK(const float* __restrict__ part,
    float* mu, SW w,
    const unsigned* __restrict__ o1P, const float* __restrict__ ob1,
    const unsigned* __restrict__ o2P, const float* __restrict__ ob2,
    const float* __restrict__ attnu, float* __restrict__ out) {
  __shared__ __align__(16) float sl[S_TOT];
  int blk = blockIdx.x, tid = threadIdx.x;
  const size_t pstr = (size_t)NS_ * 260;
  if (blk >= 64) {
    int r = blk - 64;                   // (b,i) row 0..63
    int b = r >> 4, i = r & 15;
    size_t pbase = ((size_t)(b * NT_) * NS_ + i) * 260;
    if (tid < 64) {
      float v = waveRed1(part[pbase + (size_t)tid * pstr + 256]);
      if (tid == 0) sl[0] = v;
    }
    __syncthreads();
    float rs = sl[0];
    int base = r * 4096 + tid * 4;
    float4 v = *(const float4*)&attnu[base];
    v.x /= rs; v.y /= rs; v.z /= rs; v.w /= rs;
    *(float4*)&out[8192 + base] = v;
    return;
  }
  int b = blk >> 4, i = blk & 15;
  slotUpdateT<1>(sl, b, i, tid, part, mu, (float*)nullptr, (float*)nullptr, w);
  // out-MLP up: 1024 outputs, 1/thread, packed bf16; h1 -> S_P1
  {
    const float* sn = sl + S_SNEW;
    float a0 = 0.f, a1 = 0.f;
    #pragma unroll 16
    for (int r = 0; r < 64; ++r) {
      unsigned p0 = o1P[r * 1024 + tid];
      unsigned p1 = o1P[(64 + r) * 1024 + tid];
      a0 = fmaf(sn[2 * r], bf_lo(p0), a0);
      a0 = fmaf(sn[2 * r + 1], bf_hi(p0), a0);
      a1 = fmaf(sn[128 + 2 * r], bf_lo(p1), a1);
      a1 = fmaf(sn[128 + 2 * r + 1], bf_hi(p1), a1);
    }
    sl[S_P1 + tid] = fmaxf(a0 + a1 + ob1[tid], 0.f);
  }
  __syncthreads();
  // out-MLP down: 128 outputs, 8-way K-split, packed
  float dpart = 0.f;
  {
    int d = tid & 127, qg = tid >> 7;
    const unsigned* wc2 = o2P + (size_t)(qg * 64) * 128 + d;
    const float* h = sl + S_P1 + qg * 128;
    float b0 = 0.f, b1 = 0.f;
    #pragma unroll 16
    for (int r = 0; r < 64; ++r) {
      unsigned p = wc2[r * 128];
      b0 = fmaf(h[2 * r], bf_lo(p), b0);
      b1 = fmaf(h[2 * r + 1], bf_hi(p), b1);
    }
    dpart = b0 + b1;
  }
  __syncthreads();
  {
    int d = tid & 127, qg = tid >> 7;
    sl[qg * 128 + d] = dpart;  // reuse sl[0..1023]
  }
  __syncthreads();
  if (tid < 128) {
    float o = ob2[tid];
    #pragma unroll
    for (int g = 0; g < 8; ++g) o += sl[g * 128 + tid];
    out[(size_t)blk * 128 + tid] = o;
  }
}

extern "C" void kernel_launch(void* const* d_in, const int* in_sizes, int n_in,
                              void* d_out, int out_size, void* d_ws, size_t ws_size,
                              hipStream_t stream) {
  const float* slots_in = (const float*)d_in[0];
  const float* inputs   = (const float*)d_in[1];
  const float* Wq  = (const float*)d_in[2];
  const float* Wk  = (const float*)d_in[3];
  const float* Wv  = (const float*)d_in[4];
  const float* Wih = (const float*)d_in[5];
  const float* Whh = (const float*)d_in[6];
  const float* bih = (const float*)d_in[7];
  const float* bhh = (const float*)d_in[8];
  const float* mW1 = (const float*)d_in[9];
  const float* mb1 = (const float*)d_in[10];
  const float* mW2 = (const float*)d_in[11];
  const float* mb2 = (const float*)d_in[12];
  const float* g_in  = (const float*)d_in[13];
  const float* be_in = (const float*)d_in[14];
  const float* g_sl  = (const float*)d_in[15];
  const float* be_sl = (const float*)d_in[16];
  const float* g_mu  = (const float*)d_in[17];
  const float* be_mu = (const float*)d_in[18];
  const float* oW1 = (const float*)d_in[19];
  const float* ob1 = (const float*)d_in[20];
  const float* oW2 = (const float*)d_in[21];
  const float* ob2 = (const float*)d_in[22];
  float* ws  = (float*)d_ws;
  float* out = (float*)d_out;
  (void)in_sizes; (void)n_in; (void)out_size; (void)ws_size;

  SW w;
  w.wcP = (const unsigned*)(ws + OFF_WCP);
  w.m1P = (const unsigned*)(ws + OFF_M1P);
  w.m2P = (const unsigned*)(ws + OFF_M2P);
  w.wqP = (const unsigned*)(ws + OFF_WQP);
  w.bih = bih; w.bhh = bhh; w.mb1 = mb1; w.mb2 = mb2;
  w.gmu = g_mu; w.bmu = be_mu; w.gsl = g_sl; w.bsl = be_sl;

  hipLaunchKernelGGL(tK, dim3(64), dim3(256), 0, stream,
                     Wq, Wk, Wv, Wih, Whh, mW1, mW2, ws);
  hipLaunchKernelGGL(kvK, dim3(384), dim3(1024), 0, stream,
                     inputs, ws + OFF_WTKV, g_in, be_in, slots_in, w,
                     oW1, oW2, (unsigned*)(ws + OFF_O1P), (unsigned*)(ws + OFF_O2P),
                     ws + OFF_K, ws + OFF_V, ws + OFF_MU, ws + OFF_WCOEF, ws + OFF_C);
  for (int s = 0; s < 4; ++s) {
    hipLaunchKernelGGL(pK, dim3(64, 4), dim3(1024), 0, stream,
                       ws + OFF_K, ws + OFF_V, ws + OFF_WCOEF, ws + OFF_C,
                       ws + OFF_PART, ws + OFF_ATTNU, (s == 3) ? 1 : 0);
    if (s < 3) {
      hipLaunchKernelGGL(rK, dim3(64), dim3(1024), 0, stream,
                         ws + OFF_PART, ws + OFF_MU, ws + OFF_WCOEF, ws + OFF_C, w);
    }
  }
  hipLaunchKernelGGL(oK, dim3(128), dim3(1024), 0, stream,
                     ws + OFF_PART, ws + OFF_MU, w,
                     (const unsigned*)(ws + OFF_O1P), ob1,
                     (const unsigned*)(ws + OFF_O2P), ob2, ws + OFF_ATTNU, out);
}

// Round 11
// 143.672 us; speedup vs baseline: 6.7895x; 1.1127x over previous
//
#include <hip/hip_runtime.h>
#include <math.h>

#define B_ 4
#define N_ 4096
#define D_ 128
#define NS_ 16
#define NT_ 64
#define SCALE_ 0.08838834764831843f
#define EPS_ 1e-10f

// workspace offsets (in 4-byte words)
#define OFF_K      ((size_t)0)
#define OFF_V      (OFF_K + (size_t)B_*N_*D_)
#define OFF_WTKV   (OFF_V + (size_t)B_*N_*D_)   /* f32 [128][256] */
#define OFF_WCP    (OFF_WTKV + 128*256)          /* uint2 [64][512] quad-packed */
#define OFF_M1P    (OFF_WCP + 128*512)           /* uint2 [32][512] */
#define OFF_M2P    (OFF_M1P + 64*512)            /* uint2 [128][128] */
#define OFF_WQP    (OFF_M2P + 256*128)           /* uint2 [32][128] */
#define OFF_O1P    (OFF_WQP + 64*128)            /* uint2 [64][1024] */
#define OFF_O2P    (OFF_O1P + 128*1024)          /* uint2 [256][128] */
#define OFF_MU     (OFF_O2P + 512*128)
#define OFF_WCOEF  (OFF_MU + (size_t)B_*NS_*128) /* [b][16][128][2] */
#define OFF_C      (OFF_WCOEF + (size_t)B_*128*32)
#define OFF_PART   (OFF_C + 64)
#define OFF_ATTNU  (OFF_PART + (size_t)B_*NT_*NS_*260)

// slot scratch offsets (floats)
#define S_ZS    0     /* 256 */
#define S_S2    256   /* 128 */
#define S_UU    384   /* 128 */
#define S_H2    512   /* 128 */
#define S_A1S   640   /* 512 */
#define S_SNEW  1152  /* 256 */
#define S_QM    1408  /* 128 */
#define S_QL    1536  /* 128 */
#define S_RED   1664  /* 32 scratch */
#define S_P1    2688  /* 1024 partial scratch */
#define S_TOT   3712

__device__ __forceinline__ float bf_lo(unsigned p) { return __uint_as_float(p << 16); }
__device__ __forceinline__ float bf_hi(unsigned p) { return __uint_as_float(p & 0xffff0000u); }
__device__ __forceinline__ unsigned packbf(float lo, float hi) {
  unsigned ul = __float_as_uint(lo), uh = __float_as_uint(hi);
  ul = (ul + 0x7fffu + ((ul >> 16) & 1u)) >> 16;
  uh = (uh + 0x7fffu + ((uh >> 16) & 1u)) >> 16;
  return (ul & 0xffffu) | (uh << 16);
}

__device__ __forceinline__ float waveRed1(float a) {
  #pragma unroll
  for (int off = 32; off > 0; off >>= 1) a += __shfl_down(a, off, 64);
  return a;
}
__device__ __forceinline__ float2 waveRed2(float a, float b) {
  #pragma unroll
  for (int off = 32; off > 0; off >>= 1) {
    a += __shfl_down(a, off, 64);
    b += __shfl_down(b, off, 64);
  }
  return make_float2(a, b);
}

// packed-weight + bias bundle
struct SW {
  const unsigned* wcP;   // uint2 [64][512]
  const unsigned* m1P;   // uint2 [32][512]
  const unsigned* m2P;   // uint2 [128][128]
  const unsigned* wqP;   // uint2 [32][128]
  const float* bih; const float* bhh;
  const float* mb1; const float* mb2;
  const float* gmu; const float* bmu;
  const float* gsl; const float* bsl;
};

// input: sl[S_A1S..+255] = LN'd slot row. 1024 threads. 3 barriers.
__device__ __forceinline__ void slotTail1024(float* sl, int b, int i, int tid,
    const unsigned* __restrict__ wqPu, float* wcoef, float* cbuf) {
  float* red = sl + S_RED;
  {
    int rest = tid & 255, kg = tid >> 8;
    int wh = rest >> 7, o = rest & 127;
    const uint2* wq = (const uint2*)wqPu + (size_t)(kg * 8) * 128 + o;
    const float* s = sl + S_A1S + wh * 128 + kg * 32;
    float a0 = 0.f, a1 = 0.f, a2 = 0.f, a3 = 0.f;
    #pragma unroll
    for (int r = 0; r < 8; ++r) {
      uint2 p = wq[r * 128];
      a0 = fmaf(s[4 * r],     bf_lo(p.x), a0);
      a1 = fmaf(s[4 * r + 1], bf_hi(p.x), a1);
      a2 = fmaf(s[4 * r + 2], bf_lo(p.y), a2);
      a3 = fmaf(s[4 * r + 3], bf_hi(p.y), a3);
    }
    sl[S_P1 + kg * 256 + rest] = (a0 + a1) + (a2 + a3);
  }
  __syncthreads();
  if (tid < 256) {
    float q = sl[S_P1 + tid] + sl[S_P1 + 256 + tid] + sl[S_P1 + 512 + tid] + sl[S_P1 + 768 + tid];
    if (tid < 128) sl[S_QM + tid] = q; else sl[S_QL + (tid - 128)] = q;
  }
  __syncthreads();
  if (tid < 128) {
    float iv = expf(-2.f * sl[S_QL + tid]);
    float a1 = SCALE_ * iv;
    float a2 = -2.f * SCALE_ * iv * sl[S_QM + tid];
    float* wrow = &wcoef[(((size_t)b * 16 + i) * 128 + tid) * 2];
    wrow[0] = a2;
    wrow[1] = a1;
    float cp = SCALE_ * iv * sl[S_QM + tid] * sl[S_QM + tid];
    float r = waveRed1(cp);
    if ((tid & 63) == 0) red[16 + (tid >> 6)] = r;
  }
  __syncthreads();
  if (tid == 0) cbuf[b * NS_ + i] = red[16] + red[17];
}

// 1024-thread slot update. FINAL=0: full incl. next-step prep. FINAL=1: stop with snew in LDS.
template <int FINAL>
__device__ void slotUpdateT(float* sl, int b, int i, int tid,
    const float* __restrict__ part, float* mu, float* wcoef, float* cbuf, SW w) {
  float* red = sl + S_RED;
  size_t pbase = ((size_t)(b * NT_) * NS_ + i) * 260;
  const size_t pstr = (size_t)NS_ * 260;
  // part reduce: 4 groups x 16 tiles
  {
    int g = tid >> 8, e = tid & 255;
    float s = 0.f;
    #pragma unroll 16
    for (int t = 0; t < 16; ++t) s += part[pbase + (size_t)(g * 16 + t) * pstr + e];
    sl[S_P1 + g * 256 + e] = s;
  }
  if (tid < 64) {
    float rtv = waveRed1(part[pbase + (size_t)tid * pstr + 256]);
    if (tid == 0) red[0] = rtv;
  }
  __syncthreads();  // B1
  float rt = red[0];
  if (tid < 256) {
    float s = sl[S_P1 + tid] + sl[S_P1 + 256 + tid] + sl[S_P1 + 512 + tid] + sl[S_P1 + 768 + tid];
    if (tid < 128) sl[S_ZS + tid] = s / rt; else sl[S_S2 + tid - 128] = s / rt;
  } else if (tid < 384) {
    sl[S_ZS + tid - 128] = mu[(size_t)(b * NS_ + i) * 128 + (tid - 256)];
  }
  __syncthreads();  // B2
  // GRU matvec: 512 outputs, 2-way K-split, quad-packed
  {
    int q = tid & 511, kg = tid >> 9;
    const uint2* wcol = (const uint2*)w.wcP + (size_t)(kg * 32) * 512 + q;
    const float* xz = sl + S_ZS + kg * 128;
    float a0 = 0.f, a1 = 0.f, a2 = 0.f, a3 = 0.f;
    #pragma unroll 16
    for (int r = 0; r < 32; ++r) {
      uint2 p = wcol[r * 512];
      a0 = fmaf(xz[4 * r],     bf_lo(p.x), a0);
      a1 = fmaf(xz[4 * r + 1], bf_hi(p.x), a1);
      a2 = fmaf(xz[4 * r + 2], bf_lo(p.y), a2);
      a3 = fmaf(xz[4 * r + 3], bf_hi(p.y), a3);
    }
    sl[S_P1 + kg * 512 + q] = (a0 + a1) + (a2 + a3);
  }
  __syncthreads();  // B3
  float uu_reg = 0.f;
  if (tid < 128) {
    float o_r = sl[S_P1 + tid] + sl[S_P1 + 512 + tid];
    float o_z = sl[S_P1 + 128 + tid] + sl[S_P1 + 640 + tid];
    float o_n = sl[S_P1 + 256 + tid] + sl[S_P1 + 768 + tid];
    float o_g = sl[S_P1 + 384 + tid] + sl[S_P1 + 896 + tid];
    float r = 1.f / (1.f + expf(-(o_r + w.bih[tid] + w.bhh[tid])));
    float z = 1.f / (1.f + expf(-(o_z + w.bih[128 + tid] + w.bhh[128 + tid])));
    float nn = tanhf(o_n + w.bih[256 + tid] + r * (o_g + w.bhh[256 + tid]));
    uu_reg = (1.f - z) * nn + z * sl[S_ZS + 128 + tid];
    sl[S_UU + tid] = uu_reg;
    float2 r2 = waveRed2(uu_reg, uu_reg * uu_reg);
    if ((tid & 63) == 0) { red[4 + (tid >> 6) * 2] = r2.x; red[5 + (tid >> 6) * 2] = r2.y; }
  }
  __syncthreads();  // B4
  if (tid < 128) {
    float sum = red[4] + red[6], sq = red[5] + red[7];
    float m = sum * (1.f / 128.f);
    float var = sq * (1.f / 128.f) - m * m;
    float rsq = rsqrtf(var + 1e-5f);
    sl[S_H2 + tid] = (uu_reg - m) * rsq * w.gmu[tid] + w.bmu[tid];
  }
  __syncthreads();  // B5
  // MLP up: 512 outputs, 2-way K-split, quad-packed
  {
    int q = tid & 511, kg = tid >> 9;
    const uint2* wc1 = (const uint2*)w.m1P + (size_t)(kg * 16) * 512 + q;
    const float* h = sl + S_H2 + kg * 64;
    float a0 = 0.f, a1 = 0.f, a2 = 0.f, a3 = 0.f;
    #pragma unroll
    for (int r = 0; r < 16; ++r) {
      uint2 p = wc1[r * 512];
      a0 = fmaf(h[4 * r],     bf_lo(p.x), a0);
      a1 = fmaf(h[4 * r + 1], bf_hi(p.x), a1);
      a2 = fmaf(h[4 * r + 2], bf_lo(p.y), a2);
      a3 = fmaf(h[4 * r + 3], bf_hi(p.y), a3);
    }
    sl[S_P1 + kg * 512 + q] = (a0 + a1) + (a2 + a3);
  }
  __syncthreads();  // B6
  if (tid < 512)
    sl[S_A1S + tid] = fmaxf(sl[S_P1 + tid] + sl[S_P1 + 512 + tid] + w.mb1[tid], 0.f);
  __syncthreads();  // B7
  // MLP down: 128 outputs, 8-way K-split, quad-packed
  {
    int d = tid & 127, qg = tid >> 7;
    const uint2* wc2 = (const uint2*)w.m2P + (size_t)(qg * 16) * 128 + d;
    const float* a = sl + S_A1S + qg * 64;
    float b0 = 0.f, b1 = 0.f, b2 = 0.f, b3 = 0.f;
    #pragma unroll
    for (int r = 0; r < 16; ++r) {
      uint2 p = wc2[r * 128];
      b0 = fmaf(a[4 * r],     bf_lo(p.x), b0);
      b1 = fmaf(a[4 * r + 1], bf_hi(p.x), b1);
      b2 = fmaf(a[4 * r + 2], bf_lo(p.y), b2);
      b3 = fmaf(a[4 * r + 3], bf_hi(p.y), b3);
    }
    sl[S_P1 + qg * 128 + d] = (b0 + b1) + (b2 + b3);
  }
  __syncthreads();  // B8
  if (tid < 128) {
    float o = w.mb2[tid];
    #pragma unroll
    for (int g = 0; g < 8; ++g) o += sl[S_P1 + g * 128 + tid];
    float uf = sl[S_UU + tid] + o;
    float xsv = sl[S_ZS + tid];
    float arg = sl[S_S2 + tid] - 2.f * uf * xsv + uf * uf + EPS_;
    float lsv = 0.5f * logf(fmaxf(arg, 1e-30f));
    sl[S_SNEW + tid] = uf;
    sl[S_SNEW + 128 + tid] = lsv;
  }
  __syncthreads();  // B9
  if (FINAL) return;
  // next-step LN over new slot row (fused sum/sumsq)
  float xv = 0.f;
  if (tid < 256) {
    xv = sl[S_SNEW + tid];
    float2 r2 = waveRed2(xv, xv * xv);
    if ((tid & 63) == 0) { red[8 + (tid >> 6) * 2] = r2.x; red[9 + (tid >> 6) * 2] = r2.y; }
  }
  __syncthreads();  // B10
  if (tid < 256) {
    float sum = red[8] + red[10] + red[12] + red[14];
    float sq = red[9] + red[11] + red[13] + red[15];
    float m2 = sum * (1.f / 256.f);
    float var2 = sq * (1.f / 256.f) - m2 * m2;
    float rs2 = rsqrtf(var2 + 1e-5f);
    float slv = (xv - m2) * rs2 * w.gsl[tid] + w.bsl[tid];
    sl[S_A1S + tid] = slv;
    if (tid < 128) mu[(size_t)(b * NS_ + i) * 128 + tid] = slv;
  }
  __syncthreads();  // B11
  slotTail1024(sl, b, i, tid, w.wqP, wcoef, cbuf);
}

// ---------- tK: k/v weight transpose (f32) + quad-packed slot weights ----------
__global__ __launch_bounds__(256) void tK(
    const float* __restrict__ Wq, const float* __restrict__ Wk, const float* __restrict__ Wv,
    const float* __restrict__ Wih, const float* __restrict__ Whh,
    const float* __restrict__ mW1, const float* __restrict__ mW2,
    float* __restrict__ ws) {
  int tid = blockIdx.x * blockDim.x + threadIdx.x;
  int stride = gridDim.x * blockDim.x;
  uint2* wcP = (uint2*)(ws + OFF_WCP);
  uint2* m1P = (uint2*)(ws + OFF_M1P);
  uint2* m2P = (uint2*)(ws + OFF_M2P);
  uint2* wqP = (uint2*)(ws + OFF_WQP);
  for (int idx = tid; idx < 128 * 256; idx += stride) {
    int kk = idx >> 8, c = idx & 255;
    ws[OFF_WTKV + idx] = (c < 128) ? Wk[c * 128 + kk] : Wv[(c - 128) * 128 + kk];
  }
  // wcP quad rows of virtual WC[256][512]
  for (int idx = tid; idx < 64 * 512; idx += stride) {
    int r2 = idx >> 9, q = idx & 511;
    float v[4];
    #pragma unroll
    for (int j = 0; j < 4; ++j) {
      int dd = 4 * r2 + j;
      float val;
      if (dd < 128) {
        val = (q < 384) ? Wih[q * 128 + dd] : 0.f;
      } else {
        int dh = dd - 128;
        if (q < 256)      val = Whh[q * 128 + dh];
        else if (q < 384) val = 0.f;
        else              val = Whh[(q - 128) * 128 + dh];
      }
      v[j] = val;
    }
    wcP[idx] = make_uint2(packbf(v[0], v[1]), packbf(v[2], v[3]));
  }
  for (int idx = tid; idx < 32 * 512; idx += stride) {
    int r2 = idx >> 9, q = idx & 511;
    m1P[idx] = make_uint2(packbf(mW1[q * 128 + 4 * r2], mW1[q * 128 + 4 * r2 + 1]),
                          packbf(mW1[q * 128 + 4 * r2 + 2], mW1[q * 128 + 4 * r2 + 3]));
  }
  for (int idx = tid; idx < 128 * 128; idx += stride) {
    int qq = idx >> 7, d = idx & 127;
    m2P[idx] = make_uint2(packbf(mW2[d * 512 + 4 * qq], mW2[d * 512 + 4 * qq + 1]),
                          packbf(mW2[d * 512 + 4 * qq + 2], mW2[d * 512 + 4 * qq + 3]));
  }
  for (int idx = tid; idx < 32 * 128; idx += stride) {
    int r2 = idx >> 7, o = idx & 127;
    wqP[idx] = make_uint2(packbf(Wq[o * 128 + 4 * r2], Wq[o * 128 + 4 * r2 + 1]),
                          packbf(Wq[o * 128 + 4 * r2 + 2], Wq[o * 128 + 4 * r2 + 3]));
  }
}

// ---------- kvK: LN+k/v GEMM (0..255) + slot prep (256..319) + out-weight packing (320..383) ----------
__global__ __launch_bounds__(1024, 1) void kvK(const float* __restrict__ inp,
    const float* __restrict__ wt, const float* __restrict__ gin, const float* __restrict__ bin,
    const float* __restrict__ slots_in, SW w,
    const float* __restrict__ oW1, const float* __restrict__ oW2,
    unsigned* __restrict__ o1P, unsigned* __restrict__ o2P,
    float* __restrict__ kb, float* __restrict__ vb,
    float* __restrict__ mu, float* wcoef, float* cbuf) {
  __shared__ __align__(16) float shm[9600];
  int tid = threadIdx.x;
  int blk = blockIdx.x;
  if (blk < 256) {
    float* xs = shm;            // [64][132]
    float* red = shm + 8448;    // [64][16]
    float* mrow = shm + 9472;   // 64
    float* rrow = shm + 9536;   // 64
    int rowbase = blk * 64;
    #pragma unroll
    for (int it = 0; it < 2; ++it) {
      int f = tid + it * 1024;
      int row = f >> 5, c4 = (f & 31) * 4;
      const float4 v = *(const float4*)&inp[(size_t)(rowbase + row) * 128 + c4];
      *(float4*)&xs[row * 132 + c4] = v;
    }
    __syncthreads();
    // LN: 16 threads/row, fused sum/sumsq
    int row = tid >> 4, prt = tid & 15;
    float s = 0.f, s2 = 0.f;
    #pragma unroll
    for (int e = 0; e < 8; ++e) {
      float v = xs[row * 132 + prt * 8 + e];
      s += v; s2 = fmaf(v, v, s2);
    }
    red[row * 16 + prt] = s;
    __syncthreads();
    if (prt == 0) {
      float m = 0.f;
      #pragma unroll
      for (int q = 0; q < 16; ++q) m += red[row * 16 + q];
      mrow[row] = m * (1.f / 128.f);
    }
    __syncthreads();
    float m = mrow[row];
    red[row * 16 + prt] = s2;
    __syncthreads();
    if (prt == 0) {
      float v = 0.f;
      #pragma unroll
      for (int q = 0; q < 16; ++q) v += red[row * 16 + q];
      float var = v * (1.f / 128.f) - m * m;
      rrow[row] = rsqrtf(var + 1e-5f);
    }
    __syncthreads();
    float rs = rrow[row];
    #pragma unroll
    for (int e = 0; e < 8; ++e) {
      int c = prt * 8 + e;
      xs[row * 132 + c] = (xs[row * 132 + c] - m) * rs * gin[c] + bin[c];
    }
    __syncthreads();
    // GEMM: 16 waves, wave wv owns 16 of 256 cols; float2 activation reads
    int l = tid & 63;
    int wv = __builtin_amdgcn_readfirstlane(threadIdx.x >> 6);
    int cbase = wv * 16;
    float acc[16];
    #pragma unroll
    for (int e = 0; e < 16; ++e) acc[e] = 0.f;
    #pragma unroll 4
    for (int kk = 0; kk < 128; kk += 2) {
      float2 xv = *(const float2*)&xs[l * 132 + kk];
      const float* wr0 = &wt[kk * 256 + cbase];        // wave-uniform -> s_load
      const float* wr1 = &wt[(kk + 1) * 256 + cbase];
      #pragma unroll
      for (int e = 0; e < 16; ++e) {
        acc[e] = fmaf(xv.x, wr0[e], acc[e]);
        acc[e] = fmaf(xv.y, wr1[e], acc[e]);
      }
    }
    float* outp = (cbase < 128) ? kb : vb;
    int col = cbase & 127;
    size_t o = (size_t)(rowbase + l) * 128 + col;
    #pragma unroll
    for (int e4 = 0; e4 < 4; ++e4)
      *(float4*)&outp[o + e4 * 4] =
          make_float4(acc[e4 * 4], acc[e4 * 4 + 1], acc[e4 * 4 + 2], acc[e4 * 4 + 3]);
  } else if (blk < 320) {
    float* sl = shm;
    float* red = sl + S_RED;
    int sb = blk - 256;
    int b2 = sb >> 4, i = sb & 15;
    float xv = 0.f;
    if (tid < 256) {
      xv = slots_in[(size_t)(b2 * NS_ + i) * 256 + tid];
      float2 r2 = waveRed2(xv, xv * xv);
      if ((tid & 63) == 0) { red[8 + (tid >> 6) * 2] = r2.x; red[9 + (tid >> 6) * 2] = r2.y; }
    }
    __syncthreads();
    if (tid < 256) {
      float sum = red[8] + red[10] + red[12] + red[14];
      float sq = red[9] + red[11] + red[13] + red[15];
      float m = sum * (1.f / 256.f);
      float var = sq * (1.f / 256.f) - m * m;
      float rs = rsqrtf(var + 1e-5f);
      float slv = (xv - m) * rs * w.gsl[tid] + w.bsl[tid];
      sl[S_A1S + tid] = slv;
      if (tid < 128) mu[(size_t)(b2 * NS_ + i) * 128 + tid] = slv;
    }
    __syncthreads();
    slotTail1024(sl, b2, i, tid, w.wqP, wcoef, cbuf);
  } else {
    // out-MLP weight quad-packing: 64 blocks
    int pb = blk - 320;
    uint2* o1 = (uint2*)o1P;
    {
      int idx = pb * 1024 + tid;           // 65536 uint2
      int r2 = idx >> 10, q = idx & 1023;
      o1[idx] = make_uint2(packbf(oW1[q * 256 + 4 * r2], oW1[q * 256 + 4 * r2 + 1]),
                           packbf(oW1[q * 256 + 4 * r2 + 2], oW1[q * 256 + 4 * r2 + 3]));
    }
    if (pb < 32) {
      uint2* o2 = (uint2*)o2P;
      int idx = pb * 1024 + tid;           // 32768 uint2
      int qq = idx >> 7, d = idx & 127;
      o2[idx] = make_uint2(packbf(oW2[d * 1024 + 4 * qq], oW2[d * 1024 + 4 * qq + 1]),
                           packbf(oW2[d * 1024 + 4 * qq + 2], oW2[d * 1024 + 4 * qq + 3]));
    }
  }
}

// ---------- pK: token pass per step (1024 threads, vectorized LDS) ----------
__global__ __launch_bounds__(1024, 1) void pK(const float* __restrict__ kb,
    const float* __restrict__ vb, const float* __restrict__ wcoef,
    const float* __restrict__ cbuf, float* __restrict__ part,
    float* __restrict__ attnu, int last) {
  __shared__ __align__(16) float buf[64 * 132];   // K then V, [64][132]
  __shared__ __align__(16) float a1s[16 * 68];
  __shared__ float esum[16 * 64];
  int tid = threadIdx.x;
  int jt = blockIdx.x, b = blockIdx.y;
  size_t jrow = (size_t)(b * N_ + jt * 64);
  #pragma unroll
  for (int it = 0; it < 2; ++it) {
    int f = tid + it * 1024;
    int row = f >> 5, c4 = (f & 31) * 4;
    float4 kv = *(const float4*)&kb[(jrow + row) * 128 + c4];
    *(float4*)&buf[row * 132 + c4] = kv;
  }
  __syncthreads();
  // prefetch V tile into registers (latency hides under phase A)
  float4 vr0, vr1;
  {
    int f0 = tid, f1 = tid + 1024;
    vr0 = *(const float4*)&vb[(jrow + (f0 >> 5)) * 128 + (f0 & 31) * 4];
    vr1 = *(const float4*)&vb[(jrow + (f1 >> 5)) * 128 + (f1 & 31) * 4];
  }
  // phase A: wave w owns slot w; lanes = tokens; b128 K reads, dwordx8 coef streams
  {
    int l = tid & 63;
    int w = __builtin_amdgcn_readfirstlane(threadIdx.x >> 6);
    const float* wq = &wcoef[((size_t)b * 16 + w) * 256];
    float c0 = cbuf[b * NS_ + w];
    float a0 = 0.f, a1 = 0.f, a2 = 0.f, a3 = 0.f;
    #pragma unroll 8
    for (int kk = 0; kk < 128; kk += 4) {
      float4 kv = *(const float4*)&buf[l * 132 + kk];
      float4 wA = *(const float4*)&wq[kk * 2];       // a2_k,a1_k,a2_k+1,a1_k+1
      float4 wB = *(const float4*)&wq[kk * 2 + 4];
      a0 = fmaf(fmaf(wA.y, kv.x, wA.x), kv.x, a0);
      a1 = fmaf(fmaf(wA.w, kv.y, wA.z), kv.y, a1);
      a2 = fmaf(fmaf(wB.y, kv.z, wB.x), kv.z, a2);
      a3 = fmaf(fmaf(wB.w, kv.w, wB.z), kv.w, a3);
    }
    float e0 = expf(-(c0 + (a0 + a1) + (a2 + a3))) + EPS_;
    esum[w * 64 + l] = e0;
    __syncthreads();
    float tot = 0.f;
    #pragma unroll
    for (int q = 0; q < 16; ++q) tot += esum[q * 64 + l];
    float av = e0 / tot;
    a1s[w * 68 + l] = av;
    if (last) attnu[(size_t)(b * NS_ + w) * N_ + jt * 64 + l] = av;
  }
  __syncthreads();   // phase-A K reads + a1s writes done
  {
    int f0 = tid, f1 = tid + 1024;
    *(float4*)&buf[(f0 >> 5) * 132 + (f0 & 31) * 4] = vr0;
    *(float4*)&buf[(f1 >> 5) * 132 + (f1 & 31) * 4] = vr1;
  }
  __syncthreads();
  // phase B: wave ii owns slot ii; lane (l&31) owns d=4(l&31)..+3; j split across lane halves
  {
    int ii = __builtin_amdgcn_readfirstlane(threadIdx.x >> 6);
    int lh = (tid >> 5) & 1;
    int l4 = (tid & 31) * 4;
    float av0 = 0, av1 = 0, av2 = 0, av3 = 0, aw0 = 0, aw1 = 0, aw2 = 0, aw3 = 0, rsum = 0;
    #pragma unroll
    for (int jj = 0; jj < 32; jj += 4) {
      int j = lh * 32 + jj;
      float4 a4 = *(const float4*)&a1s[ii * 68 + j];
      float aarr[4] = {a4.x, a4.y, a4.z, a4.w};
      #pragma unroll
      for (int e = 0; e < 4; ++e) {
        float a = aarr[e];
        float4 v = *(const float4*)&buf[(j + e) * 132 + l4];
        rsum += a;
        float m0 = a * v.x, m1 = a * v.y, m2 = a * v.z, m3 = a * v.w;
        av0 += m0; av1 += m1; av2 += m2; av3 += m3;
        aw0 = fmaf(m0, v.x, aw0); aw1 = fmaf(m1, v.y, aw1);
        aw2 = fmaf(m2, v.z, aw2); aw3 = fmaf(m3, v.w, aw3);
      }
    }
    av0 += __shfl_down(av0, 32, 64); av1 += __shfl_down(av1, 32, 64);
    av2 += __shfl_down(av2, 32, 64); av3 += __shfl_down(av3, 32, 64);
    aw0 += __shfl_down(aw0, 32, 64); aw1 += __shfl_down(aw1, 32, 64);
    aw2 += __shfl_down(aw2, 32, 64); aw3 += __shfl_down(aw3, 32, 64);
    rsum += __shfl_down(rsum, 32, 64);
    if ((tid & 63) < 32) {
      float* pr = &part[((size_t)(b * NT_ + jt) * NS_ + ii) * 260];
      *(float4*)&pr[l4] = make_float4(av0, av1, av2, av3);
      *(float4*)&pr[128 + l4] = make_float4(aw0, aw1, aw2, aw3);
      if ((tid & 63) == 0) pr[256] = rsum;
    }
  }
}

// ---------- rK: per-slot update (steps 0..2), 64 blocks x 1024 ----------
__global__ __launch_bounds__(1024, 1) void rK(const float* __restrict__ part,
    float* mu, float* wcoef, float* cbuf, SW w) {
  __shared__ __align__(16) float sl[S_TOT];
  int tid = threadIdx.x;
  int b = blockIdx.x >> 4, i = blockIdx.x & 15;
  slotUpdateT<0>(sl, b, i, tid, part, mu, wcoef, cbuf, w);
}

// ---------- oK: final slot update + out MLP (0..63) + attn normalize (64..127) ----------
__global__ __launch_bounds__(1024, 1) void oK(const float* __restrict__ part,
    float* mu, SW w,
    const unsigned* __restrict__ o1P, const float* __restrict__ ob1,
    const unsigned* __restrict__ o2P, const float* __restrict__ ob2,
    const float* __restrict__ attnu, float* __restrict__ out) {
  __shared__ __align__(16) float sl[S_TOT];
  int blk = blockIdx.x, tid = threadIdx.x;
  const size_t pstr = (size_t)NS_ * 260;
  if (blk >= 64) {
    int r = blk - 64;
    int b = r >> 4, i = r & 15;
    size_t pbase = ((size_t)(b * NT_) * NS_ + i) * 260;
    if (tid < 64) {
      float v = waveRed1(part[pbase + (size_t)tid * pstr + 256]);
      if (tid == 0) sl[0] = v;
    }
    __syncthreads();
    float rs = sl[0];
    int base = r * 4096 + tid * 4;
    float4 v = *(const float4*)&attnu[base];
    v.x /= rs; v.y /= rs; v.z /= rs; v.w /= rs;
    *(float4*)&out[8192 + base] = v;
    return;
  }
  int b = blk >> 4, i = blk & 15;
  slotUpdateT<1>(sl, b, i, tid, part, mu, (float*)nullptr, (float*)nullptr, w);
  // out-MLP up: 1024 outputs, 1/thread, quad-packed; h1 -> S_P1
  {
    const float* sn = sl + S_SNEW;
    const uint2* o1 = (const uint2*)o1P;
    float a0 = 0.f, a1 = 0.f;
    #pragma unroll 8
    for (int r = 0; r < 32; ++r) {
      uint2 p0 = o1[r * 1024 + tid];
      uint2 p1 = o1[(32 + r) * 1024 + tid];
      a0 = fmaf(sn[4 * r],     bf_lo(p0.x), a0);
      a0 = fmaf(sn[4 * r + 1], bf_hi(p0.x), a0);
      a0 = fmaf(sn[4 * r + 2], bf_lo(p0.y), a0);
      a0 = fmaf(sn[4 * r + 3], bf_hi(p0.y), a0);
      a1 = fmaf(sn[128 + 4 * r],     bf_lo(p1.x), a1);
      a1 = fmaf(sn[128 + 4 * r + 1], bf_hi(p1.x), a1);
      a1 = fmaf(sn[128 + 4 * r + 2], bf_lo(p1.y), a1);
      a1 = fmaf(sn[128 + 4 * r + 3], bf_hi(p1.y), a1);
    }
    sl[S_P1 + tid] = fmaxf(a0 + a1 + ob1[tid], 0.f);
  }
  __syncthreads();
  // out-MLP down: 128 outputs, 8-way K-split, quad-packed
  float dpart = 0.f;
  {
    int d = tid & 127, qg = tid >> 7;
    const uint2* wc2 = (const uint2*)o2P + (size_t)(qg * 32) * 128 + d;
    const float* h = sl + S_P1 + qg * 128;
    float b0 = 0.f, b1 = 0.f, b2 = 0.f, b3 = 0.f;
    #pragma unroll 8
    for (int r = 0; r < 32; ++r) {
      uint2 p = wc2[r * 128];
      b0 = fmaf(h[4 * r],     bf_lo(p.x), b0);
      b1 = fmaf(h[4 * r + 1], bf_hi(p.x), b1);
      b2 = fmaf(h[4 * r + 2], bf_lo(p.y), b2);
      b3 = fmaf(h[4 * r + 3], bf_hi(p.y), b3);
    }
    dpart = (b0 + b1) + (b2 + b3);
  }
  __syncthreads();
  {
    int d = tid & 127, qg = tid >> 7;
    sl[qg * 128 + d] = dpart;  // reuse sl[0..1023]
  }
  __syncthreads();
  if (tid < 128) {
    float o = ob2[tid];
    #pragma unroll
    for (int g = 0; g < 8; ++g) o += sl[g * 128 + tid];
    out[(size_t)blk * 128 + tid] = o;
  }
}

extern "C" void kernel_launch(void* const* d_in, const int* in_sizes, int n_in,
                              void* d_out, int out_size, void* d_ws, size_t ws_size,
                              hipStream_t stream) {
  const float* slots_in = (const float*)d_in[0];
  const float* inputs   = (const float*)d_in[1];
  const float* Wq  = (const float*)d_in[2];
  const float* Wk  = (const float*)d_in[3];
  const float* Wv  = (const float*)d_in[4];
  const float* Wih = (const float*)d_in[5];
  const float* Whh = (const float*)d_in[6];
  const float* bih = (const float*)d_in[7];
  const float* bhh = (const float*)d_in[8];
  const float* mW1 = (const float*)d_in[9];
  const float* mb1 = (const float*)d_in[10];
  const float* mW2 = (const float*)d_in[11];
  const float* mb2 = (const float*)d_in[12];
  const float* g_in  = (const float*)d_in[13];
  const float* be_in = (const float*)d_in[14];
  const float* g_sl  = (const float*)d_in[15];
  const float* be_sl = (const float*)d_in[16];
  const float* g_mu  = (const float*)d_in[17];
  const float* be_mu = (const float*)d_in[18];
  const float* oW1 = (const float*)d_in[19];
  const float* ob1 = (const float*)d_in[20];
  const float* oW2 = (const float*)d_in[21];
  const float* ob2 = (const float*)d_in[22];
  float* ws  = (float*)d_ws;
  float* out = (float*)d_out;
  (void)in_sizes; (void)n_in; (void)out_size; (void)ws_size;

  SW w;
  w.wcP = (const unsigned*)(ws + OFF_WCP);
  w.m1P = (const unsigned*)(ws + OFF_M1P);
  w.m2P = (const unsigned*)(ws + OFF_M2P);
  w.wqP = (const unsigned*)(ws + OFF_WQP);
  w.bih = bih; w.bhh = bhh; w.mb1 = mb1; w.mb2 = mb2;
  w.gmu = g_mu; w.bmu = be_mu; w.gsl = g_sl; w.bsl = be_sl;

  hipLaunchKernelGGL(tK, dim3(64), dim3(256), 0, stream,
                     Wq, Wk, Wv, Wih, Whh, mW1, mW2, ws);
  hipLaunchKernelGGL(kvK, dim3(384), dim3(1024), 0, stream,
                     inputs, ws + OFF_WTKV, g_in, be_in, slots_in, w,
                     oW1, oW2, (unsigned*)(ws + OFF_O1P), (unsigned*)(ws + OFF_O2P),
                     ws + OFF_K, ws + OFF_V, ws + OFF_MU, ws + OFF_WCOEF, ws + OFF_C);
  for (int s = 0; s < 4; ++s) {
    hipLaunchKernelGGL(pK, dim3(64, 4), dim3(1024), 0, stream,
                       ws + OFF_K, ws + OFF_V, ws + OFF_WCOEF, ws + OFF_C,
                       ws + OFF_PART, ws + OFF_ATTNU, (s == 3) ? 1 : 0);
    if (s < 3) {
      hipLaunchKernelGGL(rK, dim3(64), dim3(1024), 0, stream,
                         ws + OFF_PART, ws + OFF_MU, ws + OFF_WCOEF, ws + OFF_C, w);
    }
  }
  hipLaunchKernelGGL(oK, dim3(128), dim3(1024), 0, stream,
                     ws + OFF_PART, ws + OFF_MU, w,
                     (const unsigned*)(ws + OFF_O1P), ob1,
                     (const unsigned*)(ws + OFF_O2P), ob2, ws + OFF_ATTNU, out);
}